// Round 5
// baseline (2123.677 us; speedup 1.0000x reference)
//
#include <hip/hip_runtime.h>
#include <math.h>

#define NB 8
#define NPTS 2048
#define NF 323
#define CPAD 352      // bf16 feature row stride (multiple of 32, >= 323)
#define K 20
#define EPSV 1e-5f
#define SLOPE 0.2f
#define NCAND 32      // approx candidates kept for exact re-rank (>= K+1)

typedef __attribute__((ext_vector_type(8))) short short8;
typedef __attribute__((ext_vector_type(4))) float f32x4;

__device__ __forceinline__ float lrelu(float x){ return x >= 0.f ? x : SLOPE * x; }

__device__ __forceinline__ unsigned fkey(float f){
    unsigned u = __float_as_uint(f);
    return (u & 0x80000000u) ? ~u : (u | 0x80000000u);
}
__device__ __forceinline__ float funkey(unsigned k){
    return (k & 0x80000000u) ? __uint_as_float(k ^ 0x80000000u) : __uint_as_float(~k);
}

__device__ __forceinline__ unsigned short f2bf_rne(float x){
    unsigned u = __float_as_uint(x);
    unsigned r = u + 0x7fffu + ((u >> 16) & 1u);
    return (unsigned short)(r >> 16);
}
__device__ __forceinline__ void split_bf(float x, unsigned short& h, unsigned short& l){
    h = f2bf_rne(x);
    float hf = __uint_as_float(((unsigned)h) << 16);
    l = f2bf_rne(x - hf);
}

// ---- x (B,3,N) -> F (B*N,323) fp32 + Fh/Fl bf16 planes, channels [0,3) ----
__global__ void copy_x_kernel(const float* __restrict__ x, float* __restrict__ F,
                              unsigned short* __restrict__ Fh, unsigned short* __restrict__ Fl){
    int gid = blockIdx.x * 256 + threadIdx.x;
    if (gid >= NB * NPTS) return;
    int b = gid / NPTS, n = gid % NPTS;
    float* dst = F + (size_t)gid * NF;
    #pragma unroll
    for (int c = 0; c < 3; c++){
        float v = x[((size_t)b * 3 + c) * NPTS + n];
        dst[c] = v;
        unsigned short h, l; split_bf(v, h, l);
        Fh[(size_t)gid * CPAD + c] = h;
        Fl[(size_t)gid * CPAD + c] = l;
    }
}

// ---- per-point squared norm over first C channels (fp32, for approx dist only) ----
__global__ __launch_bounds__(256) void sqnorm_kernel(const float* __restrict__ F, float* __restrict__ sq, int C){
    int row = blockIdx.x * 4 + (threadIdx.x >> 6);
    int lane = threadIdx.x & 63;
    const float* f = F + (size_t)row * NF;
    float s = 0.f;
    for (int c = lane; c < C; c += 64){ float t = f[c]; s += t * t; }
    #pragma unroll
    for (int off = 32; off; off >>= 1) s += __shfl_xor(s, off);
    if (lane == 0) sq[row] = s;
}

// ---- per-point squared norm, fp64 (for exact re-rank) ----
__global__ __launch_bounds__(256) void sqnormd_kernel(const float* __restrict__ F, double* __restrict__ sqd, int C){
    int row = blockIdx.x * 4 + (threadIdx.x >> 6);
    int lane = threadIdx.x & 63;
    const float* f = F + (size_t)row * NF;
    double s = 0.0;
    for (int c = lane; c < C; c += 64){ double t = (double)f[c]; s = fma(t, t, s); }
    #pragma unroll
    for (int off = 32; off; off >>= 1) s += __shfl_xor(s, off);
    if (lane == 0) sqd[row] = s;
}

// ---- W5 -> bf16 hi/lo, padded to CPAD ----
__global__ void convW_kernel(const float* __restrict__ W5, unsigned short* __restrict__ Wh,
                             unsigned short* __restrict__ Wl){
    int gid = blockIdx.x * 256 + threadIdx.x;
    if (gid >= 1024 * CPAD) return;
    int o = gid / CPAD, c = gid % CPAD;
    float w = (c < NF) ? W5[(size_t)o * NF + c] : 0.f;
    unsigned short h, l; split_bf(w, h, l);
    Wh[gid] = h; Wl[gid] = l;
}

// ---- approx inv-dist Gram tile via bf16x3 MFMA: 128x128 per block, 4 waves ----
__global__ __launch_bounds__(256) void dist_mfma_kernel(
    const unsigned short* __restrict__ Fh, const unsigned short* __restrict__ Fl,
    const float* __restrict__ sq, float* __restrict__ dist, int b0, int Kp)
{
    __shared__ __align__(16) unsigned short Ah[128][40], Al[128][40], Bh[128][40], Bl[128][40];
    int tid = threadIdx.x;
    int b = b0 + blockIdx.z;
    int i0 = blockIdx.y * 128, j0 = blockIdx.x * 128;
    const size_t fbase = (size_t)b * NPTS * CPAD;
    int lane = tid & 63, wave = tid >> 6;
    int wr = wave >> 1, wc = wave & 1;
    int fr = lane & 15, kg = lane >> 4;
    int sr = tid >> 1, sh = (tid & 1) * 16;

    f32x4 acc[4][4];
    #pragma unroll
    for (int a = 0; a < 4; a++)
        #pragma unroll
        for (int c = 0; c < 4; c++) acc[a][c] = (f32x4){0.f, 0.f, 0.f, 0.f};

    for (int k0 = 0; k0 < Kp; k0 += 32){
        __syncthreads();
        {
            const unsigned short* pAh = Fh + fbase + (size_t)(i0 + sr) * CPAD + k0 + sh;
            const unsigned short* pAl = Fl + fbase + (size_t)(i0 + sr) * CPAD + k0 + sh;
            const unsigned short* pBh = Fh + fbase + (size_t)(j0 + sr) * CPAD + k0 + sh;
            const unsigned short* pBl = Fl + fbase + (size_t)(j0 + sr) * CPAD + k0 + sh;
            uint4 t0 = *(const uint4*)pAh; uint4 t1 = *(const uint4*)(pAh + 8);
            *(uint4*)&Ah[sr][sh] = t0;    *(uint4*)&Ah[sr][sh + 8] = t1;
            uint4 t2 = *(const uint4*)pAl; uint4 t3 = *(const uint4*)(pAl + 8);
            *(uint4*)&Al[sr][sh] = t2;    *(uint4*)&Al[sr][sh + 8] = t3;
            uint4 t4 = *(const uint4*)pBh; uint4 t5 = *(const uint4*)(pBh + 8);
            *(uint4*)&Bh[sr][sh] = t4;    *(uint4*)&Bh[sr][sh + 8] = t5;
            uint4 t6 = *(const uint4*)pBl; uint4 t7 = *(const uint4*)(pBl + 8);
            *(uint4*)&Bl[sr][sh] = t6;    *(uint4*)&Bl[sr][sh + 8] = t7;
        }
        __syncthreads();
        short8 afh[4], afl[4], bfh[4], bfl[4];
        #pragma unroll
        for (int mi = 0; mi < 4; mi++){
            afh[mi] = *(const short8*)&Ah[wr * 64 + mi * 16 + fr][kg * 8];
            afl[mi] = *(const short8*)&Al[wr * 64 + mi * 16 + fr][kg * 8];
            bfh[mi] = *(const short8*)&Bh[wc * 64 + mi * 16 + fr][kg * 8];
            bfl[mi] = *(const short8*)&Bl[wc * 64 + mi * 16 + fr][kg * 8];
        }
        #pragma unroll
        for (int mi = 0; mi < 4; mi++)
            #pragma unroll
            for (int ni = 0; ni < 4; ni++){
                acc[mi][ni] = __builtin_amdgcn_mfma_f32_16x16x32_bf16(afh[mi], bfh[ni], acc[mi][ni], 0, 0, 0);
                acc[mi][ni] = __builtin_amdgcn_mfma_f32_16x16x32_bf16(afh[mi], bfl[ni], acc[mi][ni], 0, 0, 0);
                acc[mi][ni] = __builtin_amdgcn_mfma_f32_16x16x32_bf16(afl[mi], bfh[ni], acc[mi][ni], 0, 0, 0);
            }
    }
    const float* sqb = sq + (b << 11);
    float* dbase = dist + (size_t)blockIdx.z * NPTS * NPTS;
    #pragma unroll
    for (int mi = 0; mi < 4; mi++){
        #pragma unroll
        for (int r = 0; r < 4; r++){
            int i = i0 + wr * 64 + mi * 16 + kg * 4 + r;
            float si = sqb[i];
            float* dr = dbase + (size_t)i * NPTS;
            #pragma unroll
            for (int ni = 0; ni < 4; ni++){
                int j = j0 + wc * 64 + ni * 16 + fr;
                dr[j] = 2.f * acc[mi][ni][r] - si - sqb[j];
            }
        }
    }
}

// ---- approx top-NCAND per row (wave per row); tie: larger val, then smaller index ----
__global__ __launch_bounds__(256) void topk_kernel(const float* __restrict__ dist, int* __restrict__ cand,
                                                   int chunk_base){
    int lrow = blockIdx.x * 4 + (threadIdx.x >> 6);
    int lane = threadIdx.x & 63;
    const float* D = dist + (size_t)lrow * NPTS;
    float vals[32];
    #pragma unroll
    for (int t = 0; t < 32; t++) vals[t] = D[t * 64 + lane];
    int* out = cand + (size_t)(chunk_base + lrow) * NCAND;
    for (int it = 0; it < NCAND; it++){
        float bv = vals[0]; int bt = 0;
        #pragma unroll
        for (int t = 1; t < 32; t++){ if (vals[t] > bv){ bv = vals[t]; bt = t; } }
        int bcol = bt * 64 + lane;
        #pragma unroll
        for (int off = 1; off < 64; off <<= 1){
            float ov = __shfl_xor(bv, off);
            int   oc = __shfl_xor(bcol, off);
            if (ov > bv || (ov == bv && oc < bcol)){ bv = ov; bcol = oc; }
        }
        if (lane == 0) out[it] = bcol;
        #pragma unroll
        for (int q = 0; q < 32; q++){
            if (bcol == q * 64 + lane) vals[q] = -INFINITY;
        }
    }
}

// ---- FP64 re-rank of NCAND candidates -> true top-21, drop first (self) ----
// Block per row: 16 groups x 16 lanes; each group owns 2 candidates (ILP).
// d = 2*sum(fi*fj) - si - sqd[cj] with fp64 norms precomputed (sqnormd).
// 4-level group reduction. Selection by rank-compaction (strict total order:
// val desc, idx asc), keep ranks 1..K -> identical selection semantics.
__global__ __launch_bounds__(256) void refine_kernel(const float* __restrict__ F,
                                                     const double* __restrict__ sqd,
                                                     const int* __restrict__ cand,
                                                     int* __restrict__ idxo, int C){
    int row = blockIdx.x;
    int tid = threadIdx.x;
    int lane = tid & 63, wave = tid >> 6;
    int grp = tid >> 4, gl = tid & 15;
    int b = row >> 11;
    __shared__ double sval[NCAND];
    __shared__ int    sidx[NCAND];

    const float* Fi = F + (size_t)row * NF;
    double fi[21];
    #pragma unroll
    for (int q = 0; q < 21; q++){
        int c = gl + 16 * q;
        fi[q] = (c < C) ? (double)Fi[c] : 0.0;
    }
    double si = sqd[row];
    const int* cp = cand + (size_t)row * NCAND;

    #pragma unroll
    for (int jj = 0; jj < 2; jj++){
        int j = grp * 2 + jj;
        int cj = cp[j];
        const float* Fj = F + ((size_t)(b << 11) + cj) * NF;
        double t0 = 0.0, t1 = 0.0;
        #pragma unroll
        for (int q = 0; q < 21; q++){
            int c = gl + 16 * q;
            double fj = (c < C) ? (double)Fj[c] : 0.0;
            if (q & 1) t1 = fma(fi[q], fj, t1);
            else       t0 = fma(fi[q], fj, t0);
        }
        double t = t0 + t1;
        #pragma unroll
        for (int off = 1; off < 16; off <<= 1) t += __shfl_xor(t, off);
        double d = 2.0 * t - si - sqd[(b << 11) + cj];
        if (gl == 0){ sval[j] = d; sidx[j] = cj; }
    }
    __syncthreads();
    if (wave == 0){
        double v = (lane < NCAND) ? sval[lane] : -1.0e300;
        int    i = (lane < NCAND) ? sidx[lane] : 0x7fffffff;
        int cnt = 0;
        #pragma unroll
        for (int m = 0; m < NCAND; m++){
            double vm = __shfl(v, m);
            int    im = __shfl(i, m);
            if (vm > v || (vm == v && im < i)) cnt++;
        }
        if (lane < NCAND && cnt >= 1 && cnt <= K)
            idxo[(size_t)row * K + cnt - 1] = i;
    }
}

// ---- v = Wa*x, u = (Wb-Wa)*x  -> layout (b,n,o) ----
template<int O>
__global__ __launch_bounds__(256) void uv_gemm_kernel(const float* __restrict__ F, const float* __restrict__ W,
                                                      float* __restrict__ u, float* __restrict__ v, int C){
    const int G = 256 / O;
    const int ROWS = G * 8;
    __shared__ float Wa[O][17], Wd[O][17], Fl[ROWS][17];
    int tid = threadIdx.x;
    int o = tid % O, g = tid / O;
    int row0 = blockIdx.x * ROWS;
    float va[8], ua[8];
    #pragma unroll
    for (int r = 0; r < 8; r++){ va[r] = 0.f; ua[r] = 0.f; }
    for (int c0 = 0; c0 < C; c0 += 16){
        __syncthreads();
        for (int idx = tid; idx < O * 16; idx += 256){
            int oo = idx >> 4, cc = idx & 15; int c = c0 + cc;
            float wa = 0.f, wb = 0.f;
            if (c < C){ wa = W[(size_t)oo * (2 * C) + c]; wb = W[(size_t)oo * (2 * C) + C + c]; }
            Wa[oo][cc] = wa; Wd[oo][cc] = wb - wa;
        }
        for (int idx = tid; idx < ROWS * 16; idx += 256){
            int rr = idx >> 4, cc = idx & 15; int c = c0 + cc;
            Fl[rr][cc] = (c < C) ? F[(size_t)(row0 + rr) * NF + c] : 0.f;
        }
        __syncthreads();
        #pragma unroll
        for (int cc = 0; cc < 16; cc++){
            float wa = Wa[o][cc], wd = Wd[o][cc];
            #pragma unroll
            for (int r = 0; r < 8; r++){
                float f = Fl[g * 8 + r][cc];
                va[r] += wa * f; ua[r] += wd * f;
            }
        }
    }
    #pragma unroll
    for (int r = 0; r < 8; r++){
        size_t row = (size_t)row0 + g * 8 + r;
        v[row * O + o] = va[r];
        u[row * O + o] = ua[r];
    }
}

// ---- gather neighbors: per (b,n,o) max/min of v[nbr] + exact channel stats ----
template<int O>
__global__ __launch_bounds__(256) void gather_kernel(const float* __restrict__ v, const float* __restrict__ u,
                                                     const int* __restrict__ idxb, float* __restrict__ mx,
                                                     float* __restrict__ mn, float* __restrict__ ssum,
                                                     float* __restrict__ ssum2){
    const int G = 256 / O;
    int tid = threadIdx.x;
    int o = tid % O, g = tid / O;
    float csum = 0.f, csq = 0.f;
    int stride = gridDim.x * G;
    for (int row = blockIdx.x * G + g; row < NB * NPTS; row += stride){
        int b = row >> 11;
        float uv = u[(size_t)row * O + o];
        const int* ip = idxb + (size_t)row * K;
        float s1 = 0.f, s2 = 0.f, vmax = -INFINITY, vmin = INFINITY;
        for (int j = 0; j < K; j++){
            int nb = ip[j];
            float vv = v[((size_t)(b << 11) + nb) * O + o];
            s1 += vv; s2 += vv * vv;
            vmax = fmaxf(vmax, vv); vmin = fminf(vmin, vv);
        }
        mx[(size_t)row * O + o] = vmax;
        mn[(size_t)row * O + o] = vmin;
        csum += s1 + (float)K * uv;
        csq  += s2 + 2.f * uv * s1 + (float)K * uv * uv;
    }
    __shared__ float red[256];
    red[tid] = csum; __syncthreads();
    if (tid < O){ float t = 0.f; for (int gg = 0; gg < G; gg++) t += red[gg * O + tid]; atomicAdd(&ssum[tid], t); }
    __syncthreads();
    red[tid] = csq; __syncthreads();
    if (tid < O){ float t = 0.f; for (int gg = 0; gg < G; gg++) t += red[gg * O + tid]; atomicAdd(&ssum2[tid], t); }
}

__global__ void finalize_kernel(const float* __restrict__ ssum, const float* __restrict__ ssum2,
                                const float* __restrict__ gg, const float* __restrict__ bb,
                                float* __restrict__ scale, float* __restrict__ shift, int O, float inv_count){
    int o = blockIdx.x * blockDim.x + threadIdx.x;
    if (o >= O) return;
    float mean = ssum[o] * inv_count;
    float var = fmaxf(ssum2[o] * inv_count - mean * mean, 0.f);
    float sc = gg[o] * rsqrtf(var + EPSV);
    scale[o] = sc;
    shift[o] = bb[o] - mean * sc;
}

template<int O>
__global__ __launch_bounds__(256) void apply_kernel(const float* __restrict__ u, const float* __restrict__ mx,
                                                    const float* __restrict__ mn, const float* __restrict__ scale,
                                                    const float* __restrict__ shift, float* __restrict__ F,
                                                    unsigned short* __restrict__ Fh, unsigned short* __restrict__ Fl,
                                                    int coff){
    int gid = blockIdx.x * 256 + threadIdx.x;
    int row = gid / O, o = gid % O;
    float sc = scale[o];
    float sel = sc >= 0.f ? mx[gid] : mn[gid];
    float val = lrelu((u[gid] + sel) * sc + shift[o]);
    F[(size_t)row * NF + coff + o] = val;
    unsigned short h, l; split_bf(val, h, l);
    Fh[(size_t)row * CPAD + coff + o] = h;
    Fl[(size_t)row * CPAD + coff + o] = l;
}

// ---- final GEMM via bf16x3 MFMA, fused BN-stat + max/min epilogue ----
__global__ __launch_bounds__(256) void final_mfma_kernel(
    const unsigned short* __restrict__ Wh, const unsigned short* __restrict__ Wl,
    const unsigned short* __restrict__ Fh, const unsigned short* __restrict__ Fl,
    float* __restrict__ ssum, float* __restrict__ ssum2,
    unsigned* __restrict__ maxk, unsigned* __restrict__ mink)
{
    __shared__ __align__(16) unsigned short Ah[128][40], Al[128][40], Bh[128][40], Bl[128][40];
    int tid = threadIdx.x;
    int o0 = blockIdx.x * 128, n0 = blockIdx.y * 128, b = blockIdx.z;
    const size_t fbase = (size_t)b * NPTS * CPAD;
    int lane = tid & 63, wave = tid >> 6;
    int wr = wave >> 1, wc = wave & 1;
    int fr = lane & 15, kg = lane >> 4;
    int sr = tid >> 1, sh = (tid & 1) * 16;

    f32x4 acc[4][4];
    #pragma unroll
    for (int a = 0; a < 4; a++)
        #pragma unroll
        for (int c = 0; c < 4; c++) acc[a][c] = (f32x4){0.f, 0.f, 0.f, 0.f};

    for (int k0 = 0; k0 < CPAD; k0 += 32){
        __syncthreads();
        {
            const unsigned short* pAh = Wh + (size_t)(o0 + sr) * CPAD + k0 + sh;
            const unsigned short* pAl = Wl + (size_t)(o0 + sr) * CPAD + k0 + sh;
            const unsigned short* pBh = Fh + fbase + (size_t)(n0 + sr) * CPAD + k0 + sh;
            const unsigned short* pBl = Fl + fbase + (size_t)(n0 + sr) * CPAD + k0 + sh;
            uint4 t0 = *(const uint4*)pAh; uint4 t1 = *(const uint4*)(pAh + 8);
            *(uint4*)&Ah[sr][sh] = t0;    *(uint4*)&Ah[sr][sh + 8] = t1;
            uint4 t2 = *(const uint4*)pAl; uint4 t3 = *(const uint4*)(pAl + 8);
            *(uint4*)&Al[sr][sh] = t2;    *(uint4*)&Al[sr][sh + 8] = t3;
            uint4 t4 = *(const uint4*)pBh; uint4 t5 = *(const uint4*)(pBh + 8);
            *(uint4*)&Bh[sr][sh] = t4;    *(uint4*)&Bh[sr][sh + 8] = t5;
            uint4 t6 = *(const uint4*)pBl; uint4 t7 = *(const uint4*)(pBl + 8);
            *(uint4*)&Bl[sr][sh] = t6;    *(uint4*)&Bl[sr][sh + 8] = t7;
        }
        __syncthreads();
        short8 afh[4], afl[4], bfh[4], bfl[4];
        #pragma unroll
        for (int mi = 0; mi < 4; mi++){
            afh[mi] = *(const short8*)&Ah[wr * 64 + mi * 16 + fr][kg * 8];
            afl[mi] = *(const short8*)&Al[wr * 64 + mi * 16 + fr][kg * 8];
            bfh[mi] = *(const short8*)&Bh[wc * 64 + mi * 16 + fr][kg * 8];
            bfl[mi] = *(const short8*)&Bl[wc * 64 + mi * 16 + fr][kg * 8];
        }
        #pragma unroll
        for (int mi = 0; mi < 4; mi++)
            #pragma unroll
            for (int ni = 0; ni < 4; ni++){
                acc[mi][ni] = __builtin_amdgcn_mfma_f32_16x16x32_bf16(afh[mi], bfh[ni], acc[mi][ni], 0, 0, 0);
                acc[mi][ni] = __builtin_amdgcn_mfma_f32_16x16x32_bf16(afh[mi], bfl[ni], acc[mi][ni], 0, 0, 0);
                acc[mi][ni] = __builtin_amdgcn_mfma_f32_16x16x32_bf16(afl[mi], bfh[ni], acc[mi][ni], 0, 0, 0);
            }
    }
    #pragma unroll
    for (int mi = 0; mi < 4; mi++){
        #pragma unroll
        for (int r = 0; r < 4; r++){
            int o = o0 + wr * 64 + mi * 16 + kg * 4 + r;
            float s = 0.f, s2 = 0.f, mxv = -INFINITY, mnv = INFINITY;
            #pragma unroll
            for (int ni = 0; ni < 4; ni++){
                float y = acc[mi][ni][r];
                s += y; s2 += y * y;
                mxv = fmaxf(mxv, y); mnv = fminf(mnv, y);
            }
            #pragma unroll
            for (int off = 1; off < 16; off <<= 1){
                s  += __shfl_xor(s, off);
                s2 += __shfl_xor(s2, off);
                mxv = fmaxf(mxv, __shfl_xor(mxv, off));
                mnv = fminf(mnv, __shfl_xor(mnv, off));
            }
            if (fr == 0){
                atomicAdd(&ssum[o], s);
                atomicAdd(&ssum2[o], s2);
                atomicMax(&maxk[b * 1024 + o], fkey(mxv));
                atomicMin(&mink[b * 1024 + o], fkey(mnv));
            }
        }
    }
}

__global__ void final_out_kernel(const unsigned* __restrict__ maxk, const unsigned* __restrict__ mink,
                                 const float* __restrict__ ssum, const float* __restrict__ ssum2,
                                 const float* __restrict__ g5, const float* __restrict__ b5,
                                 float* __restrict__ out){
    int gid = blockIdx.x * 256 + threadIdx.x;
    if (gid >= NB * 1024) return;
    int o = gid & 1023;
    const float inv = 1.f / (NB * NPTS);
    float mean = ssum[o] * inv;
    float var = fmaxf(ssum2[o] * inv - mean * mean, 0.f);
    float sc = g5[o] * rsqrtf(var + EPSV);
    float sh = b5[o] - mean * sc;
    float sel = sc >= 0.f ? funkey(maxk[gid]) : funkey(mink[gid]);
    out[gid] = lrelu(sel * sc + sh);
}

extern "C" void kernel_launch(void* const* d_in, const int* in_sizes, int n_in,
                              void* d_out, int out_size, void* d_ws, size_t ws_size,
                              hipStream_t stream){
    (void)in_sizes; (void)n_in; (void)out_size;
    const float* x = (const float*)d_in[0];
    const float* Ws[5] = {(const float*)d_in[1], (const float*)d_in[4], (const float*)d_in[7],
                          (const float*)d_in[10], (const float*)d_in[13]};
    const float* Gs[5] = {(const float*)d_in[2], (const float*)d_in[5], (const float*)d_in[8],
                          (const float*)d_in[11], (const float*)d_in[14]};
    const float* Bs[5] = {(const float*)d_in[3], (const float*)d_in[6], (const float*)d_in[9],
                          (const float*)d_in[12], (const float*)d_in[15]};
    float* out = (float*)d_out;

    char* base = (char*)d_ws;
    size_t off = 0;
    auto alloc = [&](size_t bytes) -> char* {
        char* p = base + off;
        off = (off + bytes + 255) & ~(size_t)255;
        return p;
    };
    float*          F    = (float*)alloc((size_t)NB * NPTS * NF * 4);
    unsigned short* Fh   = (unsigned short*)alloc((size_t)NB * NPTS * CPAD * 2);
    unsigned short* Fl   = (unsigned short*)alloc((size_t)NB * NPTS * CPAD * 2);
    unsigned short* W5h  = (unsigned short*)alloc((size_t)1024 * CPAD * 2);
    unsigned short* W5l  = (unsigned short*)alloc((size_t)1024 * CPAD * 2);
    float*          sq   = (float*)alloc((size_t)NB * NPTS * 4);
    double*         sqd  = (double*)alloc((size_t)NB * NPTS * 8);
    int*            cand = (int*)  alloc((size_t)NB * NPTS * NCAND * 4);
    int*            idxb = (int*)  alloc((size_t)NB * NPTS * K * 4);
    float*          mx   = (float*)alloc((size_t)NB * NPTS * 128 * 4);
    float*          mn   = (float*)alloc((size_t)NB * NPTS * 128 * 4);
    float*          ssum = (float*)alloc(1024 * 4);
    float*          ssum2= (float*)alloc(1024 * 4);
    float*          scale= (float*)alloc(1024 * 4);
    float*          shift= (float*)alloc(1024 * 4);
    unsigned*       maxk = (unsigned*)alloc(NB * 1024 * 4);
    unsigned*       mink = (unsigned*)alloc(NB * 1024 * 4);
    // union region: dist (bz batches) overlaps u,v (used in disjoint phases)
    char* R = base + off;
    size_t avail = (ws_size > off) ? ws_size - off : 0;
    int bz = (avail >= (size_t)2 * NPTS * NPTS * 4 + 256) ? 2 : 1;
    float* dist = (float*)R;
    float* u    = (float*)R;
    float* v    = (float*)(R + (size_t)NB * NPTS * 128 * 4);

    hipMemsetAsync(Fh, 0, (size_t)NB * NPTS * CPAD * 2, stream);
    hipMemsetAsync(Fl, 0, (size_t)NB * NPTS * CPAD * 2, stream);
    copy_x_kernel<<<(NB * NPTS + 255) / 256, 256, 0, stream>>>(x, F, Fh, Fl);
    convW_kernel<<<(1024 * CPAD + 255) / 256, 256, 0, stream>>>(Ws[4], W5h, W5l);

    const int Cs[4] = {3, 67, 131, 195};
    const int Os[4] = {64, 64, 64, 128};
    for (int s = 0; s < 4; s++){
        int C = Cs[s], O = Os[s];
        int Kp = (C + 31) & ~31;
        sqnorm_kernel<<<NB * NPTS / 4, 256, 0, stream>>>(F, sq, C);
        sqnormd_kernel<<<NB * NPTS / 4, 256, 0, stream>>>(F, sqd, C);
        for (int b0 = 0; b0 < NB; b0 += bz){
            dist_mfma_kernel<<<dim3(NPTS / 128, NPTS / 128, bz), 256, 0, stream>>>(Fh, Fl, sq, dist, b0, Kp);
            topk_kernel<<<bz * NPTS / 4, 256, 0, stream>>>(dist, cand, b0 * NPTS);
        }
        refine_kernel<<<NB * NPTS, 256, 0, stream>>>(F, sqd, cand, idxb, C);
        hipMemsetAsync(ssum, 0, 1024 * 4, stream);
        hipMemsetAsync(ssum2, 0, 1024 * 4, stream);
        if (O == 64){
            uv_gemm_kernel<64><<<NB * NPTS / 32, 256, 0, stream>>>(F, Ws[s], u, v, C);
            gather_kernel<64><<<256, 256, 0, stream>>>(v, u, idxb, mx, mn, ssum, ssum2);
            finalize_kernel<<<1, 64, 0, stream>>>(ssum, ssum2, Gs[s], Bs[s], scale, shift, 64,
                                                  1.f / ((float)NB * NPTS * K));
            apply_kernel<64><<<NB * NPTS * 64 / 256, 256, 0, stream>>>(u, mx, mn, scale, shift, F, Fh, Fl, C);
        } else {
            uv_gemm_kernel<128><<<NB * NPTS / 16, 256, 0, stream>>>(F, Ws[s], u, v, C);
            gather_kernel<128><<<256, 256, 0, stream>>>(v, u, idxb, mx, mn, ssum, ssum2);
            finalize_kernel<<<1, 128, 0, stream>>>(ssum, ssum2, Gs[s], Bs[s], scale, shift, 128,
                                                   1.f / ((float)NB * NPTS * K));
            apply_kernel<128><<<NB * NPTS * 128 / 256, 256, 0, stream>>>(u, mx, mn, scale, shift, F, Fh, Fl, C);
        }
    }

    hipMemsetAsync(ssum, 0, 1024 * 4, stream);
    hipMemsetAsync(ssum2, 0, 1024 * 4, stream);
    hipMemsetAsync(maxk, 0, NB * 1024 * 4, stream);
    hipMemsetAsync(mink, 0xFF, NB * 1024 * 4, stream);
    final_mfma_kernel<<<dim3(1024 / 128, NPTS / 128, NB), 256, 0, stream>>>(W5h, W5l, Fh, Fl,
                                                                            ssum, ssum2, maxk, mink);
    final_out_kernel<<<NB * 1024 / 256, 256, 0, stream>>>(maxk, mink, ssum, ssum2, Gs[4], Bs[4], out);
}

// Round 6
// 1774.046 us; speedup vs baseline: 1.1971x; 1.1971x over previous
//
#include <hip/hip_runtime.h>
#include <math.h>

#define NB 8
#define NPTS 2048
#define NF 323
#define FSTR 328      // fp32 feature row stride (16B-aligned rows)
#define CPAD 352      // bf16 feature row stride (multiple of 32, >= 323)
#define K 20
#define EPSV 1e-5f
#define SLOPE 0.2f
#define NCAND 32      // approx candidates kept for exact re-rank (>= K+1)

typedef __attribute__((ext_vector_type(8))) short short8;
typedef __attribute__((ext_vector_type(4))) float f32x4;

__device__ __forceinline__ float lrelu(float x){ return x >= 0.f ? x : SLOPE * x; }

__device__ __forceinline__ unsigned fkey(float f){
    unsigned u = __float_as_uint(f);
    return (u & 0x80000000u) ? ~u : (u | 0x80000000u);
}
__device__ __forceinline__ float funkey(unsigned k){
    return (k & 0x80000000u) ? __uint_as_float(k ^ 0x80000000u) : __uint_as_float(~k);
}

__device__ __forceinline__ unsigned short f2bf_rne(float x){
    unsigned u = __float_as_uint(x);
    unsigned r = u + 0x7fffu + ((u >> 16) & 1u);
    return (unsigned short)(r >> 16);
}
__device__ __forceinline__ void split_bf(float x, unsigned short& h, unsigned short& l){
    h = f2bf_rne(x);
    float hf = __uint_as_float(((unsigned)h) << 16);
    l = f2bf_rne(x - hf);
}

// ---- x (B,3,N) -> F (B*N,FSTR) fp32 + Fh/Fl bf16 planes, channels [0,3) ----
__global__ void copy_x_kernel(const float* __restrict__ x, float* __restrict__ F,
                              unsigned short* __restrict__ Fh, unsigned short* __restrict__ Fl){
    int gid = blockIdx.x * 256 + threadIdx.x;
    if (gid >= NB * NPTS) return;
    int b = gid / NPTS, n = gid % NPTS;
    float* dst = F + (size_t)gid * FSTR;
    #pragma unroll
    for (int c = 0; c < 3; c++){
        float v = x[((size_t)b * 3 + c) * NPTS + n];
        dst[c] = v;
        unsigned short h, l; split_bf(v, h, l);
        Fh[(size_t)gid * CPAD + c] = h;
        Fl[(size_t)gid * CPAD + c] = l;
    }
}

// ---- per-point squared norm over first C channels (fp32, for approx dist only) ----
__global__ __launch_bounds__(256) void sqnorm_kernel(const float* __restrict__ F, float* __restrict__ sq, int C){
    int row = blockIdx.x * 4 + (threadIdx.x >> 6);
    int lane = threadIdx.x & 63;
    const float* f = F + (size_t)row * FSTR;
    float s = 0.f;
    for (int c = lane; c < C; c += 64){ float t = f[c]; s += t * t; }
    #pragma unroll
    for (int off = 32; off; off >>= 1) s += __shfl_xor(s, off);
    if (lane == 0) sq[row] = s;
}

// ---- per-point squared norm, fp64 (for exact re-rank) ----
__global__ __launch_bounds__(256) void sqnormd_kernel(const float* __restrict__ F, double* __restrict__ sqd, int C){
    int row = blockIdx.x * 4 + (threadIdx.x >> 6);
    int lane = threadIdx.x & 63;
    const float* f = F + (size_t)row * FSTR;
    double s = 0.0;
    for (int c = lane; c < C; c += 64){ double t = (double)f[c]; s = fma(t, t, s); }
    #pragma unroll
    for (int off = 32; off; off >>= 1) s += __shfl_xor(s, off);
    if (lane == 0) sqd[row] = s;
}

// ---- W5 -> bf16 hi/lo, padded to CPAD ----
__global__ void convW_kernel(const float* __restrict__ W5, unsigned short* __restrict__ Wh,
                             unsigned short* __restrict__ Wl){
    int gid = blockIdx.x * 256 + threadIdx.x;
    if (gid >= 1024 * CPAD) return;
    int o = gid / CPAD, c = gid % CPAD;
    float w = (c < NF) ? W5[(size_t)o * NF + c] : 0.f;
    unsigned short h, l; split_bf(w, h, l);
    Wh[gid] = h; Wl[gid] = l;
}

// ---- approx inv-dist Gram tile via bf16x3 MFMA: 128x128 per block, 4 waves ----
__global__ __launch_bounds__(256) void dist_mfma_kernel(
    const unsigned short* __restrict__ Fh, const unsigned short* __restrict__ Fl,
    const float* __restrict__ sq, float* __restrict__ dist, int b0, int Kp)
{
    __shared__ __align__(16) unsigned short Ah[128][40], Al[128][40], Bh[128][40], Bl[128][40];
    int tid = threadIdx.x;
    int b = b0 + blockIdx.z;
    int i0 = blockIdx.y * 128, j0 = blockIdx.x * 128;
    const size_t fbase = (size_t)b * NPTS * CPAD;
    int lane = tid & 63, wave = tid >> 6;
    int wr = wave >> 1, wc = wave & 1;
    int fr = lane & 15, kg = lane >> 4;
    int sr = tid >> 1, sh = (tid & 1) * 16;

    f32x4 acc[4][4];
    #pragma unroll
    for (int a = 0; a < 4; a++)
        #pragma unroll
        for (int c = 0; c < 4; c++) acc[a][c] = (f32x4){0.f, 0.f, 0.f, 0.f};

    for (int k0 = 0; k0 < Kp; k0 += 32){
        __syncthreads();
        {
            const unsigned short* pAh = Fh + fbase + (size_t)(i0 + sr) * CPAD + k0 + sh;
            const unsigned short* pAl = Fl + fbase + (size_t)(i0 + sr) * CPAD + k0 + sh;
            const unsigned short* pBh = Fh + fbase + (size_t)(j0 + sr) * CPAD + k0 + sh;
            const unsigned short* pBl = Fl + fbase + (size_t)(j0 + sr) * CPAD + k0 + sh;
            uint4 t0 = *(const uint4*)pAh; uint4 t1 = *(const uint4*)(pAh + 8);
            *(uint4*)&Ah[sr][sh] = t0;    *(uint4*)&Ah[sr][sh + 8] = t1;
            uint4 t2 = *(const uint4*)pAl; uint4 t3 = *(const uint4*)(pAl + 8);
            *(uint4*)&Al[sr][sh] = t2;    *(uint4*)&Al[sr][sh + 8] = t3;
            uint4 t4 = *(const uint4*)pBh; uint4 t5 = *(const uint4*)(pBh + 8);
            *(uint4*)&Bh[sr][sh] = t4;    *(uint4*)&Bh[sr][sh + 8] = t5;
            uint4 t6 = *(const uint4*)pBl; uint4 t7 = *(const uint4*)(pBl + 8);
            *(uint4*)&Bl[sr][sh] = t6;    *(uint4*)&Bl[sr][sh + 8] = t7;
        }
        __syncthreads();
        short8 afh[4], afl[4], bfh[4], bfl[4];
        #pragma unroll
        for (int mi = 0; mi < 4; mi++){
            afh[mi] = *(const short8*)&Ah[wr * 64 + mi * 16 + fr][kg * 8];
            afl[mi] = *(const short8*)&Al[wr * 64 + mi * 16 + fr][kg * 8];
            bfh[mi] = *(const short8*)&Bh[wc * 64 + mi * 16 + fr][kg * 8];
            bfl[mi] = *(const short8*)&Bl[wc * 64 + mi * 16 + fr][kg * 8];
        }
        #pragma unroll
        for (int mi = 0; mi < 4; mi++)
            #pragma unroll
            for (int ni = 0; ni < 4; ni++){
                acc[mi][ni] = __builtin_amdgcn_mfma_f32_16x16x32_bf16(afh[mi], bfh[ni], acc[mi][ni], 0, 0, 0);
                acc[mi][ni] = __builtin_amdgcn_mfma_f32_16x16x32_bf16(afh[mi], bfl[ni], acc[mi][ni], 0, 0, 0);
                acc[mi][ni] = __builtin_amdgcn_mfma_f32_16x16x32_bf16(afl[mi], bfh[ni], acc[mi][ni], 0, 0, 0);
            }
    }
    const float* sqb = sq + (b << 11);
    float* dbase = dist + (size_t)blockIdx.z * NPTS * NPTS;
    #pragma unroll
    for (int mi = 0; mi < 4; mi++){
        #pragma unroll
        for (int r = 0; r < 4; r++){
            int i = i0 + wr * 64 + mi * 16 + kg * 4 + r;
            float si = sqb[i];
            float* dr = dbase + (size_t)i * NPTS;
            #pragma unroll
            for (int ni = 0; ni < 4; ni++){
                int j = j0 + wc * 64 + ni * 16 + fr;
                dr[j] = 2.f * acc[mi][ni][r] - si - sqb[j];
            }
        }
    }
}

// ---- approx top-NCAND per row (wave per row); tie: larger val, then smaller index ----
__global__ __launch_bounds__(256) void topk_kernel(const float* __restrict__ dist, int* __restrict__ cand,
                                                   int chunk_base){
    int lrow = blockIdx.x * 4 + (threadIdx.x >> 6);
    int lane = threadIdx.x & 63;
    const float* D = dist + (size_t)lrow * NPTS;
    float vals[32];
    #pragma unroll
    for (int t = 0; t < 32; t++) vals[t] = D[t * 64 + lane];
    int* out = cand + (size_t)(chunk_base + lrow) * NCAND;
    for (int it = 0; it < NCAND; it++){
        float bv = vals[0]; int bt = 0;
        #pragma unroll
        for (int t = 1; t < 32; t++){ if (vals[t] > bv){ bv = vals[t]; bt = t; } }
        int bcol = bt * 64 + lane;
        #pragma unroll
        for (int off = 1; off < 64; off <<= 1){
            float ov = __shfl_xor(bv, off);
            int   oc = __shfl_xor(bcol, off);
            if (ov > bv || (ov == bv && oc < bcol)){ bv = ov; bcol = oc; }
        }
        if (lane == 0) out[it] = bcol;
        #pragma unroll
        for (int q = 0; q < 32; q++){
            if (bcol == q * 64 + lane) vals[q] = -INFINITY;
        }
    }
}

// ---- FP64 re-rank of NCAND candidates -> true top-21, drop first (self) ----
// Transposed: one lane per candidate (32 lanes = one row), 8 rows per block.
// Each lane accumulates the full fp64 dot over C channels in 4 independent
// partials (no cross-lane reduction). Selection by 32-wide rank compaction
// (strict total order: val desc, idx asc), keep ranks 1..K — identical
// selection semantics to rounds 3-5.
__global__ __launch_bounds__(256) void refine_kernel(const float* __restrict__ F,
                                                     const double* __restrict__ sqd,
                                                     const int* __restrict__ cand,
                                                     int* __restrict__ idxo, int C){
    int tid = threadIdx.x;
    int half = tid >> 5, cl = tid & 31;
    int row = blockIdx.x * 8 + half;
    int b = row >> 11;
    const float* Fi = F + (size_t)row * FSTR;
    int cj = cand[(size_t)row * NCAND + cl];
    const float* Fj = F + ((size_t)(b << 11) + cj) * FSTR;

    double t0 = 0.0, t1 = 0.0, t2 = 0.0, t3 = 0.0;
    int nv = C >> 2;                 // C % 4 == 3 for all stages
    for (int q = 0; q < nv; q++){
        float4 a  = *(const float4*)(Fi + q * 4);
        float4 bb = *(const float4*)(Fj + q * 4);
        t0 = fma((double)a.x, (double)bb.x, t0);
        t1 = fma((double)a.y, (double)bb.y, t1);
        t2 = fma((double)a.z, (double)bb.z, t2);
        t3 = fma((double)a.w, (double)bb.w, t3);
    }
    int c0 = nv * 4;
    t0 = fma((double)Fi[c0],     (double)Fj[c0],     t0);
    t1 = fma((double)Fi[c0 + 1], (double)Fj[c0 + 1], t1);
    t2 = fma((double)Fi[c0 + 2], (double)Fj[c0 + 2], t2);
    double t = (t0 + t1) + (t2 + t3);
    double d = 2.0 * t - sqd[row] - sqd[(b << 11) + cj];

    int cnt = 0;
    #pragma unroll
    for (int m = 0; m < NCAND; m++){
        double vm = __shfl(d, m, 32);
        int    im = __shfl(cj, m, 32);
        if (vm > d || (vm == d && im < cj)) cnt++;
    }
    if (cnt >= 1 && cnt <= K)
        idxo[(size_t)row * K + cnt - 1] = cj;
}

// ---- v = Wa*x, u = (Wb-Wa)*x  -> layout (b,n,o) ----
template<int O>
__global__ __launch_bounds__(256) void uv_gemm_kernel(const float* __restrict__ F, const float* __restrict__ W,
                                                      float* __restrict__ u, float* __restrict__ v, int C){
    const int G = 256 / O;
    const int ROWS = G * 8;
    __shared__ float Wa[O][17], Wd[O][17], Fl[ROWS][17];
    int tid = threadIdx.x;
    int o = tid % O, g = tid / O;
    int row0 = blockIdx.x * ROWS;
    float va[8], ua[8];
    #pragma unroll
    for (int r = 0; r < 8; r++){ va[r] = 0.f; ua[r] = 0.f; }
    for (int c0 = 0; c0 < C; c0 += 16){
        __syncthreads();
        for (int idx = tid; idx < O * 16; idx += 256){
            int oo = idx >> 4, cc = idx & 15; int c = c0 + cc;
            float wa = 0.f, wb = 0.f;
            if (c < C){ wa = W[(size_t)oo * (2 * C) + c]; wb = W[(size_t)oo * (2 * C) + C + c]; }
            Wa[oo][cc] = wa; Wd[oo][cc] = wb - wa;
        }
        for (int idx = tid; idx < ROWS * 16; idx += 256){
            int rr = idx >> 4, cc = idx & 15; int c = c0 + cc;
            Fl[rr][cc] = (c < C) ? F[(size_t)(row0 + rr) * FSTR + c] : 0.f;
        }
        __syncthreads();
        #pragma unroll
        for (int cc = 0; cc < 16; cc++){
            float wa = Wa[o][cc], wd = Wd[o][cc];
            #pragma unroll
            for (int r = 0; r < 8; r++){
                float f = Fl[g * 8 + r][cc];
                va[r] += wa * f; ua[r] += wd * f;
            }
        }
    }
    #pragma unroll
    for (int r = 0; r < 8; r++){
        size_t row = (size_t)row0 + g * 8 + r;
        v[row * O + o] = va[r];
        u[row * O + o] = ua[r];
    }
}

// ---- gather neighbors: per (b,n,o) max/min of v[nbr] + exact channel stats ----
template<int O>
__global__ __launch_bounds__(256) void gather_kernel(const float* __restrict__ v, const float* __restrict__ u,
                                                     const int* __restrict__ idxb, float* __restrict__ mx,
                                                     float* __restrict__ mn, float* __restrict__ ssum,
                                                     float* __restrict__ ssum2){
    const int G = 256 / O;
    int tid = threadIdx.x;
    int o = tid % O, g = tid / O;
    float csum = 0.f, csq = 0.f;
    int stride = gridDim.x * G;
    for (int row = blockIdx.x * G + g; row < NB * NPTS; row += stride){
        int b = row >> 11;
        float uv = u[(size_t)row * O + o];
        const int* ip = idxb + (size_t)row * K;
        float s1 = 0.f, s2 = 0.f, vmax = -INFINITY, vmin = INFINITY;
        for (int j = 0; j < K; j++){
            int nb = ip[j];
            float vv = v[((size_t)(b << 11) + nb) * O + o];
            s1 += vv; s2 += vv * vv;
            vmax = fmaxf(vmax, vv); vmin = fminf(vmin, vv);
        }
        mx[(size_t)row * O + o] = vmax;
        mn[(size_t)row * O + o] = vmin;
        csum += s1 + (float)K * uv;
        csq  += s2 + 2.f * uv * s1 + (float)K * uv * uv;
    }
    __shared__ float red[256];
    red[tid] = csum; __syncthreads();
    if (tid < O){ float t = 0.f; for (int gg = 0; gg < G; gg++) t += red[gg * O + tid]; atomicAdd(&ssum[tid], t); }
    __syncthreads();
    red[tid] = csq; __syncthreads();
    if (tid < O){ float t = 0.f; for (int gg = 0; gg < G; gg++) t += red[gg * O + tid]; atomicAdd(&ssum2[tid], t); }
}

__global__ void finalize_kernel(const float* __restrict__ ssum, const float* __restrict__ ssum2,
                                const float* __restrict__ gg, const float* __restrict__ bb,
                                float* __restrict__ scale, float* __restrict__ shift, int O, float inv_count){
    int o = blockIdx.x * blockDim.x + threadIdx.x;
    if (o >= O) return;
    float mean = ssum[o] * inv_count;
    float var = fmaxf(ssum2[o] * inv_count - mean * mean, 0.f);
    float sc = gg[o] * rsqrtf(var + EPSV);
    scale[o] = sc;
    shift[o] = bb[o] - mean * sc;
}

template<int O>
__global__ __launch_bounds__(256) void apply_kernel(const float* __restrict__ u, const float* __restrict__ mx,
                                                    const float* __restrict__ mn, const float* __restrict__ scale,
                                                    const float* __restrict__ shift, float* __restrict__ F,
                                                    unsigned short* __restrict__ Fh, unsigned short* __restrict__ Fl,
                                                    int coff){
    int gid = blockIdx.x * 256 + threadIdx.x;
    int row = gid / O, o = gid % O;
    float sc = scale[o];
    float sel = sc >= 0.f ? mx[gid] : mn[gid];
    float val = lrelu((u[gid] + sel) * sc + shift[o]);
    F[(size_t)row * FSTR + coff + o] = val;
    unsigned short h, l; split_bf(val, h, l);
    Fh[(size_t)row * CPAD + coff + o] = h;
    Fl[(size_t)row * CPAD + coff + o] = l;
}

// ---- final GEMM via bf16x3 MFMA, fused BN-stat + max/min epilogue ----
__global__ __launch_bounds__(256) void final_mfma_kernel(
    const unsigned short* __restrict__ Wh, const unsigned short* __restrict__ Wl,
    const unsigned short* __restrict__ Fh, const unsigned short* __restrict__ Fl,
    float* __restrict__ ssum, float* __restrict__ ssum2,
    unsigned* __restrict__ maxk, unsigned* __restrict__ mink)
{
    __shared__ __align__(16) unsigned short Ah[128][40], Al[128][40], Bh[128][40], Bl[128][40];
    int tid = threadIdx.x;
    int o0 = blockIdx.x * 128, n0 = blockIdx.y * 128, b = blockIdx.z;
    const size_t fbase = (size_t)b * NPTS * CPAD;
    int lane = tid & 63, wave = tid >> 6;
    int wr = wave >> 1, wc = wave & 1;
    int fr = lane & 15, kg = lane >> 4;
    int sr = tid >> 1, sh = (tid & 1) * 16;

    f32x4 acc[4][4];
    #pragma unroll
    for (int a = 0; a < 4; a++)
        #pragma unroll
        for (int c = 0; c < 4; c++) acc[a][c] = (f32x4){0.f, 0.f, 0.f, 0.f};

    for (int k0 = 0; k0 < CPAD; k0 += 32){
        __syncthreads();
        {
            const unsigned short* pAh = Wh + (size_t)(o0 + sr) * CPAD + k0 + sh;
            const unsigned short* pAl = Wl + (size_t)(o0 + sr) * CPAD + k0 + sh;
            const unsigned short* pBh = Fh + fbase + (size_t)(n0 + sr) * CPAD + k0 + sh;
            const unsigned short* pBl = Fl + fbase + (size_t)(n0 + sr) * CPAD + k0 + sh;
            uint4 t0 = *(const uint4*)pAh; uint4 t1 = *(const uint4*)(pAh + 8);
            *(uint4*)&Ah[sr][sh] = t0;    *(uint4*)&Ah[sr][sh + 8] = t1;
            uint4 t2 = *(const uint4*)pAl; uint4 t3 = *(const uint4*)(pAl + 8);
            *(uint4*)&Al[sr][sh] = t2;    *(uint4*)&Al[sr][sh + 8] = t3;
            uint4 t4 = *(const uint4*)pBh; uint4 t5 = *(const uint4*)(pBh + 8);
            *(uint4*)&Bh[sr][sh] = t4;    *(uint4*)&Bh[sr][sh + 8] = t5;
            uint4 t6 = *(const uint4*)pBl; uint4 t7 = *(const uint4*)(pBl + 8);
            *(uint4*)&Bl[sr][sh] = t6;    *(uint4*)&Bl[sr][sh + 8] = t7;
        }
        __syncthreads();
        short8 afh[4], afl[4], bfh[4], bfl[4];
        #pragma unroll
        for (int mi = 0; mi < 4; mi++){
            afh[mi] = *(const short8*)&Ah[wr * 64 + mi * 16 + fr][kg * 8];
            afl[mi] = *(const short8*)&Al[wr * 64 + mi * 16 + fr][kg * 8];
            bfh[mi] = *(const short8*)&Bh[wc * 64 + mi * 16 + fr][kg * 8];
            bfl[mi] = *(const short8*)&Bl[wc * 64 + mi * 16 + fr][kg * 8];
        }
        #pragma unroll
        for (int mi = 0; mi < 4; mi++)
            #pragma unroll
            for (int ni = 0; ni < 4; ni++){
                acc[mi][ni] = __builtin_amdgcn_mfma_f32_16x16x32_bf16(afh[mi], bfh[ni], acc[mi][ni], 0, 0, 0);
                acc[mi][ni] = __builtin_amdgcn_mfma_f32_16x16x32_bf16(afh[mi], bfl[ni], acc[mi][ni], 0, 0, 0);
                acc[mi][ni] = __builtin_amdgcn_mfma_f32_16x16x32_bf16(afl[mi], bfh[ni], acc[mi][ni], 0, 0, 0);
            }
    }
    #pragma unroll
    for (int mi = 0; mi < 4; mi++){
        #pragma unroll
        for (int r = 0; r < 4; r++){
            int o = o0 + wr * 64 + mi * 16 + kg * 4 + r;
            float s = 0.f, s2 = 0.f, mxv = -INFINITY, mnv = INFINITY;
            #pragma unroll
            for (int ni = 0; ni < 4; ni++){
                float y = acc[mi][ni][r];
                s += y; s2 += y * y;
                mxv = fmaxf(mxv, y); mnv = fminf(mnv, y);
            }
            #pragma unroll
            for (int off = 1; off < 16; off <<= 1){
                s  += __shfl_xor(s, off);
                s2 += __shfl_xor(s2, off);
                mxv = fmaxf(mxv, __shfl_xor(mxv, off));
                mnv = fminf(mnv, __shfl_xor(mnv, off));
            }
            if (fr == 0){
                atomicAdd(&ssum[o], s);
                atomicAdd(&ssum2[o], s2);
                atomicMax(&maxk[b * 1024 + o], fkey(mxv));
                atomicMin(&mink[b * 1024 + o], fkey(mnv));
            }
        }
    }
}

__global__ void final_out_kernel(const unsigned* __restrict__ maxk, const unsigned* __restrict__ mink,
                                 const float* __restrict__ ssum, const float* __restrict__ ssum2,
                                 const float* __restrict__ g5, const float* __restrict__ b5,
                                 float* __restrict__ out){
    int gid = blockIdx.x * 256 + threadIdx.x;
    if (gid >= NB * 1024) return;
    int o = gid & 1023;
    const float inv = 1.f / (NB * NPTS);
    float mean = ssum[o] * inv;
    float var = fmaxf(ssum2[o] * inv - mean * mean, 0.f);
    float sc = g5[o] * rsqrtf(var + EPSV);
    float sh = b5[o] - mean * sc;
    float sel = sc >= 0.f ? funkey(maxk[gid]) : funkey(mink[gid]);
    out[gid] = lrelu(sel * sc + sh);
}

extern "C" void kernel_launch(void* const* d_in, const int* in_sizes, int n_in,
                              void* d_out, int out_size, void* d_ws, size_t ws_size,
                              hipStream_t stream){
    (void)in_sizes; (void)n_in; (void)out_size;
    const float* x = (const float*)d_in[0];
    const float* Ws[5] = {(const float*)d_in[1], (const float*)d_in[4], (const float*)d_in[7],
                          (const float*)d_in[10], (const float*)d_in[13]};
    const float* Gs[5] = {(const float*)d_in[2], (const float*)d_in[5], (const float*)d_in[8],
                          (const float*)d_in[11], (const float*)d_in[14]};
    const float* Bs[5] = {(const float*)d_in[3], (const float*)d_in[6], (const float*)d_in[9],
                          (const float*)d_in[12], (const float*)d_in[15]};
    float* out = (float*)d_out;

    char* base = (char*)d_ws;
    size_t off = 0;
    auto alloc = [&](size_t bytes) -> char* {
        char* p = base + off;
        off = (off + bytes + 255) & ~(size_t)255;
        return p;
    };
    float*          F    = (float*)alloc((size_t)NB * NPTS * FSTR * 4);
    unsigned short* Fh   = (unsigned short*)alloc((size_t)NB * NPTS * CPAD * 2);
    unsigned short* Fl   = (unsigned short*)alloc((size_t)NB * NPTS * CPAD * 2);
    unsigned short* W5h  = (unsigned short*)alloc((size_t)1024 * CPAD * 2);
    unsigned short* W5l  = (unsigned short*)alloc((size_t)1024 * CPAD * 2);
    float*          sq   = (float*)alloc((size_t)NB * NPTS * 4);
    double*         sqd  = (double*)alloc((size_t)NB * NPTS * 8);
    int*            cand = (int*)  alloc((size_t)NB * NPTS * NCAND * 4);
    int*            idxb = (int*)  alloc((size_t)NB * NPTS * K * 4);
    float*          mx   = (float*)alloc((size_t)NB * NPTS * 128 * 4);
    float*          mn   = (float*)alloc((size_t)NB * NPTS * 128 * 4);
    float*          ssum = (float*)alloc(1024 * 4);
    float*          ssum2= (float*)alloc(1024 * 4);
    float*          scale= (float*)alloc(1024 * 4);
    float*          shift= (float*)alloc(1024 * 4);
    unsigned*       maxk = (unsigned*)alloc(NB * 1024 * 4);
    unsigned*       mink = (unsigned*)alloc(NB * 1024 * 4);
    // union region: dist (bz batches) overlaps u,v (used in disjoint phases)
    char* R = base + off;
    size_t avail = (ws_size > off) ? ws_size - off : 0;
    int bz = (avail >= (size_t)2 * NPTS * NPTS * 4 + 256) ? 2 : 1;
    float* dist = (float*)R;
    float* u    = (float*)R;
    float* v    = (float*)(R + (size_t)NB * NPTS * 128 * 4);

    hipMemsetAsync(Fh, 0, (size_t)NB * NPTS * CPAD * 2, stream);
    hipMemsetAsync(Fl, 0, (size_t)NB * NPTS * CPAD * 2, stream);
    copy_x_kernel<<<(NB * NPTS + 255) / 256, 256, 0, stream>>>(x, F, Fh, Fl);
    convW_kernel<<<(1024 * CPAD + 255) / 256, 256, 0, stream>>>(Ws[4], W5h, W5l);

    const int Cs[4] = {3, 67, 131, 195};
    const int Os[4] = {64, 64, 64, 128};
    for (int s = 0; s < 4; s++){
        int C = Cs[s], O = Os[s];
        int Kp = (C + 31) & ~31;
        sqnorm_kernel<<<NB * NPTS / 4, 256, 0, stream>>>(F, sq, C);
        sqnormd_kernel<<<NB * NPTS / 4, 256, 0, stream>>>(F, sqd, C);
        for (int b0 = 0; b0 < NB; b0 += bz){
            dist_mfma_kernel<<<dim3(NPTS / 128, NPTS / 128, bz), 256, 0, stream>>>(Fh, Fl, sq, dist, b0, Kp);
            topk_kernel<<<bz * NPTS / 4, 256, 0, stream>>>(dist, cand, b0 * NPTS);
        }
        refine_kernel<<<NB * NPTS / 8, 256, 0, stream>>>(F, sqd, cand, idxb, C);
        hipMemsetAsync(ssum, 0, 1024 * 4, stream);
        hipMemsetAsync(ssum2, 0, 1024 * 4, stream);
        if (O == 64){
            uv_gemm_kernel<64><<<NB * NPTS / 32, 256, 0, stream>>>(F, Ws[s], u, v, C);
            gather_kernel<64><<<256, 256, 0, stream>>>(v, u, idxb, mx, mn, ssum, ssum2);
            finalize_kernel<<<1, 64, 0, stream>>>(ssum, ssum2, Gs[s], Bs[s], scale, shift, 64,
                                                  1.f / ((float)NB * NPTS * K));
            apply_kernel<64><<<NB * NPTS * 64 / 256, 256, 0, stream>>>(u, mx, mn, scale, shift, F, Fh, Fl, C);
        } else {
            uv_gemm_kernel<128><<<NB * NPTS / 16, 256, 0, stream>>>(F, Ws[s], u, v, C);
            gather_kernel<128><<<256, 256, 0, stream>>>(v, u, idxb, mx, mn, ssum, ssum2);
            finalize_kernel<<<1, 128, 0, stream>>>(ssum, ssum2, Gs[s], Bs[s], scale, shift, 128,
                                                   1.f / ((float)NB * NPTS * K));
            apply_kernel<128><<<NB * NPTS * 128 / 256, 256, 0, stream>>>(u, mx, mn, scale, shift, F, Fh, Fl, C);
        }
    }

    hipMemsetAsync(ssum, 0, 1024 * 4, stream);
    hipMemsetAsync(ssum2, 0, 1024 * 4, stream);
    hipMemsetAsync(maxk, 0, NB * 1024 * 4, stream);
    hipMemsetAsync(mink, 0xFF, NB * 1024 * 4, stream);
    final_mfma_kernel<<<dim3(1024 / 128, NPTS / 128, NB), 256, 0, stream>>>(W5h, W5l, Fh, Fl,
                                                                            ssum, ssum2, maxk, mink);
    final_out_kernel<<<NB * 1024 / 256, 256, 0, stream>>>(maxk, mink, ssum, ssum2, Gs[4], Bs[4], out);
}

// Round 7
// 1757.992 us; speedup vs baseline: 1.2080x; 1.0091x over previous
//
#include <hip/hip_runtime.h>
#include <math.h>

#define NB 8
#define NPTS 2048
#define NF 323
#define FSTR 328      // fp32 feature row stride (16B-aligned rows)
#define CPAD 352      // bf16 feature row stride (multiple of 32, >= 323)
#define K 20
#define EPSV 1e-5f
#define SLOPE 0.2f
#define NCAND 32      // approx candidates kept for exact re-rank (>= K+1)

typedef __attribute__((ext_vector_type(8))) short short8;
typedef __attribute__((ext_vector_type(4))) float f32x4;

__device__ __forceinline__ float lrelu(float x){ return x >= 0.f ? x : SLOPE * x; }

__device__ __forceinline__ unsigned fkey(float f){
    unsigned u = __float_as_uint(f);
    return (u & 0x80000000u) ? ~u : (u | 0x80000000u);
}
__device__ __forceinline__ float funkey(unsigned k){
    return (k & 0x80000000u) ? __uint_as_float(k ^ 0x80000000u) : __uint_as_float(~k);
}

__device__ __forceinline__ unsigned short f2bf_rne(float x){
    unsigned u = __float_as_uint(x);
    unsigned r = u + 0x7fffu + ((u >> 16) & 1u);
    return (unsigned short)(r >> 16);
}
__device__ __forceinline__ void split_bf(float x, unsigned short& h, unsigned short& l){
    h = f2bf_rne(x);
    float hf = __uint_as_float(((unsigned)h) << 16);
    l = f2bf_rne(x - hf);
}

// ---- x (B,3,N) -> F (B*N,FSTR) fp32 + Fh/Fl bf16 planes, channels [0,3) ----
__global__ void copy_x_kernel(const float* __restrict__ x, float* __restrict__ F,
                              unsigned short* __restrict__ Fh, unsigned short* __restrict__ Fl){
    int gid = blockIdx.x * 256 + threadIdx.x;
    if (gid >= NB * NPTS) return;
    int b = gid / NPTS, n = gid % NPTS;
    float* dst = F + (size_t)gid * FSTR;
    #pragma unroll
    for (int c = 0; c < 3; c++){
        float v = x[((size_t)b * 3 + c) * NPTS + n];
        dst[c] = v;
        unsigned short h, l; split_bf(v, h, l);
        Fh[(size_t)gid * CPAD + c] = h;
        Fl[(size_t)gid * CPAD + c] = l;
    }
}

// ---- per-point squared norm over first C channels (fp32, for approx dist only) ----
__global__ __launch_bounds__(256) void sqnorm_kernel(const float* __restrict__ F, float* __restrict__ sq, int C){
    int row = blockIdx.x * 4 + (threadIdx.x >> 6);
    int lane = threadIdx.x & 63;
    const float* f = F + (size_t)row * FSTR;
    float s = 0.f;
    for (int c = lane; c < C; c += 64){ float t = f[c]; s += t * t; }
    #pragma unroll
    for (int off = 32; off; off >>= 1) s += __shfl_xor(s, off);
    if (lane == 0) sq[row] = s;
}

// ---- per-point squared norm, fp64 (for exact re-rank) ----
__global__ __launch_bounds__(256) void sqnormd_kernel(const float* __restrict__ F, double* __restrict__ sqd, int C){
    int row = blockIdx.x * 4 + (threadIdx.x >> 6);
    int lane = threadIdx.x & 63;
    const float* f = F + (size_t)row * FSTR;
    double s = 0.0;
    for (int c = lane; c < C; c += 64){ double t = (double)f[c]; s = fma(t, t, s); }
    #pragma unroll
    for (int off = 32; off; off >>= 1) s += __shfl_xor(s, off);
    if (lane == 0) sqd[row] = s;
}

// ---- W5 -> bf16 hi/lo, padded to CPAD ----
__global__ void convW_kernel(const float* __restrict__ W5, unsigned short* __restrict__ Wh,
                             unsigned short* __restrict__ Wl){
    int gid = blockIdx.x * 256 + threadIdx.x;
    if (gid >= 1024 * CPAD) return;
    int o = gid / CPAD, c = gid % CPAD;
    float w = (c < NF) ? W5[(size_t)o * NF + c] : 0.f;
    unsigned short h, l; split_bf(w, h, l);
    Wh[gid] = h; Wl[gid] = l;
}

// ---- approx inv-dist Gram tile via bf16x3 MFMA: 128x128 per block, 4 waves ----
__global__ __launch_bounds__(256) void dist_mfma_kernel(
    const unsigned short* __restrict__ Fh, const unsigned short* __restrict__ Fl,
    const float* __restrict__ sq, float* __restrict__ dist, int b0, int Kp)
{
    __shared__ __align__(16) unsigned short Ah[128][40], Al[128][40], Bh[128][40], Bl[128][40];
    int tid = threadIdx.x;
    int b = b0 + blockIdx.z;
    int i0 = blockIdx.y * 128, j0 = blockIdx.x * 128;
    const size_t fbase = (size_t)b * NPTS * CPAD;
    int lane = tid & 63, wave = tid >> 6;
    int wr = wave >> 1, wc = wave & 1;
    int fr = lane & 15, kg = lane >> 4;
    int sr = tid >> 1, sh = (tid & 1) * 16;

    f32x4 acc[4][4];
    #pragma unroll
    for (int a = 0; a < 4; a++)
        #pragma unroll
        for (int c = 0; c < 4; c++) acc[a][c] = (f32x4){0.f, 0.f, 0.f, 0.f};

    for (int k0 = 0; k0 < Kp; k0 += 32){
        __syncthreads();
        {
            const unsigned short* pAh = Fh + fbase + (size_t)(i0 + sr) * CPAD + k0 + sh;
            const unsigned short* pAl = Fl + fbase + (size_t)(i0 + sr) * CPAD + k0 + sh;
            const unsigned short* pBh = Fh + fbase + (size_t)(j0 + sr) * CPAD + k0 + sh;
            const unsigned short* pBl = Fl + fbase + (size_t)(j0 + sr) * CPAD + k0 + sh;
            uint4 t0 = *(const uint4*)pAh; uint4 t1 = *(const uint4*)(pAh + 8);
            *(uint4*)&Ah[sr][sh] = t0;    *(uint4*)&Ah[sr][sh + 8] = t1;
            uint4 t2 = *(const uint4*)pAl; uint4 t3 = *(const uint4*)(pAl + 8);
            *(uint4*)&Al[sr][sh] = t2;    *(uint4*)&Al[sr][sh + 8] = t3;
            uint4 t4 = *(const uint4*)pBh; uint4 t5 = *(const uint4*)(pBh + 8);
            *(uint4*)&Bh[sr][sh] = t4;    *(uint4*)&Bh[sr][sh + 8] = t5;
            uint4 t6 = *(const uint4*)pBl; uint4 t7 = *(const uint4*)(pBl + 8);
            *(uint4*)&Bl[sr][sh] = t6;    *(uint4*)&Bl[sr][sh + 8] = t7;
        }
        __syncthreads();
        short8 afh[4], afl[4], bfh[4], bfl[4];
        #pragma unroll
        for (int mi = 0; mi < 4; mi++){
            afh[mi] = *(const short8*)&Ah[wr * 64 + mi * 16 + fr][kg * 8];
            afl[mi] = *(const short8*)&Al[wr * 64 + mi * 16 + fr][kg * 8];
            bfh[mi] = *(const short8*)&Bh[wc * 64 + mi * 16 + fr][kg * 8];
            bfl[mi] = *(const short8*)&Bl[wc * 64 + mi * 16 + fr][kg * 8];
        }
        #pragma unroll
        for (int mi = 0; mi < 4; mi++)
            #pragma unroll
            for (int ni = 0; ni < 4; ni++){
                acc[mi][ni] = __builtin_amdgcn_mfma_f32_16x16x32_bf16(afh[mi], bfh[ni], acc[mi][ni], 0, 0, 0);
                acc[mi][ni] = __builtin_amdgcn_mfma_f32_16x16x32_bf16(afh[mi], bfl[ni], acc[mi][ni], 0, 0, 0);
                acc[mi][ni] = __builtin_amdgcn_mfma_f32_16x16x32_bf16(afl[mi], bfh[ni], acc[mi][ni], 0, 0, 0);
            }
    }
    const float* sqb = sq + (b << 11);
    float* dbase = dist + (size_t)blockIdx.z * NPTS * NPTS;
    #pragma unroll
    for (int mi = 0; mi < 4; mi++){
        #pragma unroll
        for (int r = 0; r < 4; r++){
            int i = i0 + wr * 64 + mi * 16 + kg * 4 + r;
            float si = sqb[i];
            float* dr = dbase + (size_t)i * NPTS;
            #pragma unroll
            for (int ni = 0; ni < 4; ni++){
                int j = j0 + wc * 64 + ni * 16 + fr;
                dr[j] = 2.f * acc[mi][ni][r] - si - sqb[j];
            }
        }
    }
}

// ---- approx top-NCAND per row (wave per row); tie: larger val, then smaller index ----
__global__ __launch_bounds__(256) void topk_kernel(const float* __restrict__ dist, int* __restrict__ cand,
                                                   int chunk_base){
    int lrow = blockIdx.x * 4 + (threadIdx.x >> 6);
    int lane = threadIdx.x & 63;
    const float* D = dist + (size_t)lrow * NPTS;
    float vals[32];
    #pragma unroll
    for (int t = 0; t < 32; t++) vals[t] = D[t * 64 + lane];
    int* out = cand + (size_t)(chunk_base + lrow) * NCAND;
    for (int it = 0; it < NCAND; it++){
        float bv = vals[0]; int bt = 0;
        #pragma unroll
        for (int t = 1; t < 32; t++){ if (vals[t] > bv){ bv = vals[t]; bt = t; } }
        int bcol = bt * 64 + lane;
        #pragma unroll
        for (int off = 1; off < 64; off <<= 1){
            float ov = __shfl_xor(bv, off);
            int   oc = __shfl_xor(bcol, off);
            if (ov > bv || (ov == bv && oc < bcol)){ bv = ov; bcol = oc; }
        }
        if (lane == 0) out[it] = bcol;
        #pragma unroll
        for (int q = 0; q < 32; q++){
            if (bcol == q * 64 + lane) vals[q] = -INFINITY;
        }
    }
}

// ---- FP64 re-rank of NCAND candidates -> true top-21, drop first (self) ----
// One lane per candidate, 8 rows per block. XCD-bijective block swizzle:
// each XCD gets 256 contiguous blocks = one batch -> candidate reads are
// L2-resident (per-XCD working set ~1.6 MB). Selection identical to r3-r6.
__global__ __launch_bounds__(256) void refine_kernel(const float* __restrict__ F,
                                                     const double* __restrict__ sqd,
                                                     const int* __restrict__ cand,
                                                     int* __restrict__ idxo, int C){
    int orig = blockIdx.x;
    int wg = (orig & 7) * (gridDim.x >> 3) + (orig >> 3);   // bijective: gridDim % 8 == 0
    int tid = threadIdx.x;
    int half = tid >> 5, cl = tid & 31;
    int row = wg * 8 + half;
    int b = row >> 11;
    const float* Fi = F + (size_t)row * FSTR;
    int cj = cand[(size_t)row * NCAND + cl];
    const float* Fj = F + ((size_t)(b << 11) + cj) * FSTR;

    double t0 = 0.0, t1 = 0.0, t2 = 0.0, t3 = 0.0;
    int nv = C >> 2;                 // C % 4 == 3 for all stages
    for (int q = 0; q < nv; q++){
        float4 a  = *(const float4*)(Fi + q * 4);
        float4 bb = *(const float4*)(Fj + q * 4);
        t0 = fma((double)a.x, (double)bb.x, t0);
        t1 = fma((double)a.y, (double)bb.y, t1);
        t2 = fma((double)a.z, (double)bb.z, t2);
        t3 = fma((double)a.w, (double)bb.w, t3);
    }
    int c0 = nv * 4;
    t0 = fma((double)Fi[c0],     (double)Fj[c0],     t0);
    t1 = fma((double)Fi[c0 + 1], (double)Fj[c0 + 1], t1);
    t2 = fma((double)Fi[c0 + 2], (double)Fj[c0 + 2], t2);
    double t = (t0 + t1) + (t2 + t3);
    double d = 2.0 * t - sqd[row] - sqd[(b << 11) + cj];

    int cnt = 0;
    #pragma unroll
    for (int m = 0; m < NCAND; m++){
        double vm = __shfl(d, m, 32);
        int    im = __shfl(cj, m, 32);
        if (vm > d || (vm == d && im < cj)) cnt++;
    }
    if (cnt >= 1 && cnt <= K)
        idxo[(size_t)row * K + cnt - 1] = cj;
}

// ---- v = Wa*x, u = (Wb-Wa)*x  -> layout (b,n,o) ----
template<int O>
__global__ __launch_bounds__(256) void uv_gemm_kernel(const float* __restrict__ F, const float* __restrict__ W,
                                                      float* __restrict__ u, float* __restrict__ v, int C){
    const int G = 256 / O;
    const int ROWS = G * 8;
    __shared__ float Wa[O][17], Wd[O][17], Fl[ROWS][17];
    int tid = threadIdx.x;
    int o = tid % O, g = tid / O;
    int row0 = blockIdx.x * ROWS;
    float va[8], ua[8];
    #pragma unroll
    for (int r = 0; r < 8; r++){ va[r] = 0.f; ua[r] = 0.f; }
    for (int c0 = 0; c0 < C; c0 += 16){
        __syncthreads();
        for (int idx = tid; idx < O * 16; idx += 256){
            int oo = idx >> 4, cc = idx & 15; int c = c0 + cc;
            float wa = 0.f, wb = 0.f;
            if (c < C){ wa = W[(size_t)oo * (2 * C) + c]; wb = W[(size_t)oo * (2 * C) + C + c]; }
            Wa[oo][cc] = wa; Wd[oo][cc] = wb - wa;
        }
        for (int idx = tid; idx < ROWS * 16; idx += 256){
            int rr = idx >> 4, cc = idx & 15; int c = c0 + cc;
            Fl[rr][cc] = (c < C) ? F[(size_t)(row0 + rr) * FSTR + c] : 0.f;
        }
        __syncthreads();
        #pragma unroll
        for (int cc = 0; cc < 16; cc++){
            float wa = Wa[o][cc], wd = Wd[o][cc];
            #pragma unroll
            for (int r = 0; r < 8; r++){
                float f = Fl[g * 8 + r][cc];
                va[r] += wa * f; ua[r] += wd * f;
            }
        }
    }
    #pragma unroll
    for (int r = 0; r < 8; r++){
        size_t row = (size_t)row0 + g * 8 + r;
        v[row * O + o] = va[r];
        u[row * O + o] = ua[r];
    }
}

// ---- gather neighbors: per (b,n,o) max/min of v[nbr] + exact channel stats ----
// Contiguous 64-row chunk per block + XCD-bijective swizzle: per-XCD v/u
// working set ~1 MB -> L2-resident neighbor gathers.
template<int O>
__global__ __launch_bounds__(256) void gather_kernel(const float* __restrict__ v, const float* __restrict__ u,
                                                     const int* __restrict__ idxb, float* __restrict__ mx,
                                                     float* __restrict__ mn, float* __restrict__ ssum,
                                                     float* __restrict__ ssum2){
    const int G = 256 / O;
    const int RPB = (NB * NPTS) / 256;   // 64 rows per block
    int orig = blockIdx.x;
    int wg = (orig & 7) * (gridDim.x >> 3) + (orig >> 3);   // gridDim = 256
    int tid = threadIdx.x;
    int o = tid % O, g = tid / O;
    float csum = 0.f, csq = 0.f;
    for (int it = 0; it < RPB / G; it++){
        int row = wg * RPB + it * G + g;
        int b = row >> 11;
        float uv = u[(size_t)row * O + o];
        const int* ip = idxb + (size_t)row * K;
        float s1 = 0.f, s2 = 0.f, vmax = -INFINITY, vmin = INFINITY;
        for (int j = 0; j < K; j++){
            int nb = ip[j];
            float vv = v[((size_t)(b << 11) + nb) * O + o];
            s1 += vv; s2 += vv * vv;
            vmax = fmaxf(vmax, vv); vmin = fminf(vmin, vv);
        }
        mx[(size_t)row * O + o] = vmax;
        mn[(size_t)row * O + o] = vmin;
        csum += s1 + (float)K * uv;
        csq  += s2 + 2.f * uv * s1 + (float)K * uv * uv;
    }
    __shared__ float red[256];
    red[tid] = csum; __syncthreads();
    if (tid < O){ float t = 0.f; for (int gg = 0; gg < G; gg++) t += red[gg * O + tid]; atomicAdd(&ssum[tid], t); }
    __syncthreads();
    red[tid] = csq; __syncthreads();
    if (tid < O){ float t = 0.f; for (int gg = 0; gg < G; gg++) t += red[gg * O + tid]; atomicAdd(&ssum2[tid], t); }
}

__global__ void finalize_kernel(const float* __restrict__ ssum, const float* __restrict__ ssum2,
                                const float* __restrict__ gg, const float* __restrict__ bb,
                                float* __restrict__ scale, float* __restrict__ shift, int O, float inv_count){
    int o = blockIdx.x * blockDim.x + threadIdx.x;
    if (o >= O) return;
    float mean = ssum[o] * inv_count;
    float var = fmaxf(ssum2[o] * inv_count - mean * mean, 0.f);
    float sc = gg[o] * rsqrtf(var + EPSV);
    scale[o] = sc;
    shift[o] = bb[o] - mean * sc;
}

template<int O>
__global__ __launch_bounds__(256) void apply_kernel(const float* __restrict__ u, const float* __restrict__ mx,
                                                    const float* __restrict__ mn, const float* __restrict__ scale,
                                                    const float* __restrict__ shift, float* __restrict__ F,
                                                    unsigned short* __restrict__ Fh, unsigned short* __restrict__ Fl,
                                                    int coff){
    int gid = blockIdx.x * 256 + threadIdx.x;
    int row = gid / O, o = gid % O;
    float sc = scale[o];
    float sel = sc >= 0.f ? mx[gid] : mn[gid];
    float val = lrelu((u[gid] + sel) * sc + shift[o]);
    F[(size_t)row * FSTR + coff + o] = val;
    unsigned short h, l; split_bf(val, h, l);
    Fh[(size_t)row * CPAD + coff + o] = h;
    Fl[(size_t)row * CPAD + coff + o] = l;
}

// ---- final GEMM via bf16x3 MFMA, fused BN-stat + max/min epilogue ----
__global__ __launch_bounds__(256) void final_mfma_kernel(
    const unsigned short* __restrict__ Wh, const unsigned short* __restrict__ Wl,
    const unsigned short* __restrict__ Fh, const unsigned short* __restrict__ Fl,
    float* __restrict__ ssum, float* __restrict__ ssum2,
    unsigned* __restrict__ maxk, unsigned* __restrict__ mink)
{
    __shared__ __align__(16) unsigned short Ah[128][40], Al[128][40], Bh[128][40], Bl[128][40];
    int tid = threadIdx.x;
    int o0 = blockIdx.x * 128, n0 = blockIdx.y * 128, b = blockIdx.z;
    const size_t fbase = (size_t)b * NPTS * CPAD;
    int lane = tid & 63, wave = tid >> 6;
    int wr = wave >> 1, wc = wave & 1;
    int fr = lane & 15, kg = lane >> 4;
    int sr = tid >> 1, sh = (tid & 1) * 16;

    f32x4 acc[4][4];
    #pragma unroll
    for (int a = 0; a < 4; a++)
        #pragma unroll
        for (int c = 0; c < 4; c++) acc[a][c] = (f32x4){0.f, 0.f, 0.f, 0.f};

    for (int k0 = 0; k0 < CPAD; k0 += 32){
        __syncthreads();
        {
            const unsigned short* pAh = Wh + (size_t)(o0 + sr) * CPAD + k0 + sh;
            const unsigned short* pAl = Wl + (size_t)(o0 + sr) * CPAD + k0 + sh;
            const unsigned short* pBh = Fh + fbase + (size_t)(n0 + sr) * CPAD + k0 + sh;
            const unsigned short* pBl = Fl + fbase + (size_t)(n0 + sr) * CPAD + k0 + sh;
            uint4 t0 = *(const uint4*)pAh; uint4 t1 = *(const uint4*)(pAh + 8);
            *(uint4*)&Ah[sr][sh] = t0;    *(uint4*)&Ah[sr][sh + 8] = t1;
            uint4 t2 = *(const uint4*)pAl; uint4 t3 = *(const uint4*)(pAl + 8);
            *(uint4*)&Al[sr][sh] = t2;    *(uint4*)&Al[sr][sh + 8] = t3;
            uint4 t4 = *(const uint4*)pBh; uint4 t5 = *(const uint4*)(pBh + 8);
            *(uint4*)&Bh[sr][sh] = t4;    *(uint4*)&Bh[sr][sh + 8] = t5;
            uint4 t6 = *(const uint4*)pBl; uint4 t7 = *(const uint4*)(pBl + 8);
            *(uint4*)&Bl[sr][sh] = t6;    *(uint4*)&Bl[sr][sh + 8] = t7;
        }
        __syncthreads();
        short8 afh[4], afl[4], bfh[4], bfl[4];
        #pragma unroll
        for (int mi = 0; mi < 4; mi++){
            afh[mi] = *(const short8*)&Ah[wr * 64 + mi * 16 + fr][kg * 8];
            afl[mi] = *(const short8*)&Al[wr * 64 + mi * 16 + fr][kg * 8];
            bfh[mi] = *(const short8*)&Bh[wc * 64 + mi * 16 + fr][kg * 8];
            bfl[mi] = *(const short8*)&Bl[wc * 64 + mi * 16 + fr][kg * 8];
        }
        #pragma unroll
        for (int mi = 0; mi < 4; mi++)
            #pragma unroll
            for (int ni = 0; ni < 4; ni++){
                acc[mi][ni] = __builtin_amdgcn_mfma_f32_16x16x32_bf16(afh[mi], bfh[ni], acc[mi][ni], 0, 0, 0);
                acc[mi][ni] = __builtin_amdgcn_mfma_f32_16x16x32_bf16(afh[mi], bfl[ni], acc[mi][ni], 0, 0, 0);
                acc[mi][ni] = __builtin_amdgcn_mfma_f32_16x16x32_bf16(afl[mi], bfh[ni], acc[mi][ni], 0, 0, 0);
            }
    }
    #pragma unroll
    for (int mi = 0; mi < 4; mi++){
        #pragma unroll
        for (int r = 0; r < 4; r++){
            int o = o0 + wr * 64 + mi * 16 + kg * 4 + r;
            float s = 0.f, s2 = 0.f, mxv = -INFINITY, mnv = INFINITY;
            #pragma unroll
            for (int ni = 0; ni < 4; ni++){
                float y = acc[mi][ni][r];
                s += y; s2 += y * y;
                mxv = fmaxf(mxv, y); mnv = fminf(mnv, y);
            }
            #pragma unroll
            for (int off = 1; off < 16; off <<= 1){
                s  += __shfl_xor(s, off);
                s2 += __shfl_xor(s2, off);
                mxv = fmaxf(mxv, __shfl_xor(mxv, off));
                mnv = fminf(mnv, __shfl_xor(mnv, off));
            }
            if (fr == 0){
                atomicAdd(&ssum[o], s);
                atomicAdd(&ssum2[o], s2);
                atomicMax(&maxk[b * 1024 + o], fkey(mxv));
                atomicMin(&mink[b * 1024 + o], fkey(mnv));
            }
        }
    }
}

__global__ void final_out_kernel(const unsigned* __restrict__ maxk, const unsigned* __restrict__ mink,
                                 const float* __restrict__ ssum, const float* __restrict__ ssum2,
                                 const float* __restrict__ g5, const float* __restrict__ b5,
                                 float* __restrict__ out){
    int gid = blockIdx.x * 256 + threadIdx.x;
    if (gid >= NB * 1024) return;
    int o = gid & 1023;
    const float inv = 1.f / (NB * NPTS);
    float mean = ssum[o] * inv;
    float var = fmaxf(ssum2[o] * inv - mean * mean, 0.f);
    float sc = g5[o] * rsqrtf(var + EPSV);
    float sh = b5[o] - mean * sc;
    float sel = sc >= 0.f ? funkey(maxk[gid]) : funkey(mink[gid]);
    out[gid] = lrelu(sel * sc + sh);
}

extern "C" void kernel_launch(void* const* d_in, const int* in_sizes, int n_in,
                              void* d_out, int out_size, void* d_ws, size_t ws_size,
                              hipStream_t stream){
    (void)in_sizes; (void)n_in; (void)out_size;
    const float* x = (const float*)d_in[0];
    const float* Ws[5] = {(const float*)d_in[1], (const float*)d_in[4], (const float*)d_in[7],
                          (const float*)d_in[10], (const float*)d_in[13]};
    const float* Gs[5] = {(const float*)d_in[2], (const float*)d_in[5], (const float*)d_in[8],
                          (const float*)d_in[11], (const float*)d_in[14]};
    const float* Bs[5] = {(const float*)d_in[3], (const float*)d_in[6], (const float*)d_in[9],
                          (const float*)d_in[12], (const float*)d_in[15]};
    float* out = (float*)d_out;

    char* base = (char*)d_ws;
    size_t off = 0;
    auto alloc = [&](size_t bytes) -> char* {
        char* p = base + off;
        off = (off + bytes + 255) & ~(size_t)255;
        return p;
    };
    float*          F    = (float*)alloc((size_t)NB * NPTS * FSTR * 4);
    unsigned short* Fh   = (unsigned short*)alloc((size_t)NB * NPTS * CPAD * 2);
    unsigned short* Fl   = (unsigned short*)alloc((size_t)NB * NPTS * CPAD * 2);
    unsigned short* W5h  = (unsigned short*)alloc((size_t)1024 * CPAD * 2);
    unsigned short* W5l  = (unsigned short*)alloc((size_t)1024 * CPAD * 2);
    float*          sq   = (float*)alloc((size_t)NB * NPTS * 4);
    double*         sqd  = (double*)alloc((size_t)NB * NPTS * 8);
    int*            cand = (int*)  alloc((size_t)NB * NPTS * NCAND * 4);
    int*            idxb = (int*)  alloc((size_t)NB * NPTS * K * 4);
    float*          mx   = (float*)alloc((size_t)NB * NPTS * 128 * 4);
    float*          mn   = (float*)alloc((size_t)NB * NPTS * 128 * 4);
    float*          ssum = (float*)alloc(1024 * 4);
    float*          ssum2= (float*)alloc(1024 * 4);
    float*          scale= (float*)alloc(1024 * 4);
    float*          shift= (float*)alloc(1024 * 4);
    unsigned*       maxk = (unsigned*)alloc(NB * 1024 * 4);
    unsigned*       mink = (unsigned*)alloc(NB * 1024 * 4);
    // union region: dist (bz batches) overlaps u,v (used in disjoint phases)
    char* R = base + off;
    size_t avail = (ws_size > off) ? ws_size - off : 0;
    int bz = (avail >= (size_t)2 * NPTS * NPTS * 4 + 256) ? 2 : 1;
    float* dist = (float*)R;
    float* u    = (float*)R;
    float* v    = (float*)(R + (size_t)NB * NPTS * 128 * 4);

    hipMemsetAsync(Fh, 0, (size_t)NB * NPTS * CPAD * 2, stream);
    hipMemsetAsync(Fl, 0, (size_t)NB * NPTS * CPAD * 2, stream);
    copy_x_kernel<<<(NB * NPTS + 255) / 256, 256, 0, stream>>>(x, F, Fh, Fl);
    convW_kernel<<<(1024 * CPAD + 255) / 256, 256, 0, stream>>>(Ws[4], W5h, W5l);

    const int Cs[4] = {3, 67, 131, 195};
    const int Os[4] = {64, 64, 64, 128};
    for (int s = 0; s < 4; s++){
        int C = Cs[s], O = Os[s];
        int Kp = (C + 31) & ~31;
        sqnorm_kernel<<<NB * NPTS / 4, 256, 0, stream>>>(F, sq, C);
        sqnormd_kernel<<<NB * NPTS / 4, 256, 0, stream>>>(F, sqd, C);
        for (int b0 = 0; b0 < NB; b0 += bz){
            dist_mfma_kernel<<<dim3(NPTS / 128, NPTS / 128, bz), 256, 0, stream>>>(Fh, Fl, sq, dist, b0, Kp);
            topk_kernel<<<bz * NPTS / 4, 256, 0, stream>>>(dist, cand, b0 * NPTS);
        }
        refine_kernel<<<NB * NPTS / 8, 256, 0, stream>>>(F, sqd, cand, idxb, C);
        hipMemsetAsync(ssum, 0, 1024 * 4, stream);
        hipMemsetAsync(ssum2, 0, 1024 * 4, stream);
        if (O == 64){
            uv_gemm_kernel<64><<<NB * NPTS / 32, 256, 0, stream>>>(F, Ws[s], u, v, C);
            gather_kernel<64><<<256, 256, 0, stream>>>(v, u, idxb, mx, mn, ssum, ssum2);
            finalize_kernel<<<1, 64, 0, stream>>>(ssum, ssum2, Gs[s], Bs[s], scale, shift, 64,
                                                  1.f / ((float)NB * NPTS * K));
            apply_kernel<64><<<NB * NPTS * 64 / 256, 256, 0, stream>>>(u, mx, mn, scale, shift, F, Fh, Fl, C);
        } else {
            uv_gemm_kernel<128><<<NB * NPTS / 16, 256, 0, stream>>>(F, Ws[s], u, v, C);
            gather_kernel<128><<<256, 256, 0, stream>>>(v, u, idxb, mx, mn, ssum, ssum2);
            finalize_kernel<<<1, 128, 0, stream>>>(ssum, ssum2, Gs[s], Bs[s], scale, shift, 128,
                                                   1.f / ((float)NB * NPTS * K));
            apply_kernel<128><<<NB * NPTS * 128 / 256, 256, 0, stream>>>(u, mx, mn, scale, shift, F, Fh, Fl, C);
        }
    }

    hipMemsetAsync(ssum, 0, 1024 * 4, stream);
    hipMemsetAsync(ssum2, 0, 1024 * 4, stream);
    hipMemsetAsync(maxk, 0, NB * 1024 * 4, stream);
    hipMemsetAsync(mink, 0xFF, NB * 1024 * 4, stream);
    final_mfma_kernel<<<dim3(1024 / 128, NPTS / 128, NB), 256, 0, stream>>>(W5h, W5l, Fh, Fl,
                                                                            ssum, ssum2, maxk, mink);
    final_out_kernel<<<NB * 1024 / 256, 256, 0, stream>>>(maxk, mink, ssum, ssum2, Gs[4], Bs[4], out);
}

// Round 8
// 1713.636 us; speedup vs baseline: 1.2393x; 1.0259x over previous
//
#include <hip/hip_runtime.h>
#include <math.h>

#define NB 8
#define NPTS 2048
#define NF 323
#define FSTR 328      // fp32 feature row stride (16B-aligned rows)
#define CPAD 352      // bf16 feature row stride (multiple of 32, >= 323)
#define K 20
#define EPSV 1e-5f
#define SLOPE 0.2f
#define NCAND 32      // approx candidates kept for exact re-rank (>= K+1)

typedef __attribute__((ext_vector_type(8))) short short8;
typedef __attribute__((ext_vector_type(4))) float f32x4;

__device__ __forceinline__ float lrelu(float x){ return x >= 0.f ? x : SLOPE * x; }

__device__ __forceinline__ unsigned fkey(float f){
    unsigned u = __float_as_uint(f);
    return (u & 0x80000000u) ? ~u : (u | 0x80000000u);
}
__device__ __forceinline__ float funkey(unsigned k){
    return (k & 0x80000000u) ? __uint_as_float(k ^ 0x80000000u) : __uint_as_float(~k);
}

__device__ __forceinline__ unsigned short f2bf_rne(float x){
    unsigned u = __float_as_uint(x);
    unsigned r = u + 0x7fffu + ((u >> 16) & 1u);
    return (unsigned short)(r >> 16);
}
__device__ __forceinline__ void split_bf(float x, unsigned short& h, unsigned short& l){
    h = f2bf_rne(x);
    float hf = __uint_as_float(((unsigned)h) << 16);
    l = f2bf_rne(x - hf);
}

// ---- x (B,3,N) -> F (B*N,FSTR) fp32 + Fh/Fl bf16 planes, channels [0,3) ----
__global__ void copy_x_kernel(const float* __restrict__ x, float* __restrict__ F,
                              unsigned short* __restrict__ Fh, unsigned short* __restrict__ Fl){
    int gid = blockIdx.x * 256 + threadIdx.x;
    if (gid >= NB * NPTS) return;
    int b = gid / NPTS, n = gid % NPTS;
    float* dst = F + (size_t)gid * FSTR;
    #pragma unroll
    for (int c = 0; c < 3; c++){
        float v = x[((size_t)b * 3 + c) * NPTS + n];
        dst[c] = v;
        unsigned short h, l; split_bf(v, h, l);
        Fh[(size_t)gid * CPAD + c] = h;
        Fl[(size_t)gid * CPAD + c] = l;
    }
}

// ---- per-point squared norm over first C channels (fp32, for approx dist only) ----
__global__ __launch_bounds__(256) void sqnorm_kernel(const float* __restrict__ F, float* __restrict__ sq, int C){
    int row = blockIdx.x * 4 + (threadIdx.x >> 6);
    int lane = threadIdx.x & 63;
    const float* f = F + (size_t)row * FSTR;
    float s = 0.f;
    for (int c = lane; c < C; c += 64){ float t = f[c]; s += t * t; }
    #pragma unroll
    for (int off = 32; off; off >>= 1) s += __shfl_xor(s, off);
    if (lane == 0) sq[row] = s;
}

// ---- per-point squared norm, fp64 (for exact re-rank) ----
__global__ __launch_bounds__(256) void sqnormd_kernel(const float* __restrict__ F, double* __restrict__ sqd, int C){
    int row = blockIdx.x * 4 + (threadIdx.x >> 6);
    int lane = threadIdx.x & 63;
    const float* f = F + (size_t)row * FSTR;
    double s = 0.0;
    for (int c = lane; c < C; c += 64){ double t = (double)f[c]; s = fma(t, t, s); }
    #pragma unroll
    for (int off = 32; off; off >>= 1) s += __shfl_xor(s, off);
    if (lane == 0) sqd[row] = s;
}

// ---- W5 -> bf16 hi/lo, padded to CPAD ----
__global__ void convW_kernel(const float* __restrict__ W5, unsigned short* __restrict__ Wh,
                             unsigned short* __restrict__ Wl){
    int gid = blockIdx.x * 256 + threadIdx.x;
    if (gid >= 1024 * CPAD) return;
    int o = gid / CPAD, c = gid % CPAD;
    float w = (c < NF) ? W5[(size_t)o * NF + c] : 0.f;
    unsigned short h, l; split_bf(w, h, l);
    Wh[gid] = h; Wl[gid] = l;
}

// ---- approx inv-dist Gram tile via bf16x3 MFMA: 128x128 per block, 4 waves ----
__global__ __launch_bounds__(256) void dist_mfma_kernel(
    const unsigned short* __restrict__ Fh, const unsigned short* __restrict__ Fl,
    const float* __restrict__ sq, float* __restrict__ dist, int b0, int Kp)
{
    __shared__ __align__(16) unsigned short Ah[128][40], Al[128][40], Bh[128][40], Bl[128][40];
    int tid = threadIdx.x;
    int b = b0 + blockIdx.z;
    int i0 = blockIdx.y * 128, j0 = blockIdx.x * 128;
    const size_t fbase = (size_t)b * NPTS * CPAD;
    int lane = tid & 63, wave = tid >> 6;
    int wr = wave >> 1, wc = wave & 1;
    int fr = lane & 15, kg = lane >> 4;
    int sr = tid >> 1, sh = (tid & 1) * 16;

    f32x4 acc[4][4];
    #pragma unroll
    for (int a = 0; a < 4; a++)
        #pragma unroll
        for (int c = 0; c < 4; c++) acc[a][c] = (f32x4){0.f, 0.f, 0.f, 0.f};

    for (int k0 = 0; k0 < Kp; k0 += 32){
        __syncthreads();
        {
            const unsigned short* pAh = Fh + fbase + (size_t)(i0 + sr) * CPAD + k0 + sh;
            const unsigned short* pAl = Fl + fbase + (size_t)(i0 + sr) * CPAD + k0 + sh;
            const unsigned short* pBh = Fh + fbase + (size_t)(j0 + sr) * CPAD + k0 + sh;
            const unsigned short* pBl = Fl + fbase + (size_t)(j0 + sr) * CPAD + k0 + sh;
            uint4 t0 = *(const uint4*)pAh; uint4 t1 = *(const uint4*)(pAh + 8);
            *(uint4*)&Ah[sr][sh] = t0;    *(uint4*)&Ah[sr][sh + 8] = t1;
            uint4 t2 = *(const uint4*)pAl; uint4 t3 = *(const uint4*)(pAl + 8);
            *(uint4*)&Al[sr][sh] = t2;    *(uint4*)&Al[sr][sh + 8] = t3;
            uint4 t4 = *(const uint4*)pBh; uint4 t5 = *(const uint4*)(pBh + 8);
            *(uint4*)&Bh[sr][sh] = t4;    *(uint4*)&Bh[sr][sh + 8] = t5;
            uint4 t6 = *(const uint4*)pBl; uint4 t7 = *(const uint4*)(pBl + 8);
            *(uint4*)&Bl[sr][sh] = t6;    *(uint4*)&Bl[sr][sh + 8] = t7;
        }
        __syncthreads();
        short8 afh[4], afl[4], bfh[4], bfl[4];
        #pragma unroll
        for (int mi = 0; mi < 4; mi++){
            afh[mi] = *(const short8*)&Ah[wr * 64 + mi * 16 + fr][kg * 8];
            afl[mi] = *(const short8*)&Al[wr * 64 + mi * 16 + fr][kg * 8];
            bfh[mi] = *(const short8*)&Bh[wc * 64 + mi * 16 + fr][kg * 8];
            bfl[mi] = *(const short8*)&Bl[wc * 64 + mi * 16 + fr][kg * 8];
        }
        #pragma unroll
        for (int mi = 0; mi < 4; mi++)
            #pragma unroll
            for (int ni = 0; ni < 4; ni++){
                acc[mi][ni] = __builtin_amdgcn_mfma_f32_16x16x32_bf16(afh[mi], bfh[ni], acc[mi][ni], 0, 0, 0);
                acc[mi][ni] = __builtin_amdgcn_mfma_f32_16x16x32_bf16(afh[mi], bfl[ni], acc[mi][ni], 0, 0, 0);
                acc[mi][ni] = __builtin_amdgcn_mfma_f32_16x16x32_bf16(afl[mi], bfh[ni], acc[mi][ni], 0, 0, 0);
            }
    }
    const float* sqb = sq + (b << 11);
    float* dbase = dist + (size_t)blockIdx.z * NPTS * NPTS;
    #pragma unroll
    for (int mi = 0; mi < 4; mi++){
        #pragma unroll
        for (int r = 0; r < 4; r++){
            int i = i0 + wr * 64 + mi * 16 + kg * 4 + r;
            float si = sqb[i];
            float* dr = dbase + (size_t)i * NPTS;
            #pragma unroll
            for (int ni = 0; ni < 4; ni++){
                int j = j0 + wc * 64 + ni * 16 + fr;
                dr[j] = 2.f * acc[mi][ni][r] - si - sqb[j];
            }
        }
    }
}

// ---- approx top-NCAND per row (wave per row); tie: larger val, then smaller index ----
__global__ __launch_bounds__(256) void topk_kernel(const float* __restrict__ dist, int* __restrict__ cand,
                                                   int chunk_base){
    int lrow = blockIdx.x * 4 + (threadIdx.x >> 6);
    int lane = threadIdx.x & 63;
    const float* D = dist + (size_t)lrow * NPTS;
    float vals[32];
    #pragma unroll
    for (int t = 0; t < 32; t++) vals[t] = D[t * 64 + lane];
    int* out = cand + (size_t)(chunk_base + lrow) * NCAND;
    for (int it = 0; it < NCAND; it++){
        float bv = vals[0]; int bt = 0;
        #pragma unroll
        for (int t = 1; t < 32; t++){ if (vals[t] > bv){ bv = vals[t]; bt = t; } }
        int bcol = bt * 64 + lane;
        #pragma unroll
        for (int off = 1; off < 64; off <<= 1){
            float ov = __shfl_xor(bv, off);
            int   oc = __shfl_xor(bcol, off);
            if (ov > bv || (ov == bv && oc < bcol)){ bv = ov; bcol = oc; }
        }
        if (lane == 0) out[it] = bcol;
        #pragma unroll
        for (int q = 0; q < 32; q++){
            if (bcol == q * 64 + lane) vals[q] = -INFINITY;
        }
    }
}

// ---- FP64 re-rank of NCAND candidates -> true top-21, drop first (self) ----
// One lane per candidate, 8 rows per block, XCD-bijective swizzle (L2-resident
// reads). C is a compile-time template parameter so the channel loop fully
// unrolls -> compiler pipelines the loads (round-7 was load-latency serial).
// Accumulation order per partial (c -> t[c%4], ascending c) is IDENTICAL to
// rounds 5-7 -> bitwise-same selection.
template<int C>
__global__ __launch_bounds__(256, 4) void refine_kernel(const float* __restrict__ F,
                                                        const double* __restrict__ sqd,
                                                        const int* __restrict__ cand,
                                                        int* __restrict__ idxo){
    int orig = blockIdx.x;
    int wg = (orig & 7) * (gridDim.x >> 3) + (orig >> 3);   // bijective: gridDim % 8 == 0
    int tid = threadIdx.x;
    int half = tid >> 5, cl = tid & 31;
    int row = wg * 8 + half;
    int b = row >> 11;
    const float* Fi = F + (size_t)row * FSTR;
    int cj = cand[(size_t)row * NCAND + cl];
    const float* Fj = F + ((size_t)(b << 11) + cj) * FSTR;

    double t0 = 0.0, t1 = 0.0, t2 = 0.0, t3 = 0.0;
    constexpr int nv = C >> 2;       // C % 4 == 3 for all stages
    #pragma unroll
    for (int q = 0; q < nv; q++){
        float4 a  = *(const float4*)(Fi + q * 4);
        float4 bb = *(const float4*)(Fj + q * 4);
        t0 = fma((double)a.x, (double)bb.x, t0);
        t1 = fma((double)a.y, (double)bb.y, t1);
        t2 = fma((double)a.z, (double)bb.z, t2);
        t3 = fma((double)a.w, (double)bb.w, t3);
    }
    constexpr int c0 = nv * 4;
    t0 = fma((double)Fi[c0],     (double)Fj[c0],     t0);
    t1 = fma((double)Fi[c0 + 1], (double)Fj[c0 + 1], t1);
    t2 = fma((double)Fi[c0 + 2], (double)Fj[c0 + 2], t2);
    double t = (t0 + t1) + (t2 + t3);
    double d = 2.0 * t - sqd[row] - sqd[(b << 11) + cj];

    int cnt = 0;
    #pragma unroll
    for (int m = 0; m < NCAND; m++){
        double vm = __shfl(d, m, 32);
        int    im = __shfl(cj, m, 32);
        if (vm > d || (vm == d && im < cj)) cnt++;
    }
    if (cnt >= 1 && cnt <= K)
        idxo[(size_t)row * K + cnt - 1] = cj;
}

// ---- v = Wa*x, u = (Wb-Wa)*x  -> layout (b,n,o) ----
template<int O>
__global__ __launch_bounds__(256) void uv_gemm_kernel(const float* __restrict__ F, const float* __restrict__ W,
                                                      float* __restrict__ u, float* __restrict__ v, int C){
    const int G = 256 / O;
    const int ROWS = G * 8;
    __shared__ float Wa[O][17], Wd[O][17], Fl[ROWS][17];
    int tid = threadIdx.x;
    int o = tid % O, g = tid / O;
    int row0 = blockIdx.x * ROWS;
    float va[8], ua[8];
    #pragma unroll
    for (int r = 0; r < 8; r++){ va[r] = 0.f; ua[r] = 0.f; }
    for (int c0 = 0; c0 < C; c0 += 16){
        __syncthreads();
        for (int idx = tid; idx < O * 16; idx += 256){
            int oo = idx >> 4, cc = idx & 15; int c = c0 + cc;
            float wa = 0.f, wb = 0.f;
            if (c < C){ wa = W[(size_t)oo * (2 * C) + c]; wb = W[(size_t)oo * (2 * C) + C + c]; }
            Wa[oo][cc] = wa; Wd[oo][cc] = wb - wa;
        }
        for (int idx = tid; idx < ROWS * 16; idx += 256){
            int rr = idx >> 4, cc = idx & 15; int c = c0 + cc;
            Fl[rr][cc] = (c < C) ? F[(size_t)(row0 + rr) * FSTR + c] : 0.f;
        }
        __syncthreads();
        #pragma unroll
        for (int cc = 0; cc < 16; cc++){
            float wa = Wa[o][cc], wd = Wd[o][cc];
            #pragma unroll
            for (int r = 0; r < 8; r++){
                float f = Fl[g * 8 + r][cc];
                va[r] += wa * f; ua[r] += wd * f;
            }
        }
    }
    #pragma unroll
    for (int r = 0; r < 8; r++){
        size_t row = (size_t)row0 + g * 8 + r;
        v[row * O + o] = va[r];
        u[row * O + o] = ua[r];
    }
}

// ---- gather neighbors: per (b,n,o) max/min of v[nbr] + exact channel stats ----
template<int O>
__global__ __launch_bounds__(256) void gather_kernel(const float* __restrict__ v, const float* __restrict__ u,
                                                     const int* __restrict__ idxb, float* __restrict__ mx,
                                                     float* __restrict__ mn, float* __restrict__ ssum,
                                                     float* __restrict__ ssum2){
    const int G = 256 / O;
    const int RPB = (NB * NPTS) / 256;   // 64 rows per block
    int orig = blockIdx.x;
    int wg = (orig & 7) * (gridDim.x >> 3) + (orig >> 3);   // gridDim = 256
    int tid = threadIdx.x;
    int o = tid % O, g = tid / O;
    float csum = 0.f, csq = 0.f;
    for (int it = 0; it < RPB / G; it++){
        int row = wg * RPB + it * G + g;
        int b = row >> 11;
        float uv = u[(size_t)row * O + o];
        const int* ip = idxb + (size_t)row * K;
        float s1 = 0.f, s2 = 0.f, vmax = -INFINITY, vmin = INFINITY;
        for (int j = 0; j < K; j++){
            int nb = ip[j];
            float vv = v[((size_t)(b << 11) + nb) * O + o];
            s1 += vv; s2 += vv * vv;
            vmax = fmaxf(vmax, vv); vmin = fminf(vmin, vv);
        }
        mx[(size_t)row * O + o] = vmax;
        mn[(size_t)row * O + o] = vmin;
        csum += s1 + (float)K * uv;
        csq  += s2 + 2.f * uv * s1 + (float)K * uv * uv;
    }
    __shared__ float red[256];
    red[tid] = csum; __syncthreads();
    if (tid < O){ float t = 0.f; for (int gg = 0; gg < G; gg++) t += red[gg * O + tid]; atomicAdd(&ssum[tid], t); }
    __syncthreads();
    red[tid] = csq; __syncthreads();
    if (tid < O){ float t = 0.f; for (int gg = 0; gg < G; gg++) t += red[gg * O + tid]; atomicAdd(&ssum2[tid], t); }
}

__global__ void finalize_kernel(const float* __restrict__ ssum, const float* __restrict__ ssum2,
                                const float* __restrict__ gg, const float* __restrict__ bb,
                                float* __restrict__ scale, float* __restrict__ shift, int O, float inv_count){
    int o = blockIdx.x * blockDim.x + threadIdx.x;
    if (o >= O) return;
    float mean = ssum[o] * inv_count;
    float var = fmaxf(ssum2[o] * inv_count - mean * mean, 0.f);
    float sc = gg[o] * rsqrtf(var + EPSV);
    scale[o] = sc;
    shift[o] = bb[o] - mean * sc;
}

template<int O>
__global__ __launch_bounds__(256) void apply_kernel(const float* __restrict__ u, const float* __restrict__ mx,
                                                    const float* __restrict__ mn, const float* __restrict__ scale,
                                                    const float* __restrict__ shift, float* __restrict__ F,
                                                    unsigned short* __restrict__ Fh, unsigned short* __restrict__ Fl,
                                                    int coff){
    int gid = blockIdx.x * 256 + threadIdx.x;
    int row = gid / O, o = gid % O;
    float sc = scale[o];
    float sel = sc >= 0.f ? mx[gid] : mn[gid];
    float val = lrelu((u[gid] + sel) * sc + shift[o]);
    F[(size_t)row * FSTR + coff + o] = val;
    unsigned short h, l; split_bf(val, h, l);
    Fh[(size_t)row * CPAD + coff + o] = h;
    Fl[(size_t)row * CPAD + coff + o] = l;
}

// ---- final GEMM via bf16x3 MFMA, fused BN-stat + max/min epilogue ----
__global__ __launch_bounds__(256) void final_mfma_kernel(
    const unsigned short* __restrict__ Wh, const unsigned short* __restrict__ Wl,
    const unsigned short* __restrict__ Fh, const unsigned short* __restrict__ Fl,
    float* __restrict__ ssum, float* __restrict__ ssum2,
    unsigned* __restrict__ maxk, unsigned* __restrict__ mink)
{
    __shared__ __align__(16) unsigned short Ah[128][40], Al[128][40], Bh[128][40], Bl[128][40];
    int tid = threadIdx.x;
    int o0 = blockIdx.x * 128, n0 = blockIdx.y * 128, b = blockIdx.z;
    const size_t fbase = (size_t)b * NPTS * CPAD;
    int lane = tid & 63, wave = tid >> 6;
    int wr = wave >> 1, wc = wave & 1;
    int fr = lane & 15, kg = lane >> 4;
    int sr = tid >> 1, sh = (tid & 1) * 16;

    f32x4 acc[4][4];
    #pragma unroll
    for (int a = 0; a < 4; a++)
        #pragma unroll
        for (int c = 0; c < 4; c++) acc[a][c] = (f32x4){0.f, 0.f, 0.f, 0.f};

    for (int k0 = 0; k0 < CPAD; k0 += 32){
        __syncthreads();
        {
            const unsigned short* pAh = Wh + (size_t)(o0 + sr) * CPAD + k0 + sh;
            const unsigned short* pAl = Wl + (size_t)(o0 + sr) * CPAD + k0 + sh;
            const unsigned short* pBh = Fh + fbase + (size_t)(n0 + sr) * CPAD + k0 + sh;
            const unsigned short* pBl = Fl + fbase + (size_t)(n0 + sr) * CPAD + k0 + sh;
            uint4 t0 = *(const uint4*)pAh; uint4 t1 = *(const uint4*)(pAh + 8);
            *(uint4*)&Ah[sr][sh] = t0;    *(uint4*)&Ah[sr][sh + 8] = t1;
            uint4 t2 = *(const uint4*)pAl; uint4 t3 = *(const uint4*)(pAl + 8);
            *(uint4*)&Al[sr][sh] = t2;    *(uint4*)&Al[sr][sh + 8] = t3;
            uint4 t4 = *(const uint4*)pBh; uint4 t5 = *(const uint4*)(pBh + 8);
            *(uint4*)&Bh[sr][sh] = t4;    *(uint4*)&Bh[sr][sh + 8] = t5;
            uint4 t6 = *(const uint4*)pBl; uint4 t7 = *(const uint4*)(pBl + 8);
            *(uint4*)&Bl[sr][sh] = t6;    *(uint4*)&Bl[sr][sh + 8] = t7;
        }
        __syncthreads();
        short8 afh[4], afl[4], bfh[4], bfl[4];
        #pragma unroll
        for (int mi = 0; mi < 4; mi++){
            afh[mi] = *(const short8*)&Ah[wr * 64 + mi * 16 + fr][kg * 8];
            afl[mi] = *(const short8*)&Al[wr * 64 + mi * 16 + fr][kg * 8];
            bfh[mi] = *(const short8*)&Bh[wc * 64 + mi * 16 + fr][kg * 8];
            bfl[mi] = *(const short8*)&Bl[wc * 64 + mi * 16 + fr][kg * 8];
        }
        #pragma unroll
        for (int mi = 0; mi < 4; mi++)
            #pragma unroll
            for (int ni = 0; ni < 4; ni++){
                acc[mi][ni] = __builtin_amdgcn_mfma_f32_16x16x32_bf16(afh[mi], bfh[ni], acc[mi][ni], 0, 0, 0);
                acc[mi][ni] = __builtin_amdgcn_mfma_f32_16x16x32_bf16(afh[mi], bfl[ni], acc[mi][ni], 0, 0, 0);
                acc[mi][ni] = __builtin_amdgcn_mfma_f32_16x16x32_bf16(afl[mi], bfh[ni], acc[mi][ni], 0, 0, 0);
            }
    }
    #pragma unroll
    for (int mi = 0; mi < 4; mi++){
        #pragma unroll
        for (int r = 0; r < 4; r++){
            int o = o0 + wr * 64 + mi * 16 + kg * 4 + r;
            float s = 0.f, s2 = 0.f, mxv = -INFINITY, mnv = INFINITY;
            #pragma unroll
            for (int ni = 0; ni < 4; ni++){
                float y = acc[mi][ni][r];
                s += y; s2 += y * y;
                mxv = fmaxf(mxv, y); mnv = fminf(mnv, y);
            }
            #pragma unroll
            for (int off = 1; off < 16; off <<= 1){
                s  += __shfl_xor(s, off);
                s2 += __shfl_xor(s2, off);
                mxv = fmaxf(mxv, __shfl_xor(mxv, off));
                mnv = fminf(mnv, __shfl_xor(mnv, off));
            }
            if (fr == 0){
                atomicAdd(&ssum[o], s);
                atomicAdd(&ssum2[o], s2);
                atomicMax(&maxk[b * 1024 + o], fkey(mxv));
                atomicMin(&mink[b * 1024 + o], fkey(mnv));
            }
        }
    }
}

__global__ void final_out_kernel(const unsigned* __restrict__ maxk, const unsigned* __restrict__ mink,
                                 const float* __restrict__ ssum, const float* __restrict__ ssum2,
                                 const float* __restrict__ g5, const float* __restrict__ b5,
                                 float* __restrict__ out){
    int gid = blockIdx.x * 256 + threadIdx.x;
    if (gid >= NB * 1024) return;
    int o = gid & 1023;
    const float inv = 1.f / (NB * NPTS);
    float mean = ssum[o] * inv;
    float var = fmaxf(ssum2[o] * inv - mean * mean, 0.f);
    float sc = g5[o] * rsqrtf(var + EPSV);
    float sh = b5[o] - mean * sc;
    float sel = sc >= 0.f ? funkey(maxk[gid]) : funkey(mink[gid]);
    out[gid] = lrelu(sel * sc + sh);
}

extern "C" void kernel_launch(void* const* d_in, const int* in_sizes, int n_in,
                              void* d_out, int out_size, void* d_ws, size_t ws_size,
                              hipStream_t stream){
    (void)in_sizes; (void)n_in; (void)out_size;
    const float* x = (const float*)d_in[0];
    const float* Ws[5] = {(const float*)d_in[1], (const float*)d_in[4], (const float*)d_in[7],
                          (const float*)d_in[10], (const float*)d_in[13]};
    const float* Gs[5] = {(const float*)d_in[2], (const float*)d_in[5], (const float*)d_in[8],
                          (const float*)d_in[11], (const float*)d_in[14]};
    const float* Bs[5] = {(const float*)d_in[3], (const float*)d_in[6], (const float*)d_in[9],
                          (const float*)d_in[12], (const float*)d_in[15]};
    float* out = (float*)d_out;

    char* base = (char*)d_ws;
    size_t off = 0;
    auto alloc = [&](size_t bytes) -> char* {
        char* p = base + off;
        off = (off + bytes + 255) & ~(size_t)255;
        return p;
    };
    float*          F    = (float*)alloc((size_t)NB * NPTS * FSTR * 4);
    unsigned short* Fh   = (unsigned short*)alloc((size_t)NB * NPTS * CPAD * 2);
    unsigned short* Fl   = (unsigned short*)alloc((size_t)NB * NPTS * CPAD * 2);
    unsigned short* W5h  = (unsigned short*)alloc((size_t)1024 * CPAD * 2);
    unsigned short* W5l  = (unsigned short*)alloc((size_t)1024 * CPAD * 2);
    float*          sq   = (float*)alloc((size_t)NB * NPTS * 4);
    double*         sqd  = (double*)alloc((size_t)NB * NPTS * 8);
    int*            cand = (int*)  alloc((size_t)NB * NPTS * NCAND * 4);
    int*            idxb = (int*)  alloc((size_t)NB * NPTS * K * 4);
    float*          mx   = (float*)alloc((size_t)NB * NPTS * 128 * 4);
    float*          mn   = (float*)alloc((size_t)NB * NPTS * 128 * 4);
    float*          ssum = (float*)alloc(1024 * 4);
    float*          ssum2= (float*)alloc(1024 * 4);
    float*          scale= (float*)alloc(1024 * 4);
    float*          shift= (float*)alloc(1024 * 4);
    unsigned*       maxk = (unsigned*)alloc(NB * 1024 * 4);
    unsigned*       mink = (unsigned*)alloc(NB * 1024 * 4);
    // union region: dist (bz batches) overlaps u,v (used in disjoint phases)
    char* R = base + off;
    size_t avail = (ws_size > off) ? ws_size - off : 0;
    int bz = (avail >= (size_t)2 * NPTS * NPTS * 4 + 256) ? 2 : 1;
    float* dist = (float*)R;
    float* u    = (float*)R;
    float* v    = (float*)(R + (size_t)NB * NPTS * 128 * 4);

    hipMemsetAsync(Fh, 0, (size_t)NB * NPTS * CPAD * 2, stream);
    hipMemsetAsync(Fl, 0, (size_t)NB * NPTS * CPAD * 2, stream);
    copy_x_kernel<<<(NB * NPTS + 255) / 256, 256, 0, stream>>>(x, F, Fh, Fl);
    convW_kernel<<<(1024 * CPAD + 255) / 256, 256, 0, stream>>>(Ws[4], W5h, W5l);

    const int Cs[4] = {3, 67, 131, 195};
    const int Os[4] = {64, 64, 64, 128};
    for (int s = 0; s < 4; s++){
        int C = Cs[s], O = Os[s];
        int Kp = (C + 31) & ~31;
        sqnorm_kernel<<<NB * NPTS / 4, 256, 0, stream>>>(F, sq, C);
        sqnormd_kernel<<<NB * NPTS / 4, 256, 0, stream>>>(F, sqd, C);
        for (int b0 = 0; b0 < NB; b0 += bz){
            dist_mfma_kernel<<<dim3(NPTS / 128, NPTS / 128, bz), 256, 0, stream>>>(Fh, Fl, sq, dist, b0, Kp);
            topk_kernel<<<bz * NPTS / 4, 256, 0, stream>>>(dist, cand, b0 * NPTS);
        }
        switch (C){
            case 3:   refine_kernel<3>  <<<NB * NPTS / 8, 256, 0, stream>>>(F, sqd, cand, idxb); break;
            case 67:  refine_kernel<67> <<<NB * NPTS / 8, 256, 0, stream>>>(F, sqd, cand, idxb); break;
            case 131: refine_kernel<131><<<NB * NPTS / 8, 256, 0, stream>>>(F, sqd, cand, idxb); break;
            default:  refine_kernel<195><<<NB * NPTS / 8, 256, 0, stream>>>(F, sqd, cand, idxb); break;
        }
        hipMemsetAsync(ssum, 0, 1024 * 4, stream);
        hipMemsetAsync(ssum2, 0, 1024 * 4, stream);
        if (O == 64){
            uv_gemm_kernel<64><<<NB * NPTS / 32, 256, 0, stream>>>(F, Ws[s], u, v, C);
            gather_kernel<64><<<256, 256, 0, stream>>>(v, u, idxb, mx, mn, ssum, ssum2);
            finalize_kernel<<<1, 64, 0, stream>>>(ssum, ssum2, Gs[s], Bs[s], scale, shift, 64,
                                                  1.f / ((float)NB * NPTS * K));
            apply_kernel<64><<<NB * NPTS * 64 / 256, 256, 0, stream>>>(u, mx, mn, scale, shift, F, Fh, Fl, C);
        } else {
            uv_gemm_kernel<128><<<NB * NPTS / 16, 256, 0, stream>>>(F, Ws[s], u, v, C);
            gather_kernel<128><<<256, 256, 0, stream>>>(v, u, idxb, mx, mn, ssum, ssum2);
            finalize_kernel<<<1, 128, 0, stream>>>(ssum, ssum2, Gs[s], Bs[s], scale, shift, 128,
                                                   1.f / ((float)NB * NPTS * K));
            apply_kernel<128><<<NB * NPTS * 128 / 256, 256, 0, stream>>>(u, mx, mn, scale, shift, F, Fh, Fl, C);
        }
    }

    hipMemsetAsync(ssum, 0, 1024 * 4, stream);
    hipMemsetAsync(ssum2, 0, 1024 * 4, stream);
    hipMemsetAsync(maxk, 0, NB * 1024 * 4, stream);
    hipMemsetAsync(mink, 0xFF, NB * 1024 * 4, stream);
    final_mfma_kernel<<<dim3(1024 / 128, NPTS / 128, NB), 256, 0, stream>>>(W5h, W5l, Fh, Fl,
                                                                            ssum, ssum2, maxk, mink);
    final_out_kernel<<<NB * 1024 / 256, 256, 0, stream>>>(maxk, mink, ssum, ssum2, Gs[4], Bs[4], out);
}

// Round 9
// 1412.337 us; speedup vs baseline: 1.5037x; 1.2133x over previous
//
#include <hip/hip_runtime.h>
#include <math.h>

#define NB 8
#define NPTS 2048
#define NF 323
#define FSTR 328      // fp32 feature row stride (16B-aligned rows)
#define CPAD 352      // bf16 feature row stride (multiple of 32, >= 323)
#define K 20
#define EPSV 1e-5f
#define SLOPE 0.2f
#define NCAND 32      // approx candidates kept for exact re-rank (>= K+1)

typedef __attribute__((ext_vector_type(8))) short short8;
typedef __attribute__((ext_vector_type(4))) float f32x4;

__device__ __forceinline__ float lrelu(float x){ return x >= 0.f ? x : SLOPE * x; }

__device__ __forceinline__ unsigned fkey(float f){
    unsigned u = __float_as_uint(f);
    return (u & 0x80000000u) ? ~u : (u | 0x80000000u);
}
__device__ __forceinline__ float funkey(unsigned k){
    return (k & 0x80000000u) ? __uint_as_float(k ^ 0x80000000u) : __uint_as_float(~k);
}

__device__ __forceinline__ unsigned short f2bf_rne(float x){
    unsigned u = __float_as_uint(x);
    unsigned r = u + 0x7fffu + ((u >> 16) & 1u);
    return (unsigned short)(r >> 16);
}
__device__ __forceinline__ void split_bf(float x, unsigned short& h, unsigned short& l){
    h = f2bf_rne(x);
    float hf = __uint_as_float(((unsigned)h) << 16);
    l = f2bf_rne(x - hf);
}

// ---- x (B,3,N) -> F (B*N,FSTR) fp32 + Fh/Fl bf16 planes, channels [0,3) ----
__global__ void copy_x_kernel(const float* __restrict__ x, float* __restrict__ F,
                              unsigned short* __restrict__ Fh, unsigned short* __restrict__ Fl){
    int gid = blockIdx.x * 256 + threadIdx.x;
    if (gid >= NB * NPTS) return;
    int b = gid / NPTS, n = gid % NPTS;
    float* dst = F + (size_t)gid * FSTR;
    #pragma unroll
    for (int c = 0; c < 3; c++){
        float v = x[((size_t)b * 3 + c) * NPTS + n];
        dst[c] = v;
        unsigned short h, l; split_bf(v, h, l);
        Fh[(size_t)gid * CPAD + c] = h;
        Fl[(size_t)gid * CPAD + c] = l;
    }
}

// ---- per-point squared norms: fp32 (approx dist) + fp64 (exact re-rank), fused ----
// Per-lane expressions/order identical to the former separate kernels.
__global__ __launch_bounds__(256) void sqnorm2_kernel(const float* __restrict__ F, float* __restrict__ sq,
                                                      double* __restrict__ sqd, int C){
    int row = blockIdx.x * 4 + (threadIdx.x >> 6);
    int lane = threadIdx.x & 63;
    const float* f = F + (size_t)row * FSTR;
    float s = 0.f;
    double sd = 0.0;
    for (int c = lane; c < C; c += 64){
        float t = f[c];
        s += t * t;
        double td = (double)t;
        sd = fma(td, td, sd);
    }
    #pragma unroll
    for (int off = 32; off; off >>= 1) s += __shfl_xor(s, off);
    #pragma unroll
    for (int off = 32; off; off >>= 1) sd += __shfl_xor(sd, off);
    if (lane == 0){ sq[row] = s; sqd[row] = sd; }
}

// ---- W5 -> bf16 hi/lo, padded to CPAD ----
__global__ void convW_kernel(const float* __restrict__ W5, unsigned short* __restrict__ Wh,
                             unsigned short* __restrict__ Wl){
    int gid = blockIdx.x * 256 + threadIdx.x;
    if (gid >= 1024 * CPAD) return;
    int o = gid / CPAD, c = gid % CPAD;
    float w = (c < NF) ? W5[(size_t)o * NF + c] : 0.f;
    unsigned short h, l; split_bf(w, h, l);
    Wh[gid] = h; Wl[gid] = l;
}

// ---- approx inv-dist Gram tile via bf16x3 MFMA: 128x128 per block, 4 waves ----
__global__ __launch_bounds__(256) void dist_mfma_kernel(
    const unsigned short* __restrict__ Fh, const unsigned short* __restrict__ Fl,
    const float* __restrict__ sq, float* __restrict__ dist, int b0, int Kp)
{
    __shared__ __align__(16) unsigned short Ah[128][40], Al[128][40], Bh[128][40], Bl[128][40];
    int tid = threadIdx.x;
    int b = b0 + blockIdx.z;
    int i0 = blockIdx.y * 128, j0 = blockIdx.x * 128;
    const size_t fbase = (size_t)b * NPTS * CPAD;
    int lane = tid & 63, wave = tid >> 6;
    int wr = wave >> 1, wc = wave & 1;
    int fr = lane & 15, kg = lane >> 4;
    int sr = tid >> 1, sh = (tid & 1) * 16;

    f32x4 acc[4][4];
    #pragma unroll
    for (int a = 0; a < 4; a++)
        #pragma unroll
        for (int c = 0; c < 4; c++) acc[a][c] = (f32x4){0.f, 0.f, 0.f, 0.f};

    for (int k0 = 0; k0 < Kp; k0 += 32){
        __syncthreads();
        {
            const unsigned short* pAh = Fh + fbase + (size_t)(i0 + sr) * CPAD + k0 + sh;
            const unsigned short* pAl = Fl + fbase + (size_t)(i0 + sr) * CPAD + k0 + sh;
            const unsigned short* pBh = Fh + fbase + (size_t)(j0 + sr) * CPAD + k0 + sh;
            const unsigned short* pBl = Fl + fbase + (size_t)(j0 + sr) * CPAD + k0 + sh;
            uint4 t0 = *(const uint4*)pAh; uint4 t1 = *(const uint4*)(pAh + 8);
            *(uint4*)&Ah[sr][sh] = t0;    *(uint4*)&Ah[sr][sh + 8] = t1;
            uint4 t2 = *(const uint4*)pAl; uint4 t3 = *(const uint4*)(pAl + 8);
            *(uint4*)&Al[sr][sh] = t2;    *(uint4*)&Al[sr][sh + 8] = t3;
            uint4 t4 = *(const uint4*)pBh; uint4 t5 = *(const uint4*)(pBh + 8);
            *(uint4*)&Bh[sr][sh] = t4;    *(uint4*)&Bh[sr][sh + 8] = t5;
            uint4 t6 = *(const uint4*)pBl; uint4 t7 = *(const uint4*)(pBl + 8);
            *(uint4*)&Bl[sr][sh] = t6;    *(uint4*)&Bl[sr][sh + 8] = t7;
        }
        __syncthreads();
        short8 afh[4], afl[4], bfh[4], bfl[4];
        #pragma unroll
        for (int mi = 0; mi < 4; mi++){
            afh[mi] = *(const short8*)&Ah[wr * 64 + mi * 16 + fr][kg * 8];
            afl[mi] = *(const short8*)&Al[wr * 64 + mi * 16 + fr][kg * 8];
            bfh[mi] = *(const short8*)&Bh[wc * 64 + mi * 16 + fr][kg * 8];
            bfl[mi] = *(const short8*)&Bl[wc * 64 + mi * 16 + fr][kg * 8];
        }
        #pragma unroll
        for (int mi = 0; mi < 4; mi++)
            #pragma unroll
            for (int ni = 0; ni < 4; ni++){
                acc[mi][ni] = __builtin_amdgcn_mfma_f32_16x16x32_bf16(afh[mi], bfh[ni], acc[mi][ni], 0, 0, 0);
                acc[mi][ni] = __builtin_amdgcn_mfma_f32_16x16x32_bf16(afh[mi], bfl[ni], acc[mi][ni], 0, 0, 0);
                acc[mi][ni] = __builtin_amdgcn_mfma_f32_16x16x32_bf16(afl[mi], bfh[ni], acc[mi][ni], 0, 0, 0);
            }
    }
    const float* sqb = sq + (b << 11);
    float* dbase = dist + (size_t)blockIdx.z * NPTS * NPTS;
    #pragma unroll
    for (int mi = 0; mi < 4; mi++){
        #pragma unroll
        for (int r = 0; r < 4; r++){
            int i = i0 + wr * 64 + mi * 16 + kg * 4 + r;
            float si = sqb[i];
            float* dr = dbase + (size_t)i * NPTS;
            #pragma unroll
            for (int ni = 0; ni < 4; ni++){
                int j = j0 + wc * 64 + ni * 16 + fr;
                dr[j] = 2.f * acc[mi][ni][r] - si - sqb[j];
            }
        }
    }
}

// ---- approx top-NCAND per row (wave per row); tie: larger val, then smaller index ----
__global__ __launch_bounds__(256) void topk_kernel(const float* __restrict__ dist, int* __restrict__ cand,
                                                   int chunk_base){
    int lrow = blockIdx.x * 4 + (threadIdx.x >> 6);
    int lane = threadIdx.x & 63;
    const float* D = dist + (size_t)lrow * NPTS;
    float vals[32];
    #pragma unroll
    for (int t = 0; t < 32; t++) vals[t] = D[t * 64 + lane];
    int* out = cand + (size_t)(chunk_base + lrow) * NCAND;
    for (int it = 0; it < NCAND; it++){
        float bv = vals[0]; int bt = 0;
        #pragma unroll
        for (int t = 1; t < 32; t++){ if (vals[t] > bv){ bv = vals[t]; bt = t; } }
        int bcol = bt * 64 + lane;
        #pragma unroll
        for (int off = 1; off < 64; off <<= 1){
            float ov = __shfl_xor(bv, off);
            int   oc = __shfl_xor(bcol, off);
            if (ov > bv || (ov == bv && oc < bcol)){ bv = ov; bcol = oc; }
        }
        if (lane == 0) out[it] = bcol;
        #pragma unroll
        for (int q = 0; q < 32; q++){
            if (bcol == q * 64 + lane) vals[q] = -INFINITY;
        }
    }
}

// ---- FP64 re-rank of NCAND candidates -> true top-21, drop first (self) ----
// One lane per candidate, 8 rows per block, XCD-bijective swizzle, template-C
// full unroll. Accumulation order identical to rounds 5-8 -> bitwise-same.
template<int C>
__global__ __launch_bounds__(256, 4) void refine_kernel(const float* __restrict__ F,
                                                        const double* __restrict__ sqd,
                                                        const int* __restrict__ cand,
                                                        int* __restrict__ idxo){
    int orig = blockIdx.x;
    int wg = (orig & 7) * (gridDim.x >> 3) + (orig >> 3);   // bijective: gridDim % 8 == 0
    int tid = threadIdx.x;
    int half = tid >> 5, cl = tid & 31;
    int row = wg * 8 + half;
    int b = row >> 11;
    const float* Fi = F + (size_t)row * FSTR;
    int cj = cand[(size_t)row * NCAND + cl];
    const float* Fj = F + ((size_t)(b << 11) + cj) * FSTR;

    double t0 = 0.0, t1 = 0.0, t2 = 0.0, t3 = 0.0;
    constexpr int nv = C >> 2;       // C % 4 == 3 for all stages
    #pragma unroll
    for (int q = 0; q < nv; q++){
        float4 a  = *(const float4*)(Fi + q * 4);
        float4 bb = *(const float4*)(Fj + q * 4);
        t0 = fma((double)a.x, (double)bb.x, t0);
        t1 = fma((double)a.y, (double)bb.y, t1);
        t2 = fma((double)a.z, (double)bb.z, t2);
        t3 = fma((double)a.w, (double)bb.w, t3);
    }
    constexpr int c0 = nv * 4;
    t0 = fma((double)Fi[c0],     (double)Fj[c0],     t0);
    t1 = fma((double)Fi[c0 + 1], (double)Fj[c0 + 1], t1);
    t2 = fma((double)Fi[c0 + 2], (double)Fj[c0 + 2], t2);
    double t = (t0 + t1) + (t2 + t3);
    double d = 2.0 * t - sqd[row] - sqd[(b << 11) + cj];

    int cnt = 0;
    #pragma unroll
    for (int m = 0; m < NCAND; m++){
        double vm = __shfl(d, m, 32);
        int    im = __shfl(cj, m, 32);
        if (vm > d || (vm == d && im < cj)) cnt++;
    }
    if (cnt >= 1 && cnt <= K)
        idxo[(size_t)row * K + cnt - 1] = cj;
}

// ---- v = Wa*x, u = (Wb-Wa)*x -> layout (b,n,o). 4 rows/group (occupancy) ----
// Per-(row,o) accumulation order over c unchanged -> bitwise-identical u,v.
template<int O>
__global__ __launch_bounds__(256) void uv_gemm_kernel(const float* __restrict__ F, const float* __restrict__ W,
                                                      float* __restrict__ u, float* __restrict__ v, int C){
    const int G = 256 / O;
    const int R = 4;
    const int ROWS = G * R;
    __shared__ float Wa[O][17], Wd[O][17], Fl[ROWS][17];
    int tid = threadIdx.x;
    int o = tid % O, g = tid / O;
    int row0 = blockIdx.x * ROWS;
    float va[R], ua[R];
    #pragma unroll
    for (int r = 0; r < R; r++){ va[r] = 0.f; ua[r] = 0.f; }
    for (int c0 = 0; c0 < C; c0 += 16){
        __syncthreads();
        for (int idx = tid; idx < O * 16; idx += 256){
            int oo = idx >> 4, cc = idx & 15; int c = c0 + cc;
            float wa = 0.f, wb = 0.f;
            if (c < C){ wa = W[(size_t)oo * (2 * C) + c]; wb = W[(size_t)oo * (2 * C) + C + c]; }
            Wa[oo][cc] = wa; Wd[oo][cc] = wb - wa;
        }
        for (int idx = tid; idx < ROWS * 16; idx += 256){
            int rr = idx >> 4, cc = idx & 15; int c = c0 + cc;
            Fl[rr][cc] = (c < C) ? F[(size_t)(row0 + rr) * FSTR + c] : 0.f;
        }
        __syncthreads();
        #pragma unroll
        for (int cc = 0; cc < 16; cc++){
            float wa = Wa[o][cc], wd = Wd[o][cc];
            #pragma unroll
            for (int r = 0; r < R; r++){
                float f = Fl[g * R + r][cc];
                va[r] += wa * f; ua[r] += wd * f;
            }
        }
    }
    #pragma unroll
    for (int r = 0; r < R; r++){
        size_t row = (size_t)row0 + g * R + r;
        v[row * O + o] = va[r];
        u[row * O + o] = ua[r];
    }
}

// ---- gather neighbors: per (b,n,o) max/min of v[nbr] + exact channel stats ----
template<int O>
__global__ __launch_bounds__(256) void gather_kernel(const float* __restrict__ v, const float* __restrict__ u,
                                                     const int* __restrict__ idxb, float* __restrict__ mx,
                                                     float* __restrict__ mn, float* __restrict__ ssum,
                                                     float* __restrict__ ssum2){
    const int G = 256 / O;
    const int RPB = (NB * NPTS) / 256;   // 64 rows per block
    int orig = blockIdx.x;
    int wg = (orig & 7) * (gridDim.x >> 3) + (orig >> 3);   // gridDim = 256
    int tid = threadIdx.x;
    int o = tid % O, g = tid / O;
    float csum = 0.f, csq = 0.f;
    for (int it = 0; it < RPB / G; it++){
        int row = wg * RPB + it * G + g;
        int b = row >> 11;
        float uv = u[(size_t)row * O + o];
        const int* ip = idxb + (size_t)row * K;
        float s1 = 0.f, s2 = 0.f, vmax = -INFINITY, vmin = INFINITY;
        for (int j = 0; j < K; j++){
            int nb = ip[j];
            float vv = v[((size_t)(b << 11) + nb) * O + o];
            s1 += vv; s2 += vv * vv;
            vmax = fmaxf(vmax, vv); vmin = fminf(vmin, vv);
        }
        mx[(size_t)row * O + o] = vmax;
        mn[(size_t)row * O + o] = vmin;
        csum += s1 + (float)K * uv;
        csq  += s2 + 2.f * uv * s1 + (float)K * uv * uv;
    }
    __shared__ float red[256];
    red[tid] = csum; __syncthreads();
    if (tid < O){ float t = 0.f; for (int gg = 0; gg < G; gg++) t += red[gg * O + tid]; atomicAdd(&ssum[tid], t); }
    __syncthreads();
    red[tid] = csq; __syncthreads();
    if (tid < O){ float t = 0.f; for (int gg = 0; gg < G; gg++) t += red[gg * O + tid]; atomicAdd(&ssum2[tid], t); }
}

__global__ void finalize_kernel(const float* __restrict__ ssum, const float* __restrict__ ssum2,
                                const float* __restrict__ gg, const float* __restrict__ bb,
                                float* __restrict__ scale, float* __restrict__ shift, int O, float inv_count){
    int o = blockIdx.x * blockDim.x + threadIdx.x;
    if (o >= O) return;
    float mean = ssum[o] * inv_count;
    float var = fmaxf(ssum2[o] * inv_count - mean * mean, 0.f);
    float sc = gg[o] * rsqrtf(var + EPSV);
    scale[o] = sc;
    shift[o] = bb[o] - mean * sc;
}

template<int O>
__global__ __launch_bounds__(256) void apply_kernel(const float* __restrict__ u, const float* __restrict__ mx,
                                                    const float* __restrict__ mn, const float* __restrict__ scale,
                                                    const float* __restrict__ shift, float* __restrict__ F,
                                                    unsigned short* __restrict__ Fh, unsigned short* __restrict__ Fl,
                                                    int coff){
    int gid = blockIdx.x * 256 + threadIdx.x;
    int row = gid / O, o = gid % O;
    float sc = scale[o];
    float sel = sc >= 0.f ? mx[gid] : mn[gid];
    float val = lrelu((u[gid] + sel) * sc + shift[o]);
    F[(size_t)row * FSTR + coff + o] = val;
    unsigned short h, l; split_bf(val, h, l);
    Fh[(size_t)row * CPAD + coff + o] = h;
    Fl[(size_t)row * CPAD + coff + o] = l;
}

// ---- final GEMM via bf16x3 MFMA, fused BN-stat + max/min epilogue ----
__global__ __launch_bounds__(256) void final_mfma_kernel(
    const unsigned short* __restrict__ Wh, const unsigned short* __restrict__ Wl,
    const unsigned short* __restrict__ Fh, const unsigned short* __restrict__ Fl,
    float* __restrict__ ssum, float* __restrict__ ssum2,
    unsigned* __restrict__ maxk, unsigned* __restrict__ mink)
{
    __shared__ __align__(16) unsigned short Ah[128][40], Al[128][40], Bh[128][40], Bl[128][40];
    int tid = threadIdx.x;
    int o0 = blockIdx.x * 128, n0 = blockIdx.y * 128, b = blockIdx.z;
    const size_t fbase = (size_t)b * NPTS * CPAD;
    int lane = tid & 63, wave = tid >> 6;
    int wr = wave >> 1, wc = wave & 1;
    int fr = lane & 15, kg = lane >> 4;
    int sr = tid >> 1, sh = (tid & 1) * 16;

    f32x4 acc[4][4];
    #pragma unroll
    for (int a = 0; a < 4; a++)
        #pragma unroll
        for (int c = 0; c < 4; c++) acc[a][c] = (f32x4){0.f, 0.f, 0.f, 0.f};

    for (int k0 = 0; k0 < CPAD; k0 += 32){
        __syncthreads();
        {
            const unsigned short* pAh = Wh + (size_t)(o0 + sr) * CPAD + k0 + sh;
            const unsigned short* pAl = Wl + (size_t)(o0 + sr) * CPAD + k0 + sh;
            const unsigned short* pBh = Fh + fbase + (size_t)(n0 + sr) * CPAD + k0 + sh;
            const unsigned short* pBl = Fl + fbase + (size_t)(n0 + sr) * CPAD + k0 + sh;
            uint4 t0 = *(const uint4*)pAh; uint4 t1 = *(const uint4*)(pAh + 8);
            *(uint4*)&Ah[sr][sh] = t0;    *(uint4*)&Ah[sr][sh + 8] = t1;
            uint4 t2 = *(const uint4*)pAl; uint4 t3 = *(const uint4*)(pAl + 8);
            *(uint4*)&Al[sr][sh] = t2;    *(uint4*)&Al[sr][sh + 8] = t3;
            uint4 t4 = *(const uint4*)pBh; uint4 t5 = *(const uint4*)(pBh + 8);
            *(uint4*)&Bh[sr][sh] = t4;    *(uint4*)&Bh[sr][sh + 8] = t5;
            uint4 t6 = *(const uint4*)pBl; uint4 t7 = *(const uint4*)(pBl + 8);
            *(uint4*)&Bl[sr][sh] = t6;    *(uint4*)&Bl[sr][sh + 8] = t7;
        }
        __syncthreads();
        short8 afh[4], afl[4], bfh[4], bfl[4];
        #pragma unroll
        for (int mi = 0; mi < 4; mi++){
            afh[mi] = *(const short8*)&Ah[wr * 64 + mi * 16 + fr][kg * 8];
            afl[mi] = *(const short8*)&Al[wr * 64 + mi * 16 + fr][kg * 8];
            bfh[mi] = *(const short8*)&Bh[wc * 64 + mi * 16 + fr][kg * 8];
            bfl[mi] = *(const short8*)&Bl[wc * 64 + mi * 16 + fr][kg * 8];
        }
        #pragma unroll
        for (int mi = 0; mi < 4; mi++)
            #pragma unroll
            for (int ni = 0; ni < 4; ni++){
                acc[mi][ni] = __builtin_amdgcn_mfma_f32_16x16x32_bf16(afh[mi], bfh[ni], acc[mi][ni], 0, 0, 0);
                acc[mi][ni] = __builtin_amdgcn_mfma_f32_16x16x32_bf16(afh[mi], bfl[ni], acc[mi][ni], 0, 0, 0);
                acc[mi][ni] = __builtin_amdgcn_mfma_f32_16x16x32_bf16(afl[mi], bfh[ni], acc[mi][ni], 0, 0, 0);
            }
    }
    #pragma unroll
    for (int mi = 0; mi < 4; mi++){
        #pragma unroll
        for (int r = 0; r < 4; r++){
            int o = o0 + wr * 64 + mi * 16 + kg * 4 + r;
            float s = 0.f, s2 = 0.f, mxv = -INFINITY, mnv = INFINITY;
            #pragma unroll
            for (int ni = 0; ni < 4; ni++){
                float y = acc[mi][ni][r];
                s += y; s2 += y * y;
                mxv = fmaxf(mxv, y); mnv = fminf(mnv, y);
            }
            #pragma unroll
            for (int off = 1; off < 16; off <<= 1){
                s  += __shfl_xor(s, off);
                s2 += __shfl_xor(s2, off);
                mxv = fmaxf(mxv, __shfl_xor(mxv, off));
                mnv = fminf(mnv, __shfl_xor(mnv, off));
            }
            if (fr == 0){
                atomicAdd(&ssum[o], s);
                atomicAdd(&ssum2[o], s2);
                atomicMax(&maxk[b * 1024 + o], fkey(mxv));
                atomicMin(&mink[b * 1024 + o], fkey(mnv));
            }
        }
    }
}

__global__ void final_out_kernel(const unsigned* __restrict__ maxk, const unsigned* __restrict__ mink,
                                 const float* __restrict__ ssum, const float* __restrict__ ssum2,
                                 const float* __restrict__ g5, const float* __restrict__ b5,
                                 float* __restrict__ out){
    int gid = blockIdx.x * 256 + threadIdx.x;
    if (gid >= NB * 1024) return;
    int o = gid & 1023;
    const float inv = 1.f / (NB * NPTS);
    float mean = ssum[o] * inv;
    float var = fmaxf(ssum2[o] * inv - mean * mean, 0.f);
    float sc = g5[o] * rsqrtf(var + EPSV);
    float sh = b5[o] - mean * sc;
    float sel = sc >= 0.f ? funkey(maxk[gid]) : funkey(mink[gid]);
    out[gid] = lrelu(sel * sc + sh);
}

extern "C" void kernel_launch(void* const* d_in, const int* in_sizes, int n_in,
                              void* d_out, int out_size, void* d_ws, size_t ws_size,
                              hipStream_t stream){
    (void)in_sizes; (void)n_in; (void)out_size;
    const float* x = (const float*)d_in[0];
    const float* Ws[5] = {(const float*)d_in[1], (const float*)d_in[4], (const float*)d_in[7],
                          (const float*)d_in[10], (const float*)d_in[13]};
    const float* Gs[5] = {(const float*)d_in[2], (const float*)d_in[5], (const float*)d_in[8],
                          (const float*)d_in[11], (const float*)d_in[14]};
    const float* Bs[5] = {(const float*)d_in[3], (const float*)d_in[6], (const float*)d_in[9],
                          (const float*)d_in[12], (const float*)d_in[15]};
    float* out = (float*)d_out;

    char* base = (char*)d_ws;
    size_t off = 0;
    auto alloc = [&](size_t bytes) -> char* {
        char* p = base + off;
        off = (off + bytes + 255) & ~(size_t)255;
        return p;
    };
    float*          F    = (float*)alloc((size_t)NB * NPTS * FSTR * 4);
    unsigned short* Fh   = (unsigned short*)alloc((size_t)NB * NPTS * CPAD * 2);
    unsigned short* Fl   = (unsigned short*)alloc((size_t)NB * NPTS * CPAD * 2);
    unsigned short* W5h  = (unsigned short*)alloc((size_t)1024 * CPAD * 2);
    unsigned short* W5l  = (unsigned short*)alloc((size_t)1024 * CPAD * 2);
    float*          sq   = (float*)alloc((size_t)NB * NPTS * 4);
    double*         sqd  = (double*)alloc((size_t)NB * NPTS * 8);
    int*            cand = (int*)  alloc((size_t)NB * NPTS * NCAND * 4);
    int*            idxb = (int*)  alloc((size_t)NB * NPTS * K * 4);
    float*          mx   = (float*)alloc((size_t)NB * NPTS * 128 * 4);
    float*          mn   = (float*)alloc((size_t)NB * NPTS * 128 * 4);
    float*          ssum = (float*)alloc(1024 * 4);   // ssum2 contiguous after
    float*          ssum2= (float*)alloc(1024 * 4);
    float*          scale= (float*)alloc(1024 * 4);
    float*          shift= (float*)alloc(1024 * 4);
    unsigned*       maxk = (unsigned*)alloc(NB * 1024 * 4);
    unsigned*       mink = (unsigned*)alloc(NB * 1024 * 4);
    // union region: dist (bz batches) overlaps u,v (used in disjoint phases)
    char* R = base + off;
    size_t avail = (ws_size > off) ? ws_size - off : 0;
    const size_t DSZ = (size_t)NPTS * NPTS * 4;
    int bz = 1;
    if (avail >= 8 * DSZ + 256) bz = 8;
    else if (avail >= 4 * DSZ + 256) bz = 4;
    else if (avail >= 2 * DSZ + 256) bz = 2;
    float* dist = (float*)R;
    float* u    = (float*)R;
    float* v    = (float*)(R + (size_t)NB * NPTS * 128 * 4);

    hipMemsetAsync(Fh, 0, (size_t)NB * NPTS * CPAD * 2, stream);
    hipMemsetAsync(Fl, 0, (size_t)NB * NPTS * CPAD * 2, stream);
    copy_x_kernel<<<(NB * NPTS + 255) / 256, 256, 0, stream>>>(x, F, Fh, Fl);
    convW_kernel<<<(1024 * CPAD + 255) / 256, 256, 0, stream>>>(Ws[4], W5h, W5l);

    const int Cs[4] = {3, 67, 131, 195};
    const int Os[4] = {64, 64, 64, 128};
    for (int s = 0; s < 4; s++){
        int C = Cs[s], O = Os[s];
        int Kp = (C + 31) & ~31;
        sqnorm2_kernel<<<NB * NPTS / 4, 256, 0, stream>>>(F, sq, sqd, C);
        for (int b0 = 0; b0 < NB; b0 += bz){
            dist_mfma_kernel<<<dim3(NPTS / 128, NPTS / 128, bz), 256, 0, stream>>>(Fh, Fl, sq, dist, b0, Kp);
            topk_kernel<<<bz * NPTS / 4, 256, 0, stream>>>(dist, cand, b0 * NPTS);
        }
        switch (C){
            case 3:   refine_kernel<3>  <<<NB * NPTS / 8, 256, 0, stream>>>(F, sqd, cand, idxb); break;
            case 67:  refine_kernel<67> <<<NB * NPTS / 8, 256, 0, stream>>>(F, sqd, cand, idxb); break;
            case 131: refine_kernel<131><<<NB * NPTS / 8, 256, 0, stream>>>(F, sqd, cand, idxb); break;
            default:  refine_kernel<195><<<NB * NPTS / 8, 256, 0, stream>>>(F, sqd, cand, idxb); break;
        }
        hipMemsetAsync(ssum, 0, 2048 * 4, stream);   // ssum + ssum2 (contiguous)
        if (O == 64){
            uv_gemm_kernel<64><<<NB * NPTS / 16, 256, 0, stream>>>(F, Ws[s], u, v, C);
            gather_kernel<64><<<256, 256, 0, stream>>>(v, u, idxb, mx, mn, ssum, ssum2);
            finalize_kernel<<<1, 64, 0, stream>>>(ssum, ssum2, Gs[s], Bs[s], scale, shift, 64,
                                                  1.f / ((float)NB * NPTS * K));
            apply_kernel<64><<<NB * NPTS * 64 / 256, 256, 0, stream>>>(u, mx, mn, scale, shift, F, Fh, Fl, C);
        } else {
            uv_gemm_kernel<128><<<NB * NPTS / 8, 256, 0, stream>>>(F, Ws[s], u, v, C);
            gather_kernel<128><<<256, 256, 0, stream>>>(v, u, idxb, mx, mn, ssum, ssum2);
            finalize_kernel<<<1, 128, 0, stream>>>(ssum, ssum2, Gs[s], Bs[s], scale, shift, 128,
                                                   1.f / ((float)NB * NPTS * K));
            apply_kernel<128><<<NB * NPTS * 128 / 256, 256, 0, stream>>>(u, mx, mn, scale, shift, F, Fh, Fl, C);
        }
    }

    hipMemsetAsync(ssum, 0, 2048 * 4, stream);
    hipMemsetAsync(maxk, 0, NB * 1024 * 4, stream);
    hipMemsetAsync(mink, 0xFF, NB * 1024 * 4, stream);
    final_mfma_kernel<<<dim3(1024 / 128, NPTS / 128, NB), 256, 0, stream>>>(W5h, W5l, Fh, Fl,
                                                                            ssum, ssum2, maxk, mink);
    final_out_kernel<<<NB * 1024 / 256, 256, 0, stream>>>(maxk, mink, ssum, ssum2, Gs[4], Bs[4], out);
}

// Round 10
// 941.372 us; speedup vs baseline: 2.2559x; 1.5003x over previous
//
#include <hip/hip_runtime.h>
#include <math.h>

#define NB 8
#define NPTS 2048
#define NF 323
#define FSTR 328      // fp32 feature row stride (16B-aligned rows)
#define CPAD 352      // bf16 feature row stride (multiple of 32, >= 323)
#define K 20
#define EPSV 1e-5f
#define SLOPE 0.2f
#define NCAND 32      // approx candidates kept for exact re-rank (>= K+1)

typedef __attribute__((ext_vector_type(8))) short short8;
typedef __attribute__((ext_vector_type(4))) float f32x4;

__device__ __forceinline__ float lrelu(float x){ return x >= 0.f ? x : SLOPE * x; }

__device__ __forceinline__ unsigned fkey(float f){
    unsigned u = __float_as_uint(f);
    return (u & 0x80000000u) ? ~u : (u | 0x80000000u);
}
__device__ __forceinline__ float funkey(unsigned k){
    return (k & 0x80000000u) ? __uint_as_float(k ^ 0x80000000u) : __uint_as_float(~k);
}

__device__ __forceinline__ unsigned short f2bf_rne(float x){
    unsigned u = __float_as_uint(x);
    unsigned r = u + 0x7fffu + ((u >> 16) & 1u);
    return (unsigned short)(r >> 16);
}
__device__ __forceinline__ void split_bf(float x, unsigned short& h, unsigned short& l){
    h = f2bf_rne(x);
    float hf = __uint_as_float(((unsigned)h) << 16);
    l = f2bf_rne(x - hf);
}

// ---- x (B,3,N) -> F (B*N,FSTR) fp32 + Fh/Fl bf16 planes, channels [0,3) ----
__global__ void copy_x_kernel(const float* __restrict__ x, float* __restrict__ F,
                              unsigned short* __restrict__ Fh, unsigned short* __restrict__ Fl){
    int gid = blockIdx.x * 256 + threadIdx.x;
    if (gid >= NB * NPTS) return;
    int b = gid / NPTS, n = gid % NPTS;
    float* dst = F + (size_t)gid * FSTR;
    #pragma unroll
    for (int c = 0; c < 3; c++){
        float v = x[((size_t)b * 3 + c) * NPTS + n];
        dst[c] = v;
        unsigned short h, l; split_bf(v, h, l);
        Fh[(size_t)gid * CPAD + c] = h;
        Fl[(size_t)gid * CPAD + c] = l;
    }
}

// ---- per-point squared norms: fp32 (approx dist) + fp64 (exact re-rank), fused ----
__global__ __launch_bounds__(256) void sqnorm2_kernel(const float* __restrict__ F, float* __restrict__ sq,
                                                      double* __restrict__ sqd, int C){
    int row = blockIdx.x * 4 + (threadIdx.x >> 6);
    int lane = threadIdx.x & 63;
    const float* f = F + (size_t)row * FSTR;
    float s = 0.f;
    double sd = 0.0;
    for (int c = lane; c < C; c += 64){
        float t = f[c];
        s += t * t;
        double td = (double)t;
        sd = fma(td, td, sd);
    }
    #pragma unroll
    for (int off = 32; off; off >>= 1) s += __shfl_xor(s, off);
    #pragma unroll
    for (int off = 32; off; off >>= 1) sd += __shfl_xor(sd, off);
    if (lane == 0){ sq[row] = s; sqd[row] = sd; }
}

// ---- W5 -> bf16 hi/lo, padded to CPAD ----
__global__ void convW_kernel(const float* __restrict__ W5, unsigned short* __restrict__ Wh,
                             unsigned short* __restrict__ Wl){
    int gid = blockIdx.x * 256 + threadIdx.x;
    if (gid >= 1024 * CPAD) return;
    int o = gid / CPAD, c = gid % CPAD;
    float w = (c < NF) ? W5[(size_t)o * NF + c] : 0.f;
    unsigned short h, l; split_bf(w, h, l);
    Wh[gid] = h; Wl[gid] = l;
}

// ---- approx inv-dist Gram tile via bf16x3 MFMA: 128x128 per block, 4 waves ----
__global__ __launch_bounds__(256) void dist_mfma_kernel(
    const unsigned short* __restrict__ Fh, const unsigned short* __restrict__ Fl,
    const float* __restrict__ sq, float* __restrict__ dist, int b0, int Kp)
{
    __shared__ __align__(16) unsigned short Ah[128][40], Al[128][40], Bh[128][40], Bl[128][40];
    int tid = threadIdx.x;
    int b = b0 + blockIdx.z;
    int i0 = blockIdx.y * 128, j0 = blockIdx.x * 128;
    const size_t fbase = (size_t)b * NPTS * CPAD;
    int lane = tid & 63, wave = tid >> 6;
    int wr = wave >> 1, wc = wave & 1;
    int fr = lane & 15, kg = lane >> 4;
    int sr = tid >> 1, sh = (tid & 1) * 16;

    f32x4 acc[4][4];
    #pragma unroll
    for (int a = 0; a < 4; a++)
        #pragma unroll
        for (int c = 0; c < 4; c++) acc[a][c] = (f32x4){0.f, 0.f, 0.f, 0.f};

    for (int k0 = 0; k0 < Kp; k0 += 32){
        __syncthreads();
        {
            const unsigned short* pAh = Fh + fbase + (size_t)(i0 + sr) * CPAD + k0 + sh;
            const unsigned short* pAl = Fl + fbase + (size_t)(i0 + sr) * CPAD + k0 + sh;
            const unsigned short* pBh = Fh + fbase + (size_t)(j0 + sr) * CPAD + k0 + sh;
            const unsigned short* pBl = Fl + fbase + (size_t)(j0 + sr) * CPAD + k0 + sh;
            uint4 t0 = *(const uint4*)pAh; uint4 t1 = *(const uint4*)(pAh + 8);
            *(uint4*)&Ah[sr][sh] = t0;    *(uint4*)&Ah[sr][sh + 8] = t1;
            uint4 t2 = *(const uint4*)pAl; uint4 t3 = *(const uint4*)(pAl + 8);
            *(uint4*)&Al[sr][sh] = t2;    *(uint4*)&Al[sr][sh + 8] = t3;
            uint4 t4 = *(const uint4*)pBh; uint4 t5 = *(const uint4*)(pBh + 8);
            *(uint4*)&Bh[sr][sh] = t4;    *(uint4*)&Bh[sr][sh + 8] = t5;
            uint4 t6 = *(const uint4*)pBl; uint4 t7 = *(const uint4*)(pBl + 8);
            *(uint4*)&Bl[sr][sh] = t6;    *(uint4*)&Bl[sr][sh + 8] = t7;
        }
        __syncthreads();
        short8 afh[4], afl[4], bfh[4], bfl[4];
        #pragma unroll
        for (int mi = 0; mi < 4; mi++){
            afh[mi] = *(const short8*)&Ah[wr * 64 + mi * 16 + fr][kg * 8];
            afl[mi] = *(const short8*)&Al[wr * 64 + mi * 16 + fr][kg * 8];
            bfh[mi] = *(const short8*)&Bh[wc * 64 + mi * 16 + fr][kg * 8];
            bfl[mi] = *(const short8*)&Bl[wc * 64 + mi * 16 + fr][kg * 8];
        }
        #pragma unroll
        for (int mi = 0; mi < 4; mi++)
            #pragma unroll
            for (int ni = 0; ni < 4; ni++){
                acc[mi][ni] = __builtin_amdgcn_mfma_f32_16x16x32_bf16(afh[mi], bfh[ni], acc[mi][ni], 0, 0, 0);
                acc[mi][ni] = __builtin_amdgcn_mfma_f32_16x16x32_bf16(afh[mi], bfl[ni], acc[mi][ni], 0, 0, 0);
                acc[mi][ni] = __builtin_amdgcn_mfma_f32_16x16x32_bf16(afl[mi], bfh[ni], acc[mi][ni], 0, 0, 0);
            }
    }
    const float* sqb = sq + (b << 11);
    float* dbase = dist + (size_t)blockIdx.z * NPTS * NPTS;
    #pragma unroll
    for (int mi = 0; mi < 4; mi++){
        #pragma unroll
        for (int r = 0; r < 4; r++){
            int i = i0 + wr * 64 + mi * 16 + kg * 4 + r;
            float si = sqb[i];
            float* dr = dbase + (size_t)i * NPTS;
            #pragma unroll
            for (int ni = 0; ni < 4; ni++){
                int j = j0 + wc * 64 + ni * 16 + fr;
                dr[j] = 2.f * acc[mi][ni][r] - si - sqb[j];
            }
        }
    }
}

// ---- approx top-NCAND per row via fkey bit-descent + rank compaction ----
// Selected SET identical to iterative (val desc, col asc) top-32: survivors
// {key >= p} provably contain top-32 incl. all ties; exact rank-compaction
// picks ranks 0..31. Wave-uniform fallback to the iterative loop on extreme
// tie pathology (>64 survivors after full 32-bit descent).
__global__ __launch_bounds__(256) void topk_kernel(const float* __restrict__ dist, int* __restrict__ cand,
                                                   int chunk_base){
    int w = threadIdx.x >> 6;
    int lrow = blockIdx.x * 4 + w;
    int lane = threadIdx.x & 63;
    const float* D = dist + (size_t)lrow * NPTS;
    unsigned key[32];
    #pragma unroll
    for (int t = 0; t < 32; t++) key[t] = fkey(D[t * 64 + lane]);
    int* out = cand + (size_t)(chunk_base + lrow) * NCAND;

    // bit-descent: find prefix p with NCAND <= #{key >= p} <= 64
    unsigned p = 0;
    int cl_acc = 32;
    int ct_acc = NPTS;
    for (int bit = 31; bit >= 0; --bit){
        if (ct_acc <= 64) break;
        unsigned pp = p | (1u << bit);
        int cl = 0;
        #pragma unroll
        for (int t = 0; t < 32; t++) cl += (key[t] >= pp) ? 1 : 0;
        int ct = cl;
        #pragma unroll
        for (int off = 1; off < 64; off <<= 1) ct += __shfl_xor(ct, off);
        if (ct >= NCAND){ p = pp; cl_acc = cl; ct_acc = ct; }
    }

    __shared__ unsigned long long spk[4][64];
    if (ct_acc <= 64){
        // exclusive prefix of per-lane survivor counts
        int ex = cl_acc;
        #pragma unroll
        for (int off = 1; off < 64; off <<= 1){
            int tu = __shfl_up(ex, off);
            if (lane >= off) ex += tu;
        }
        ex -= cl_acc;
        spk[w][lane] = 0ull;                      // dummy init (real pk > 0 always)
        int k = ex;
        #pragma unroll
        for (int t = 0; t < 32; t++){
            if (key[t] >= p){
                unsigned col = (unsigned)(t * 64 + lane);
                spk[w][k] = ((unsigned long long)key[t] << 32) | (unsigned)(~col);
                k++;
            }
        }
        asm volatile("s_waitcnt lgkmcnt(0)" ::: "memory");
        unsigned long long mypk = spk[w][lane];
        int rank = 0;
        #pragma unroll
        for (int m = 0; m < 64; m++){
            unsigned long long pm = spk[w][m];
            rank += (pm > mypk) ? 1 : 0;
        }
        if (lane < ct_acc && rank < NCAND)
            out[rank] = (int)(~(unsigned)(mypk & 0xFFFFFFFFu));
    } else {
        // fallback: exact iterative extraction in key domain (same tie rule)
        for (int it = 0; it < NCAND; it++){
            unsigned bv = key[0]; int bt = 0;
            #pragma unroll
            for (int t = 1; t < 32; t++){ if (key[t] > bv){ bv = key[t]; bt = t; } }
            int bcol = bt * 64 + lane;
            #pragma unroll
            for (int off = 1; off < 64; off <<= 1){
                unsigned ov = __shfl_xor(bv, off);
                int      oc = __shfl_xor(bcol, off);
                if (ov > bv || (ov == bv && oc < bcol)){ bv = ov; bcol = oc; }
            }
            if (lane == 0) out[it] = bcol;
            #pragma unroll
            for (int q = 0; q < 32; q++){
                if (bcol == q * 64 + lane) key[q] = 0;
            }
        }
    }
}

// ---- FP64 re-rank of NCAND candidates -> true top-21, drop first (self) ----
template<int C>
__global__ __launch_bounds__(256, 4) void refine_kernel(const float* __restrict__ F,
                                                        const double* __restrict__ sqd,
                                                        const int* __restrict__ cand,
                                                        int* __restrict__ idxo){
    int orig = blockIdx.x;
    int wg = (orig & 7) * (gridDim.x >> 3) + (orig >> 3);   // bijective: gridDim % 8 == 0
    int tid = threadIdx.x;
    int half = tid >> 5, cl = tid & 31;
    int row = wg * 8 + half;
    int b = row >> 11;
    const float* Fi = F + (size_t)row * FSTR;
    int cj = cand[(size_t)row * NCAND + cl];
    const float* Fj = F + ((size_t)(b << 11) + cj) * FSTR;

    double t0 = 0.0, t1 = 0.0, t2 = 0.0, t3 = 0.0;
    constexpr int nv = C >> 2;       // C % 4 == 3 for all stages
    #pragma unroll
    for (int q = 0; q < nv; q++){
        float4 a  = *(const float4*)(Fi + q * 4);
        float4 bb = *(const float4*)(Fj + q * 4);
        t0 = fma((double)a.x, (double)bb.x, t0);
        t1 = fma((double)a.y, (double)bb.y, t1);
        t2 = fma((double)a.z, (double)bb.z, t2);
        t3 = fma((double)a.w, (double)bb.w, t3);
    }
    constexpr int c0 = nv * 4;
    t0 = fma((double)Fi[c0],     (double)Fj[c0],     t0);
    t1 = fma((double)Fi[c0 + 1], (double)Fj[c0 + 1], t1);
    t2 = fma((double)Fi[c0 + 2], (double)Fj[c0 + 2], t2);
    double t = (t0 + t1) + (t2 + t3);
    double d = 2.0 * t - sqd[row] - sqd[(b << 11) + cj];

    int cnt = 0;
    #pragma unroll
    for (int m = 0; m < NCAND; m++){
        double vm = __shfl(d, m, 32);
        int    im = __shfl(cj, m, 32);
        if (vm > d || (vm == d && im < cj)) cnt++;
    }
    if (cnt >= 1 && cnt <= K)
        idxo[(size_t)row * K + cnt - 1] = cj;
}

// ---- v = Wa*x, u = (Wb-Wa)*x -> layout (b,n,o). 4 rows/group (occupancy) ----
template<int O>
__global__ __launch_bounds__(256) void uv_gemm_kernel(const float* __restrict__ F, const float* __restrict__ W,
                                                      float* __restrict__ u, float* __restrict__ v, int C){
    const int G = 256 / O;
    const int R = 4;
    const int ROWS = G * R;
    __shared__ float Wa[O][17], Wd[O][17], Fl[ROWS][17];
    int tid = threadIdx.x;
    int o = tid % O, g = tid / O;
    int row0 = blockIdx.x * ROWS;
    float va[R], ua[R];
    #pragma unroll
    for (int r = 0; r < R; r++){ va[r] = 0.f; ua[r] = 0.f; }
    for (int c0 = 0; c0 < C; c0 += 16){
        __syncthreads();
        for (int idx = tid; idx < O * 16; idx += 256){
            int oo = idx >> 4, cc = idx & 15; int c = c0 + cc;
            float wa = 0.f, wb = 0.f;
            if (c < C){ wa = W[(size_t)oo * (2 * C) + c]; wb = W[(size_t)oo * (2 * C) + C + c]; }
            Wa[oo][cc] = wa; Wd[oo][cc] = wb - wa;
        }
        for (int idx = tid; idx < ROWS * 16; idx += 256){
            int rr = idx >> 4, cc = idx & 15; int c = c0 + cc;
            Fl[rr][cc] = (c < C) ? F[(size_t)(row0 + rr) * FSTR + c] : 0.f;
        }
        __syncthreads();
        #pragma unroll
        for (int cc = 0; cc < 16; cc++){
            float wa = Wa[o][cc], wd = Wd[o][cc];
            #pragma unroll
            for (int r = 0; r < R; r++){
                float f = Fl[g * R + r][cc];
                va[r] += wa * f; ua[r] += wd * f;
            }
        }
    }
    #pragma unroll
    for (int r = 0; r < R; r++){
        size_t row = (size_t)row0 + g * R + r;
        v[row * O + o] = va[r];
        u[row * O + o] = ua[r];
    }
}

// ---- gather neighbors: per (b,n,o) max/min of v[nbr] + exact channel stats ----
template<int O>
__global__ __launch_bounds__(256) void gather_kernel(const float* __restrict__ v, const float* __restrict__ u,
                                                     const int* __restrict__ idxb, float* __restrict__ mx,
                                                     float* __restrict__ mn, float* __restrict__ ssum,
                                                     float* __restrict__ ssum2){
    const int G = 256 / O;
    const int RPB = (NB * NPTS) / 256;   // 64 rows per block
    int orig = blockIdx.x;
    int wg = (orig & 7) * (gridDim.x >> 3) + (orig >> 3);   // gridDim = 256
    int tid = threadIdx.x;
    int o = tid % O, g = tid / O;
    float csum = 0.f, csq = 0.f;
    for (int it = 0; it < RPB / G; it++){
        int row = wg * RPB + it * G + g;
        int b = row >> 11;
        float uv = u[(size_t)row * O + o];
        const int* ip = idxb + (size_t)row * K;
        float s1 = 0.f, s2 = 0.f, vmax = -INFINITY, vmin = INFINITY;
        for (int j = 0; j < K; j++){
            int nb = ip[j];
            float vv = v[((size_t)(b << 11) + nb) * O + o];
            s1 += vv; s2 += vv * vv;
            vmax = fmaxf(vmax, vv); vmin = fminf(vmin, vv);
        }
        mx[(size_t)row * O + o] = vmax;
        mn[(size_t)row * O + o] = vmin;
        csum += s1 + (float)K * uv;
        csq  += s2 + 2.f * uv * s1 + (float)K * uv * uv;
    }
    __shared__ float red[256];
    red[tid] = csum; __syncthreads();
    if (tid < O){ float t = 0.f; for (int gg = 0; gg < G; gg++) t += red[gg * O + tid]; atomicAdd(&ssum[tid], t); }
    __syncthreads();
    red[tid] = csq; __syncthreads();
    if (tid < O){ float t = 0.f; for (int gg = 0; gg < G; gg++) t += red[gg * O + tid]; atomicAdd(&ssum2[tid], t); }
}

__global__ void finalize_kernel(const float* __restrict__ ssum, const float* __restrict__ ssum2,
                                const float* __restrict__ gg, const float* __restrict__ bb,
                                float* __restrict__ scale, float* __restrict__ shift, int O, float inv_count){
    int o = blockIdx.x * blockDim.x + threadIdx.x;
    if (o >= O) return;
    float mean = ssum[o] * inv_count;
    float var = fmaxf(ssum2[o] * inv_count - mean * mean, 0.f);
    float sc = gg[o] * rsqrtf(var + EPSV);
    scale[o] = sc;
    shift[o] = bb[o] - mean * sc;
}

template<int O>
__global__ __launch_bounds__(256) void apply_kernel(const float* __restrict__ u, const float* __restrict__ mx,
                                                    const float* __restrict__ mn, const float* __restrict__ scale,
                                                    const float* __restrict__ shift, float* __restrict__ F,
                                                    unsigned short* __restrict__ Fh, unsigned short* __restrict__ Fl,
                                                    int coff){
    int gid = blockIdx.x * 256 + threadIdx.x;
    int row = gid / O, o = gid % O;
    float sc = scale[o];
    float sel = sc >= 0.f ? mx[gid] : mn[gid];
    float val = lrelu((u[gid] + sel) * sc + shift[o]);
    F[(size_t)row * FSTR + coff + o] = val;
    unsigned short h, l; split_bf(val, h, l);
    Fh[(size_t)row * CPAD + coff + o] = h;
    Fl[(size_t)row * CPAD + coff + o] = l;
}

// ---- final GEMM via bf16x3 MFMA, fused BN-stat + max/min epilogue ----
__global__ __launch_bounds__(256) void final_mfma_kernel(
    const unsigned short* __restrict__ Wh, const unsigned short* __restrict__ Wl,
    const unsigned short* __restrict__ Fh, const unsigned short* __restrict__ Fl,
    float* __restrict__ ssum, float* __restrict__ ssum2,
    unsigned* __restrict__ maxk, unsigned* __restrict__ mink)
{
    __shared__ __align__(16) unsigned short Ah[128][40], Al[128][40], Bh[128][40], Bl[128][40];
    int tid = threadIdx.x;
    int o0 = blockIdx.x * 128, n0 = blockIdx.y * 128, b = blockIdx.z;
    const size_t fbase = (size_t)b * NPTS * CPAD;
    int lane = tid & 63, wave = tid >> 6;
    int wr = wave >> 1, wc = wave & 1;
    int fr = lane & 15, kg = lane >> 4;
    int sr = tid >> 1, sh = (tid & 1) * 16;

    f32x4 acc[4][4];
    #pragma unroll
    for (int a = 0; a < 4; a++)
        #pragma unroll
        for (int c = 0; c < 4; c++) acc[a][c] = (f32x4){0.f, 0.f, 0.f, 0.f};

    for (int k0 = 0; k0 < CPAD; k0 += 32){
        __syncthreads();
        {
            const unsigned short* pAh = Wh + (size_t)(o0 + sr) * CPAD + k0 + sh;
            const unsigned short* pAl = Wl + (size_t)(o0 + sr) * CPAD + k0 + sh;
            const unsigned short* pBh = Fh + fbase + (size_t)(n0 + sr) * CPAD + k0 + sh;
            const unsigned short* pBl = Fl + fbase + (size_t)(n0 + sr) * CPAD + k0 + sh;
            uint4 t0 = *(const uint4*)pAh; uint4 t1 = *(const uint4*)(pAh + 8);
            *(uint4*)&Ah[sr][sh] = t0;    *(uint4*)&Ah[sr][sh + 8] = t1;
            uint4 t2 = *(const uint4*)pAl; uint4 t3 = *(const uint4*)(pAl + 8);
            *(uint4*)&Al[sr][sh] = t2;    *(uint4*)&Al[sr][sh + 8] = t3;
            uint4 t4 = *(const uint4*)pBh; uint4 t5 = *(const uint4*)(pBh + 8);
            *(uint4*)&Bh[sr][sh] = t4;    *(uint4*)&Bh[sr][sh + 8] = t5;
            uint4 t6 = *(const uint4*)pBl; uint4 t7 = *(const uint4*)(pBl + 8);
            *(uint4*)&Bl[sr][sh] = t6;    *(uint4*)&Bl[sr][sh + 8] = t7;
        }
        __syncthreads();
        short8 afh[4], afl[4], bfh[4], bfl[4];
        #pragma unroll
        for (int mi = 0; mi < 4; mi++){
            afh[mi] = *(const short8*)&Ah[wr * 64 + mi * 16 + fr][kg * 8];
            afl[mi] = *(const short8*)&Al[wr * 64 + mi * 16 + fr][kg * 8];
            bfh[mi] = *(const short8*)&Bh[wc * 64 + mi * 16 + fr][kg * 8];
            bfl[mi] = *(const short8*)&Bl[wc * 64 + mi * 16 + fr][kg * 8];
        }
        #pragma unroll
        for (int mi = 0; mi < 4; mi++)
            #pragma unroll
            for (int ni = 0; ni < 4; ni++){
                acc[mi][ni] = __builtin_amdgcn_mfma_f32_16x16x32_bf16(afh[mi], bfh[ni], acc[mi][ni], 0, 0, 0);
                acc[mi][ni] = __builtin_amdgcn_mfma_f32_16x16x32_bf16(afh[mi], bfl[ni], acc[mi][ni], 0, 0, 0);
                acc[mi][ni] = __builtin_amdgcn_mfma_f32_16x16x32_bf16(afl[mi], bfh[ni], acc[mi][ni], 0, 0, 0);
            }
    }
    #pragma unroll
    for (int mi = 0; mi < 4; mi++){
        #pragma unroll
        for (int r = 0; r < 4; r++){
            int o = o0 + wr * 64 + mi * 16 + kg * 4 + r;
            float s = 0.f, s2 = 0.f, mxv = -INFINITY, mnv = INFINITY;
            #pragma unroll
            for (int ni = 0; ni < 4; ni++){
                float y = acc[mi][ni][r];
                s += y; s2 += y * y;
                mxv = fmaxf(mxv, y); mnv = fminf(mnv, y);
            }
            #pragma unroll
            for (int off = 1; off < 16; off <<= 1){
                s  += __shfl_xor(s, off);
                s2 += __shfl_xor(s2, off);
                mxv = fmaxf(mxv, __shfl_xor(mxv, off));
                mnv = fminf(mnv, __shfl_xor(mnv, off));
            }
            if (fr == 0){
                atomicAdd(&ssum[o], s);
                atomicAdd(&ssum2[o], s2);
                atomicMax(&maxk[b * 1024 + o], fkey(mxv));
                atomicMin(&mink[b * 1024 + o], fkey(mnv));
            }
        }
    }
}

__global__ void final_out_kernel(const unsigned* __restrict__ maxk, const unsigned* __restrict__ mink,
                                 const float* __restrict__ ssum, const float* __restrict__ ssum2,
                                 const float* __restrict__ g5, const float* __restrict__ b5,
                                 float* __restrict__ out){
    int gid = blockIdx.x * 256 + threadIdx.x;
    if (gid >= NB * 1024) return;
    int o = gid & 1023;
    const float inv = 1.f / (NB * NPTS);
    float mean = ssum[o] * inv;
    float var = fmaxf(ssum2[o] * inv - mean * mean, 0.f);
    float sc = g5[o] * rsqrtf(var + EPSV);
    float sh = b5[o] - mean * sc;
    float sel = sc >= 0.f ? funkey(maxk[gid]) : funkey(mink[gid]);
    out[gid] = lrelu(sel * sc + sh);
}

extern "C" void kernel_launch(void* const* d_in, const int* in_sizes, int n_in,
                              void* d_out, int out_size, void* d_ws, size_t ws_size,
                              hipStream_t stream){
    (void)in_sizes; (void)n_in; (void)out_size;
    const float* x = (const float*)d_in[0];
    const float* Ws[5] = {(const float*)d_in[1], (const float*)d_in[4], (const float*)d_in[7],
                          (const float*)d_in[10], (const float*)d_in[13]};
    const float* Gs[5] = {(const float*)d_in[2], (const float*)d_in[5], (const float*)d_in[8],
                          (const float*)d_in[11], (const float*)d_in[14]};
    const float* Bs[5] = {(const float*)d_in[3], (const float*)d_in[6], (const float*)d_in[9],
                          (const float*)d_in[12], (const float*)d_in[15]};
    float* out = (float*)d_out;

    char* base = (char*)d_ws;
    size_t off = 0;
    auto alloc = [&](size_t bytes) -> char* {
        char* p = base + off;
        off = (off + bytes + 255) & ~(size_t)255;
        return p;
    };
    float*          F    = (float*)alloc((size_t)NB * NPTS * FSTR * 4);
    unsigned short* Fh   = (unsigned short*)alloc((size_t)NB * NPTS * CPAD * 2);
    unsigned short* Fl   = (unsigned short*)alloc((size_t)NB * NPTS * CPAD * 2);
    unsigned short* W5h  = (unsigned short*)alloc((size_t)1024 * CPAD * 2);
    unsigned short* W5l  = (unsigned short*)alloc((size_t)1024 * CPAD * 2);
    float*          sq   = (float*)alloc((size_t)NB * NPTS * 4);
    double*         sqd  = (double*)alloc((size_t)NB * NPTS * 8);
    int*            cand = (int*)  alloc((size_t)NB * NPTS * NCAND * 4);
    int*            idxb = (int*)  alloc((size_t)NB * NPTS * K * 4);
    float*          mx   = (float*)alloc((size_t)NB * NPTS * 128 * 4);
    float*          mn   = (float*)alloc((size_t)NB * NPTS * 128 * 4);
    float*          ssum = (float*)alloc(1024 * 4);   // ssum2 contiguous after
    float*          ssum2= (float*)alloc(1024 * 4);
    float*          scale= (float*)alloc(1024 * 4);
    float*          shift= (float*)alloc(1024 * 4);
    unsigned*       maxk = (unsigned*)alloc(NB * 1024 * 4);
    unsigned*       mink = (unsigned*)alloc(NB * 1024 * 4);
    // union region: dist (bz batches) overlaps u,v (used in disjoint phases)
    char* R = base + off;
    size_t avail = (ws_size > off) ? ws_size - off : 0;
    const size_t DSZ = (size_t)NPTS * NPTS * 4;
    int bz = 1;
    if (avail >= 8 * DSZ + 256) bz = 8;
    else if (avail >= 4 * DSZ + 256) bz = 4;
    else if (avail >= 2 * DSZ + 256) bz = 2;
    float* dist = (float*)R;
    float* u    = (float*)R;
    float* v    = (float*)(R + (size_t)NB * NPTS * 128 * 4);

    hipMemsetAsync(Fh, 0, (size_t)NB * NPTS * CPAD * 2, stream);
    hipMemsetAsync(Fl, 0, (size_t)NB * NPTS * CPAD * 2, stream);
    copy_x_kernel<<<(NB * NPTS + 255) / 256, 256, 0, stream>>>(x, F, Fh, Fl);
    convW_kernel<<<(1024 * CPAD + 255) / 256, 256, 0, stream>>>(Ws[4], W5h, W5l);

    const int Cs[4] = {3, 67, 131, 195};
    const int Os[4] = {64, 64, 64, 128};
    for (int s = 0; s < 4; s++){
        int C = Cs[s], O = Os[s];
        int Kp = (C + 31) & ~31;
        sqnorm2_kernel<<<NB * NPTS / 4, 256, 0, stream>>>(F, sq, sqd, C);
        for (int b0 = 0; b0 < NB; b0 += bz){
            dist_mfma_kernel<<<dim3(NPTS / 128, NPTS / 128, bz), 256, 0, stream>>>(Fh, Fl, sq, dist, b0, Kp);
            topk_kernel<<<bz * NPTS / 4, 256, 0, stream>>>(dist, cand, b0 * NPTS);
        }
        switch (C){
            case 3:   refine_kernel<3>  <<<NB * NPTS / 8, 256, 0, stream>>>(F, sqd, cand, idxb); break;
            case 67:  refine_kernel<67> <<<NB * NPTS / 8, 256, 0, stream>>>(F, sqd, cand, idxb); break;
            case 131: refine_kernel<131><<<NB * NPTS / 8, 256, 0, stream>>>(F, sqd, cand, idxb); break;
            default:  refine_kernel<195><<<NB * NPTS / 8, 256, 0, stream>>>(F, sqd, cand, idxb); break;
        }
        hipMemsetAsync(ssum, 0, 2048 * 4, stream);   // ssum + ssum2 (contiguous)
        if (O == 64){
            uv_gemm_kernel<64><<<NB * NPTS / 16, 256, 0, stream>>>(F, Ws[s], u, v, C);
            gather_kernel<64><<<256, 256, 0, stream>>>(v, u, idxb, mx, mn, ssum, ssum2);
            finalize_kernel<<<1, 64, 0, stream>>>(ssum, ssum2, Gs[s], Bs[s], scale, shift, 64,
                                                  1.f / ((float)NB * NPTS * K));
            apply_kernel<64><<<NB * NPTS * 64 / 256, 256, 0, stream>>>(u, mx, mn, scale, shift, F, Fh, Fl, C);
        } else {
            uv_gemm_kernel<128><<<NB * NPTS / 8, 256, 0, stream>>>(F, Ws[s], u, v, C);
            gather_kernel<128><<<256, 256, 0, stream>>>(v, u, idxb, mx, mn, ssum, ssum2);
            finalize_kernel<<<1, 128, 0, stream>>>(ssum, ssum2, Gs[s], Bs[s], scale, shift, 128,
                                                   1.f / ((float)NB * NPTS * K));
            apply_kernel<128><<<NB * NPTS * 128 / 256, 256, 0, stream>>>(u, mx, mn, scale, shift, F, Fh, Fl, C);
        }
    }

    hipMemsetAsync(ssum, 0, 2048 * 4, stream);
    hipMemsetAsync(maxk, 0, NB * 1024 * 4, stream);
    hipMemsetAsync(mink, 0xFF, NB * 1024 * 4, stream);
    final_mfma_kernel<<<dim3(1024 / 128, NPTS / 128, NB), 256, 0, stream>>>(W5h, W5l, Fh, Fl,
                                                                            ssum, ssum2, maxk, mink);
    final_out_kernel<<<NB * 1024 / 256, 256, 0, stream>>>(maxk, mink, ssum, ssum2, Gs[4], Bs[4], out);
}

// Round 11
// 907.365 us; speedup vs baseline: 2.3405x; 1.0375x over previous
//
#include <hip/hip_runtime.h>
#include <math.h>

#define NB 8
#define NPTS 2048
#define NF 323
#define FSTR 328      // fp32 feature row stride (16B-aligned rows)
#define CPAD 352      // bf16 feature row stride (multiple of 32, >= 323)
#define K 20
#define EPSV 1e-5f
#define SLOPE 0.2f
#define NCAND 32      // approx candidates kept for exact re-rank (>= K+1)

typedef __attribute__((ext_vector_type(8))) short short8;
typedef __attribute__((ext_vector_type(4))) float f32x4;

__device__ __forceinline__ float lrelu(float x){ return x >= 0.f ? x : SLOPE * x; }

__device__ __forceinline__ unsigned fkey(float f){
    unsigned u = __float_as_uint(f);
    return (u & 0x80000000u) ? ~u : (u | 0x80000000u);
}
__device__ __forceinline__ float funkey(unsigned k){
    return (k & 0x80000000u) ? __uint_as_float(k ^ 0x80000000u) : __uint_as_float(~k);
}

__device__ __forceinline__ unsigned short f2bf_rne(float x){
    unsigned u = __float_as_uint(x);
    unsigned r = u + 0x7fffu + ((u >> 16) & 1u);
    return (unsigned short)(r >> 16);
}
__device__ __forceinline__ void split_bf(float x, unsigned short& h, unsigned short& l){
    h = f2bf_rne(x);
    float hf = __uint_as_float(((unsigned)h) << 16);
    l = f2bf_rne(x - hf);
}

// ---- x (B,3,N) -> F (B*N,FSTR) fp32 + Fh/Fl bf16 planes, channels [0,3) ----
__global__ void copy_x_kernel(const float* __restrict__ x, float* __restrict__ F,
                              unsigned short* __restrict__ Fh, unsigned short* __restrict__ Fl){
    int gid = blockIdx.x * 256 + threadIdx.x;
    if (gid >= NB * NPTS) return;
    int b = gid / NPTS, n = gid % NPTS;
    float* dst = F + (size_t)gid * FSTR;
    #pragma unroll
    for (int c = 0; c < 3; c++){
        float v = x[((size_t)b * 3 + c) * NPTS + n];
        dst[c] = v;
        unsigned short h, l; split_bf(v, h, l);
        Fh[(size_t)gid * CPAD + c] = h;
        Fl[(size_t)gid * CPAD + c] = l;
    }
}

// ---- per-point squared norms: fp32 (approx dist) + fp64 (exact re-rank), fused ----
__global__ __launch_bounds__(256) void sqnorm2_kernel(const float* __restrict__ F, float* __restrict__ sq,
                                                      double* __restrict__ sqd, int C){
    int row = blockIdx.x * 4 + (threadIdx.x >> 6);
    int lane = threadIdx.x & 63;
    const float* f = F + (size_t)row * FSTR;
    float s = 0.f;
    double sd = 0.0;
    for (int c = lane; c < C; c += 64){
        float t = f[c];
        s += t * t;
        double td = (double)t;
        sd = fma(td, td, sd);
    }
    #pragma unroll
    for (int off = 32; off; off >>= 1) s += __shfl_xor(s, off);
    #pragma unroll
    for (int off = 32; off; off >>= 1) sd += __shfl_xor(sd, off);
    if (lane == 0){ sq[row] = s; sqd[row] = sd; }
}

// ---- W5 -> bf16 hi/lo, padded to CPAD ----
__global__ void convW_kernel(const float* __restrict__ W5, unsigned short* __restrict__ Wh,
                             unsigned short* __restrict__ Wl){
    int gid = blockIdx.x * 256 + threadIdx.x;
    if (gid >= 1024 * CPAD) return;
    int o = gid / CPAD, c = gid % CPAD;
    float w = (c < NF) ? W5[(size_t)o * NF + c] : 0.f;
    unsigned short h, l; split_bf(w, h, l);
    Wh[gid] = h; Wl[gid] = l;
}

// ---- approx inv-dist Gram tile via bf16x3 MFMA: 128x128 per block, 4 waves ----
__global__ __launch_bounds__(256) void dist_mfma_kernel(
    const unsigned short* __restrict__ Fh, const unsigned short* __restrict__ Fl,
    const float* __restrict__ sq, float* __restrict__ dist, int b0, int Kp)
{
    __shared__ __align__(16) unsigned short Ah[128][40], Al[128][40], Bh[128][40], Bl[128][40];
    int tid = threadIdx.x;
    int b = b0 + blockIdx.z;
    int i0 = blockIdx.y * 128, j0 = blockIdx.x * 128;
    const size_t fbase = (size_t)b * NPTS * CPAD;
    int lane = tid & 63, wave = tid >> 6;
    int wr = wave >> 1, wc = wave & 1;
    int fr = lane & 15, kg = lane >> 4;
    int sr = tid >> 1, sh = (tid & 1) * 16;

    f32x4 acc[4][4];
    #pragma unroll
    for (int a = 0; a < 4; a++)
        #pragma unroll
        for (int c = 0; c < 4; c++) acc[a][c] = (f32x4){0.f, 0.f, 0.f, 0.f};

    for (int k0 = 0; k0 < Kp; k0 += 32){
        __syncthreads();
        {
            const unsigned short* pAh = Fh + fbase + (size_t)(i0 + sr) * CPAD + k0 + sh;
            const unsigned short* pAl = Fl + fbase + (size_t)(i0 + sr) * CPAD + k0 + sh;
            const unsigned short* pBh = Fh + fbase + (size_t)(j0 + sr) * CPAD + k0 + sh;
            const unsigned short* pBl = Fl + fbase + (size_t)(j0 + sr) * CPAD + k0 + sh;
            uint4 t0 = *(const uint4*)pAh; uint4 t1 = *(const uint4*)(pAh + 8);
            *(uint4*)&Ah[sr][sh] = t0;    *(uint4*)&Ah[sr][sh + 8] = t1;
            uint4 t2 = *(const uint4*)pAl; uint4 t3 = *(const uint4*)(pAl + 8);
            *(uint4*)&Al[sr][sh] = t2;    *(uint4*)&Al[sr][sh + 8] = t3;
            uint4 t4 = *(const uint4*)pBh; uint4 t5 = *(const uint4*)(pBh + 8);
            *(uint4*)&Bh[sr][sh] = t4;    *(uint4*)&Bh[sr][sh + 8] = t5;
            uint4 t6 = *(const uint4*)pBl; uint4 t7 = *(const uint4*)(pBl + 8);
            *(uint4*)&Bl[sr][sh] = t6;    *(uint4*)&Bl[sr][sh + 8] = t7;
        }
        __syncthreads();
        short8 afh[4], afl[4], bfh[4], bfl[4];
        #pragma unroll
        for (int mi = 0; mi < 4; mi++){
            afh[mi] = *(const short8*)&Ah[wr * 64 + mi * 16 + fr][kg * 8];
            afl[mi] = *(const short8*)&Al[wr * 64 + mi * 16 + fr][kg * 8];
            bfh[mi] = *(const short8*)&Bh[wc * 64 + mi * 16 + fr][kg * 8];
            bfl[mi] = *(const short8*)&Bl[wc * 64 + mi * 16 + fr][kg * 8];
        }
        #pragma unroll
        for (int mi = 0; mi < 4; mi++)
            #pragma unroll
            for (int ni = 0; ni < 4; ni++){
                acc[mi][ni] = __builtin_amdgcn_mfma_f32_16x16x32_bf16(afh[mi], bfh[ni], acc[mi][ni], 0, 0, 0);
                acc[mi][ni] = __builtin_amdgcn_mfma_f32_16x16x32_bf16(afh[mi], bfl[ni], acc[mi][ni], 0, 0, 0);
                acc[mi][ni] = __builtin_amdgcn_mfma_f32_16x16x32_bf16(afl[mi], bfh[ni], acc[mi][ni], 0, 0, 0);
            }
    }
    const float* sqb = sq + (b << 11);
    float* dbase = dist + (size_t)blockIdx.z * NPTS * NPTS;
    #pragma unroll
    for (int mi = 0; mi < 4; mi++){
        #pragma unroll
        for (int r = 0; r < 4; r++){
            int i = i0 + wr * 64 + mi * 16 + kg * 4 + r;
            float si = sqb[i];
            float* dr = dbase + (size_t)i * NPTS;
            #pragma unroll
            for (int ni = 0; ni < 4; ni++){
                int j = j0 + wc * 64 + ni * 16 + fr;
                dr[j] = 2.f * acc[mi][ni][r] - si - sqb[j];
            }
        }
    }
}

// ---- approx top-NCAND per row via fkey bit-descent + rank compaction ----
__global__ __launch_bounds__(256) void topk_kernel(const float* __restrict__ dist, int* __restrict__ cand,
                                                   int chunk_base){
    int w = threadIdx.x >> 6;
    int lrow = blockIdx.x * 4 + w;
    int lane = threadIdx.x & 63;
    const float* D = dist + (size_t)lrow * NPTS;
    unsigned key[32];
    #pragma unroll
    for (int t = 0; t < 32; t++) key[t] = fkey(D[t * 64 + lane]);
    int* out = cand + (size_t)(chunk_base + lrow) * NCAND;

    // bit-descent: find prefix p with NCAND <= #{key >= p} <= 64
    unsigned p = 0;
    int cl_acc = 32;
    int ct_acc = NPTS;
    for (int bit = 31; bit >= 0; --bit){
        if (ct_acc <= 64) break;
        unsigned pp = p | (1u << bit);
        int cl = 0;
        #pragma unroll
        for (int t = 0; t < 32; t++) cl += (key[t] >= pp) ? 1 : 0;
        int ct = cl;
        #pragma unroll
        for (int off = 1; off < 64; off <<= 1) ct += __shfl_xor(ct, off);
        if (ct >= NCAND){ p = pp; cl_acc = cl; ct_acc = ct; }
    }

    __shared__ unsigned long long spk[4][64];
    if (ct_acc <= 64){
        int ex = cl_acc;
        #pragma unroll
        for (int off = 1; off < 64; off <<= 1){
            int tu = __shfl_up(ex, off);
            if (lane >= off) ex += tu;
        }
        ex -= cl_acc;
        spk[w][lane] = 0ull;
        int k = ex;
        #pragma unroll
        for (int t = 0; t < 32; t++){
            if (key[t] >= p){
                unsigned col = (unsigned)(t * 64 + lane);
                spk[w][k] = ((unsigned long long)key[t] << 32) | (unsigned)(~col);
                k++;
            }
        }
        asm volatile("s_waitcnt lgkmcnt(0)" ::: "memory");
        unsigned long long mypk = spk[w][lane];
        int rank = 0;
        #pragma unroll
        for (int m = 0; m < 64; m++){
            unsigned long long pm = spk[w][m];
            rank += (pm > mypk) ? 1 : 0;
        }
        if (lane < ct_acc && rank < NCAND)
            out[rank] = (int)(~(unsigned)(mypk & 0xFFFFFFFFu));
    } else {
        for (int it = 0; it < NCAND; it++){
            unsigned bv = key[0]; int bt = 0;
            #pragma unroll
            for (int t = 1; t < 32; t++){ if (key[t] > bv){ bv = key[t]; bt = t; } }
            int bcol = bt * 64 + lane;
            #pragma unroll
            for (int off = 1; off < 64; off <<= 1){
                unsigned ov = __shfl_xor(bv, off);
                int      oc = __shfl_xor(bcol, off);
                if (ov > bv || (ov == bv && oc < bcol)){ bv = ov; bcol = oc; }
            }
            if (lane == 0) out[it] = bcol;
            #pragma unroll
            for (int q = 0; q < 32; q++){
                if (bcol == q * 64 + lane) key[q] = 0;
            }
        }
    }
}

// ---- FP64 re-rank of NCAND candidates -> true top-21, drop first (self) ----
template<int C>
__global__ __launch_bounds__(256, 4) void refine_kernel(const float* __restrict__ F,
                                                        const double* __restrict__ sqd,
                                                        const int* __restrict__ cand,
                                                        int* __restrict__ idxo){
    int orig = blockIdx.x;
    int wg = (orig & 7) * (gridDim.x >> 3) + (orig >> 3);   // bijective: gridDim % 8 == 0
    int tid = threadIdx.x;
    int half = tid >> 5, cl = tid & 31;
    int row = wg * 8 + half;
    int b = row >> 11;
    const float* Fi = F + (size_t)row * FSTR;
    int cj = cand[(size_t)row * NCAND + cl];
    const float* Fj = F + ((size_t)(b << 11) + cj) * FSTR;

    double t0 = 0.0, t1 = 0.0, t2 = 0.0, t3 = 0.0;
    constexpr int nv = C >> 2;       // C % 4 == 3 for all stages
    #pragma unroll
    for (int q = 0; q < nv; q++){
        float4 a  = *(const float4*)(Fi + q * 4);
        float4 bb = *(const float4*)(Fj + q * 4);
        t0 = fma((double)a.x, (double)bb.x, t0);
        t1 = fma((double)a.y, (double)bb.y, t1);
        t2 = fma((double)a.z, (double)bb.z, t2);
        t3 = fma((double)a.w, (double)bb.w, t3);
    }
    constexpr int c0 = nv * 4;
    t0 = fma((double)Fi[c0],     (double)Fj[c0],     t0);
    t1 = fma((double)Fi[c0 + 1], (double)Fj[c0 + 1], t1);
    t2 = fma((double)Fi[c0 + 2], (double)Fj[c0 + 2], t2);
    double t = (t0 + t1) + (t2 + t3);
    double d = 2.0 * t - sqd[row] - sqd[(b << 11) + cj];

    int cnt = 0;
    #pragma unroll
    for (int m = 0; m < NCAND; m++){
        double vm = __shfl(d, m, 32);
        int    im = __shfl(cj, m, 32);
        if (vm > d || (vm == d && im < cj)) cnt++;
    }
    if (cnt >= 1 && cnt <= K)
        idxo[(size_t)row * K + cnt - 1] = cj;
}

// ---- v = Wa*x, u = (Wb-Wa)*x -> layout (b,n,o). ROWS=32/block + register
// double-buffer prefetch of next chunk's W/F (hides L2 latency under FMAs).
// Per-(row,o) accumulation order over c unchanged -> bitwise-identical u,v.
template<int O>
__global__ __launch_bounds__(256) void uv_gemm_kernel(const float* __restrict__ F, const float* __restrict__ W,
                                                      float* __restrict__ u, float* __restrict__ v, int C){
    const int G = 256 / O;          // 4 (O=64) or 2 (O=128)
    const int R = 32 / G;           // 8 or 16
    const int ROWS = 32;
    const int WL = O * 16 / 256;    // 4 or 8 W elems per thread per chunk
    __shared__ float Wa[O][17], Wd[O][17], Fl[ROWS][17];
    int tid = threadIdx.x;
    int o = tid % O, g = tid / O;
    int row0 = blockIdx.x * ROWS;
    float va[R], ua[R];
    #pragma unroll
    for (int r = 0; r < R; r++){ va[r] = 0.f; ua[r] = 0.f; }

    float wa_r[WL], wb_r[WL], f_r[2];
    auto prefetch = [&](int c0){
        #pragma unroll
        for (int i = 0; i < WL; i++){
            int idx = tid + i * 256;
            int oo = idx >> 4, cc = idx & 15; int c = c0 + cc;
            float wa = 0.f, wb = 0.f;
            if (c < C){ wa = W[(size_t)oo * (2 * C) + c]; wb = W[(size_t)oo * (2 * C) + C + c]; }
            wa_r[i] = wa; wb_r[i] = wb;
        }
        #pragma unroll
        for (int i = 0; i < 2; i++){
            int idx = tid + i * 256;
            int rr = idx >> 4, cc = idx & 15; int c = c0 + cc;
            f_r[i] = (c < C) ? F[(size_t)(row0 + rr) * FSTR + c] : 0.f;
        }
    };
    prefetch(0);
    for (int c0 = 0; c0 < C; c0 += 16){
        __syncthreads();
        #pragma unroll
        for (int i = 0; i < WL; i++){
            int idx = tid + i * 256;
            int oo = idx >> 4, cc = idx & 15;
            Wa[oo][cc] = wa_r[i]; Wd[oo][cc] = wb_r[i] - wa_r[i];
        }
        #pragma unroll
        for (int i = 0; i < 2; i++){
            int idx = tid + i * 256;
            int rr = idx >> 4, cc = idx & 15;
            Fl[rr][cc] = f_r[i];
        }
        __syncthreads();
        if (c0 + 16 < C) prefetch(c0 + 16);
        #pragma unroll
        for (int cc = 0; cc < 16; cc++){
            float wa = Wa[o][cc], wd = Wd[o][cc];
            #pragma unroll
            for (int r = 0; r < R; r++){
                float f = Fl[g * R + r][cc];
                va[r] += wa * f; ua[r] += wd * f;
            }
        }
    }
    #pragma unroll
    for (int r = 0; r < R; r++){
        size_t row = (size_t)row0 + g * R + r;
        v[row * O + o] = va[r];
        u[row * O + o] = ua[r];
    }
}

// ---- gather neighbors: per (b,n,o) max/min of v[nbr] + exact channel stats ----
template<int O>
__global__ __launch_bounds__(256) void gather_kernel(const float* __restrict__ v, const float* __restrict__ u,
                                                     const int* __restrict__ idxb, float* __restrict__ mx,
                                                     float* __restrict__ mn, float* __restrict__ ssum,
                                                     float* __restrict__ ssum2){
    const int G = 256 / O;
    const int RPB = (NB * NPTS) / 256;   // 64 rows per block
    int orig = blockIdx.x;
    int wg = (orig & 7) * (gridDim.x >> 3) + (orig >> 3);   // gridDim = 256
    int tid = threadIdx.x;
    int o = tid % O, g = tid / O;
    float csum = 0.f, csq = 0.f;
    for (int it = 0; it < RPB / G; it++){
        int row = wg * RPB + it * G + g;
        int b = row >> 11;
        float uv = u[(size_t)row * O + o];
        const int* ip = idxb + (size_t)row * K;
        float s1 = 0.f, s2 = 0.f, vmax = -INFINITY, vmin = INFINITY;
        for (int j = 0; j < K; j++){
            int nb = ip[j];
            float vv = v[((size_t)(b << 11) + nb) * O + o];
            s1 += vv; s2 += vv * vv;
            vmax = fmaxf(vmax, vv); vmin = fminf(vmin, vv);
        }
        mx[(size_t)row * O + o] = vmax;
        mn[(size_t)row * O + o] = vmin;
        csum += s1 + (float)K * uv;
        csq  += s2 + 2.f * uv * s1 + (float)K * uv * uv;
    }
    __shared__ float red[256];
    red[tid] = csum; __syncthreads();
    if (tid < O){ float t = 0.f; for (int gg = 0; gg < G; gg++) t += red[gg * O + tid]; atomicAdd(&ssum[tid], t); }
    __syncthreads();
    red[tid] = csq; __syncthreads();
    if (tid < O){ float t = 0.f; for (int gg = 0; gg < G; gg++) t += red[gg * O + tid]; atomicAdd(&ssum2[tid], t); }
}

__global__ void finalize_kernel(const float* __restrict__ ssum, const float* __restrict__ ssum2,
                                const float* __restrict__ gg, const float* __restrict__ bb,
                                float* __restrict__ scale, float* __restrict__ shift, int O, float inv_count){
    int o = blockIdx.x * blockDim.x + threadIdx.x;
    if (o >= O) return;
    float mean = ssum[o] * inv_count;
    float var = fmaxf(ssum2[o] * inv_count - mean * mean, 0.f);
    float sc = gg[o] * rsqrtf(var + EPSV);
    scale[o] = sc;
    shift[o] = bb[o] - mean * sc;
}

template<int O>
__global__ __launch_bounds__(256) void apply_kernel(const float* __restrict__ u, const float* __restrict__ mx,
                                                    const float* __restrict__ mn, const float* __restrict__ scale,
                                                    const float* __restrict__ shift, float* __restrict__ F,
                                                    unsigned short* __restrict__ Fh, unsigned short* __restrict__ Fl,
                                                    int coff){
    int gid = blockIdx.x * 256 + threadIdx.x;
    int row = gid / O, o = gid % O;
    float sc = scale[o];
    float sel = sc >= 0.f ? mx[gid] : mn[gid];
    float val = lrelu((u[gid] + sel) * sc + shift[o]);
    F[(size_t)row * FSTR + coff + o] = val;
    unsigned short h, l; split_bf(val, h, l);
    Fh[(size_t)row * CPAD + coff + o] = h;
    Fl[(size_t)row * CPAD + coff + o] = l;
}

// ---- final GEMM via bf16x3 MFMA, fused BN-stat + max/min epilogue ----
__global__ __launch_bounds__(256) void final_mfma_kernel(
    const unsigned short* __restrict__ Wh, const unsigned short* __restrict__ Wl,
    const unsigned short* __restrict__ Fh, const unsigned short* __restrict__ Fl,
    float* __restrict__ ssum, float* __restrict__ ssum2,
    unsigned* __restrict__ maxk, unsigned* __restrict__ mink)
{
    __shared__ __align__(16) unsigned short Ah[128][40], Al[128][40], Bh[128][40], Bl[128][40];
    int tid = threadIdx.x;
    int o0 = blockIdx.x * 128, n0 = blockIdx.y * 128, b = blockIdx.z;
    const size_t fbase = (size_t)b * NPTS * CPAD;
    int lane = tid & 63, wave = tid >> 6;
    int wr = wave >> 1, wc = wave & 1;
    int fr = lane & 15, kg = lane >> 4;
    int sr = tid >> 1, sh = (tid & 1) * 16;

    f32x4 acc[4][4];
    #pragma unroll
    for (int a = 0; a < 4; a++)
        #pragma unroll
        for (int c = 0; c < 4; c++) acc[a][c] = (f32x4){0.f, 0.f, 0.f, 0.f};

    for (int k0 = 0; k0 < CPAD; k0 += 32){
        __syncthreads();
        {
            const unsigned short* pAh = Wh + (size_t)(o0 + sr) * CPAD + k0 + sh;
            const unsigned short* pAl = Wl + (size_t)(o0 + sr) * CPAD + k0 + sh;
            const unsigned short* pBh = Fh + fbase + (size_t)(n0 + sr) * CPAD + k0 + sh;
            const unsigned short* pBl = Fl + fbase + (size_t)(n0 + sr) * CPAD + k0 + sh;
            uint4 t0 = *(const uint4*)pAh; uint4 t1 = *(const uint4*)(pAh + 8);
            *(uint4*)&Ah[sr][sh] = t0;    *(uint4*)&Ah[sr][sh + 8] = t1;
            uint4 t2 = *(const uint4*)pAl; uint4 t3 = *(const uint4*)(pAl + 8);
            *(uint4*)&Al[sr][sh] = t2;    *(uint4*)&Al[sr][sh + 8] = t3;
            uint4 t4 = *(const uint4*)pBh; uint4 t5 = *(const uint4*)(pBh + 8);
            *(uint4*)&Bh[sr][sh] = t4;    *(uint4*)&Bh[sr][sh + 8] = t5;
            uint4 t6 = *(const uint4*)pBl; uint4 t7 = *(const uint4*)(pBl + 8);
            *(uint4*)&Bl[sr][sh] = t6;    *(uint4*)&Bl[sr][sh + 8] = t7;
        }
        __syncthreads();
        short8 afh[4], afl[4], bfh[4], bfl[4];
        #pragma unroll
        for (int mi = 0; mi < 4; mi++){
            afh[mi] = *(const short8*)&Ah[wr * 64 + mi * 16 + fr][kg * 8];
            afl[mi] = *(const short8*)&Al[wr * 64 + mi * 16 + fr][kg * 8];
            bfh[mi] = *(const short8*)&Bh[wc * 64 + mi * 16 + fr][kg * 8];
            bfl[mi] = *(const short8*)&Bl[wc * 64 + mi * 16 + fr][kg * 8];
        }
        #pragma unroll
        for (int mi = 0; mi < 4; mi++)
            #pragma unroll
            for (int ni = 0; ni < 4; ni++){
                acc[mi][ni] = __builtin_amdgcn_mfma_f32_16x16x32_bf16(afh[mi], bfh[ni], acc[mi][ni], 0, 0, 0);
                acc[mi][ni] = __builtin_amdgcn_mfma_f32_16x16x32_bf16(afh[mi], bfl[ni], acc[mi][ni], 0, 0, 0);
                acc[mi][ni] = __builtin_amdgcn_mfma_f32_16x16x32_bf16(afl[mi], bfh[ni], acc[mi][ni], 0, 0, 0);
            }
    }
    #pragma unroll
    for (int mi = 0; mi < 4; mi++){
        #pragma unroll
        for (int r = 0; r < 4; r++){
            int o = o0 + wr * 64 + mi * 16 + kg * 4 + r;
            float s = 0.f, s2 = 0.f, mxv = -INFINITY, mnv = INFINITY;
            #pragma unroll
            for (int ni = 0; ni < 4; ni++){
                float y = acc[mi][ni][r];
                s += y; s2 += y * y;
                mxv = fmaxf(mxv, y); mnv = fminf(mnv, y);
            }
            #pragma unroll
            for (int off = 1; off < 16; off <<= 1){
                s  += __shfl_xor(s, off);
                s2 += __shfl_xor(s2, off);
                mxv = fmaxf(mxv, __shfl_xor(mxv, off));
                mnv = fminf(mnv, __shfl_xor(mnv, off));
            }
            if (fr == 0){
                atomicAdd(&ssum[o], s);
                atomicAdd(&ssum2[o], s2);
                atomicMax(&maxk[b * 1024 + o], fkey(mxv));
                atomicMin(&mink[b * 1024 + o], fkey(mnv));
            }
        }
    }
}

__global__ void final_out_kernel(const unsigned* __restrict__ maxk, const unsigned* __restrict__ mink,
                                 const float* __restrict__ ssum, const float* __restrict__ ssum2,
                                 const float* __restrict__ g5, const float* __restrict__ b5,
                                 float* __restrict__ out){
    int gid = blockIdx.x * 256 + threadIdx.x;
    if (gid >= NB * 1024) return;
    int o = gid & 1023;
    const float inv = 1.f / (NB * NPTS);
    float mean = ssum[o] * inv;
    float var = fmaxf(ssum2[o] * inv - mean * mean, 0.f);
    float sc = g5[o] * rsqrtf(var + EPSV);
    float sh = b5[o] - mean * sc;
    float sel = sc >= 0.f ? funkey(maxk[gid]) : funkey(mink[gid]);
    out[gid] = lrelu(sel * sc + sh);
}

extern "C" void kernel_launch(void* const* d_in, const int* in_sizes, int n_in,
                              void* d_out, int out_size, void* d_ws, size_t ws_size,
                              hipStream_t stream){
    (void)in_sizes; (void)n_in; (void)out_size;
    const float* x = (const float*)d_in[0];
    const float* Ws[5] = {(const float*)d_in[1], (const float*)d_in[4], (const float*)d_in[7],
                          (const float*)d_in[10], (const float*)d_in[13]};
    const float* Gs[5] = {(const float*)d_in[2], (const float*)d_in[5], (const float*)d_in[8],
                          (const float*)d_in[11], (const float*)d_in[14]};
    const float* Bs[5] = {(const float*)d_in[3], (const float*)d_in[6], (const float*)d_in[9],
                          (const float*)d_in[12], (const float*)d_in[15]};
    float* out = (float*)d_out;

    char* base = (char*)d_ws;
    size_t off = 0;
    auto alloc = [&](size_t bytes) -> char* {
        char* p = base + off;
        off = (off + bytes + 255) & ~(size_t)255;
        return p;
    };
    float*          F    = (float*)alloc((size_t)NB * NPTS * FSTR * 4);
    unsigned short* Fh   = (unsigned short*)alloc((size_t)NB * NPTS * CPAD * 2);
    unsigned short* Fl   = (unsigned short*)alloc((size_t)NB * NPTS * CPAD * 2);
    unsigned short* W5h  = (unsigned short*)alloc((size_t)1024 * CPAD * 2);
    unsigned short* W5l  = (unsigned short*)alloc((size_t)1024 * CPAD * 2);
    float*          sq   = (float*)alloc((size_t)NB * NPTS * 4);
    double*         sqd  = (double*)alloc((size_t)NB * NPTS * 8);
    int*            cand = (int*)  alloc((size_t)NB * NPTS * NCAND * 4);
    int*            idxb = (int*)  alloc((size_t)NB * NPTS * K * 4);
    float*          mx   = (float*)alloc((size_t)NB * NPTS * 128 * 4);
    float*          mn   = (float*)alloc((size_t)NB * NPTS * 128 * 4);
    float*          ssum = (float*)alloc(1024 * 4);   // ssum2 contiguous after
    float*          ssum2= (float*)alloc(1024 * 4);
    float*          scale= (float*)alloc(1024 * 4);
    float*          shift= (float*)alloc(1024 * 4);
    unsigned*       maxk = (unsigned*)alloc(NB * 1024 * 4);
    unsigned*       mink = (unsigned*)alloc(NB * 1024 * 4);
    // union region: dist (bz batches) overlaps u,v (used in disjoint phases)
    char* R = base + off;
    size_t avail = (ws_size > off) ? ws_size - off : 0;
    const size_t DSZ = (size_t)NPTS * NPTS * 4;
    int bz = 1;
    if (avail >= 8 * DSZ + 256) bz = 8;
    else if (avail >= 4 * DSZ + 256) bz = 4;
    else if (avail >= 2 * DSZ + 256) bz = 2;
    float* dist = (float*)R;
    float* u    = (float*)R;
    float* v    = (float*)(R + (size_t)NB * NPTS * 128 * 4);

    hipMemsetAsync(Fh, 0, (size_t)NB * NPTS * CPAD * 2, stream);
    hipMemsetAsync(Fl, 0, (size_t)NB * NPTS * CPAD * 2, stream);
    copy_x_kernel<<<(NB * NPTS + 255) / 256, 256, 0, stream>>>(x, F, Fh, Fl);
    convW_kernel<<<(1024 * CPAD + 255) / 256, 256, 0, stream>>>(Ws[4], W5h, W5l);

    const int Cs[4] = {3, 67, 131, 195};
    const int Os[4] = {64, 64, 64, 128};
    for (int s = 0; s < 4; s++){
        int C = Cs[s], O = Os[s];
        int Kp = (C + 31) & ~31;
        sqnorm2_kernel<<<NB * NPTS / 4, 256, 0, stream>>>(F, sq, sqd, C);
        for (int b0 = 0; b0 < NB; b0 += bz){
            dist_mfma_kernel<<<dim3(NPTS / 128, NPTS / 128, bz), 256, 0, stream>>>(Fh, Fl, sq, dist, b0, Kp);
            topk_kernel<<<bz * NPTS / 4, 256, 0, stream>>>(dist, cand, b0 * NPTS);
        }
        switch (C){
            case 3:   refine_kernel<3>  <<<NB * NPTS / 8, 256, 0, stream>>>(F, sqd, cand, idxb); break;
            case 67:  refine_kernel<67> <<<NB * NPTS / 8, 256, 0, stream>>>(F, sqd, cand, idxb); break;
            case 131: refine_kernel<131><<<NB * NPTS / 8, 256, 0, stream>>>(F, sqd, cand, idxb); break;
            default:  refine_kernel<195><<<NB * NPTS / 8, 256, 0, stream>>>(F, sqd, cand, idxb); break;
        }
        hipMemsetAsync(ssum, 0, 2048 * 4, stream);   // ssum + ssum2 (contiguous)
        if (O == 64){
            uv_gemm_kernel<64><<<NB * NPTS / 32, 256, 0, stream>>>(F, Ws[s], u, v, C);
            gather_kernel<64><<<256, 256, 0, stream>>>(v, u, idxb, mx, mn, ssum, ssum2);
            finalize_kernel<<<1, 64, 0, stream>>>(ssum, ssum2, Gs[s], Bs[s], scale, shift, 64,
                                                  1.f / ((float)NB * NPTS * K));
            apply_kernel<64><<<NB * NPTS * 64 / 256, 256, 0, stream>>>(u, mx, mn, scale, shift, F, Fh, Fl, C);
        } else {
            uv_gemm_kernel<128><<<NB * NPTS / 32, 256, 0, stream>>>(F, Ws[s], u, v, C);
            gather_kernel<128><<<256, 256, 0, stream>>>(v, u, idxb, mx, mn, ssum, ssum2);
            finalize_kernel<<<1, 128, 0, stream>>>(ssum, ssum2, Gs[s], Bs[s], scale, shift, 128,
                                                   1.f / ((float)NB * NPTS * K));
            apply_kernel<128><<<NB * NPTS * 128 / 256, 256, 0, stream>>>(u, mx, mn, scale, shift, F, Fh, Fl, C);
        }
    }

    hipMemsetAsync(ssum, 0, 2048 * 4, stream);
    hipMemsetAsync(maxk, 0, NB * 1024 * 4, stream);
    hipMemsetAsync(mink, 0xFF, NB * 1024 * 4, stream);
    final_mfma_kernel<<<dim3(1024 / 128, NPTS / 128, NB), 256, 0, stream>>>(W5h, W5l, Fh, Fl,
                                                                            ssum, ssum2, maxk, mink);
    final_out_kernel<<<NB * 1024 / 256, 256, 0, stream>>>(maxk, mink, ssum, ssum2, Gs[4], Bs[4], out);
}

// Round 12
// 891.635 us; speedup vs baseline: 2.3818x; 1.0176x over previous
//
#include <hip/hip_runtime.h>
#include <math.h>

#define NB 8
#define NPTS 2048
#define NF 323
#define FSTR 328      // fp32 feature row stride (16B-aligned rows)
#define CPAD 352      // bf16 feature row stride (multiple of 32, >= 323)
#define K 20
#define EPSV 1e-5f
#define SLOPE 0.2f
#define NCAND 32      // approx candidates kept for exact re-rank (>= K+1)

typedef __attribute__((ext_vector_type(8))) short short8;
typedef __attribute__((ext_vector_type(4))) float f32x4;

__device__ __forceinline__ float lrelu(float x){ return x >= 0.f ? x : SLOPE * x; }

__device__ __forceinline__ unsigned fkey(float f){
    unsigned u = __float_as_uint(f);
    return (u & 0x80000000u) ? ~u : (u | 0x80000000u);
}
__device__ __forceinline__ float funkey(unsigned k){
    return (k & 0x80000000u) ? __uint_as_float(k ^ 0x80000000u) : __uint_as_float(~k);
}

__device__ __forceinline__ unsigned short f2bf_rne(float x){
    unsigned u = __float_as_uint(x);
    unsigned r = u + 0x7fffu + ((u >> 16) & 1u);
    return (unsigned short)(r >> 16);
}
__device__ __forceinline__ void split_bf(float x, unsigned short& h, unsigned short& l){
    h = f2bf_rne(x);
    float hf = __uint_as_float(((unsigned)h) << 16);
    l = f2bf_rne(x - hf);
}

// ---- x (B,3,N) -> F (B*N,FSTR) fp32 + Fh/Fl bf16 planes, channels [0,3) ----
__global__ void copy_x_kernel(const float* __restrict__ x, float* __restrict__ F,
                              unsigned short* __restrict__ Fh, unsigned short* __restrict__ Fl){
    int gid = blockIdx.x * 256 + threadIdx.x;
    if (gid >= NB * NPTS) return;
    int b = gid / NPTS, n = gid % NPTS;
    float* dst = F + (size_t)gid * FSTR;
    #pragma unroll
    for (int c = 0; c < 3; c++){
        float v = x[((size_t)b * 3 + c) * NPTS + n];
        dst[c] = v;
        unsigned short h, l; split_bf(v, h, l);
        Fh[(size_t)gid * CPAD + c] = h;
        Fl[(size_t)gid * CPAD + c] = l;
    }
}

// ---- per-point squared norms: fp32 (approx dist) + fp64 (exact re-rank), fused ----
__global__ __launch_bounds__(256) void sqnorm2_kernel(const float* __restrict__ F, float* __restrict__ sq,
                                                      double* __restrict__ sqd, int C){
    int row = blockIdx.x * 4 + (threadIdx.x >> 6);
    int lane = threadIdx.x & 63;
    const float* f = F + (size_t)row * FSTR;
    float s = 0.f;
    double sd = 0.0;
    for (int c = lane; c < C; c += 64){
        float t = f[c];
        s += t * t;
        double td = (double)t;
        sd = fma(td, td, sd);
    }
    #pragma unroll
    for (int off = 32; off; off >>= 1) s += __shfl_xor(s, off);
    #pragma unroll
    for (int off = 32; off; off >>= 1) sd += __shfl_xor(sd, off);
    if (lane == 0){ sq[row] = s; sqd[row] = sd; }
}

// ---- W5 -> bf16 hi/lo, padded to CPAD ----
__global__ void convW_kernel(const float* __restrict__ W5, unsigned short* __restrict__ Wh,
                             unsigned short* __restrict__ Wl){
    int gid = blockIdx.x * 256 + threadIdx.x;
    if (gid >= 1024 * CPAD) return;
    int o = gid / CPAD, c = gid % CPAD;
    float w = (c < NF) ? W5[(size_t)o * NF + c] : 0.f;
    unsigned short h, l; split_bf(w, h, l);
    Wh[gid] = h; Wl[gid] = l;
}

// ---- approx inv-dist Gram tile via bf16x3 MFMA: 128x128 per block, 4 waves ----
__global__ __launch_bounds__(256) void dist_mfma_kernel(
    const unsigned short* __restrict__ Fh, const unsigned short* __restrict__ Fl,
    const float* __restrict__ sq, float* __restrict__ dist, int b0, int Kp)
{
    __shared__ __align__(16) unsigned short Ah[128][40], Al[128][40], Bh[128][40], Bl[128][40];
    int tid = threadIdx.x;
    int b = b0 + blockIdx.z;
    int i0 = blockIdx.y * 128, j0 = blockIdx.x * 128;
    const size_t fbase = (size_t)b * NPTS * CPAD;
    int lane = tid & 63, wave = tid >> 6;
    int wr = wave >> 1, wc = wave & 1;
    int fr = lane & 15, kg = lane >> 4;
    int sr = tid >> 1, sh = (tid & 1) * 16;

    f32x4 acc[4][4];
    #pragma unroll
    for (int a = 0; a < 4; a++)
        #pragma unroll
        for (int c = 0; c < 4; c++) acc[a][c] = (f32x4){0.f, 0.f, 0.f, 0.f};

    for (int k0 = 0; k0 < Kp; k0 += 32){
        __syncthreads();
        {
            const unsigned short* pAh = Fh + fbase + (size_t)(i0 + sr) * CPAD + k0 + sh;
            const unsigned short* pAl = Fl + fbase + (size_t)(i0 + sr) * CPAD + k0 + sh;
            const unsigned short* pBh = Fh + fbase + (size_t)(j0 + sr) * CPAD + k0 + sh;
            const unsigned short* pBl = Fl + fbase + (size_t)(j0 + sr) * CPAD + k0 + sh;
            uint4 t0 = *(const uint4*)pAh; uint4 t1 = *(const uint4*)(pAh + 8);
            *(uint4*)&Ah[sr][sh] = t0;    *(uint4*)&Ah[sr][sh + 8] = t1;
            uint4 t2 = *(const uint4*)pAl; uint4 t3 = *(const uint4*)(pAl + 8);
            *(uint4*)&Al[sr][sh] = t2;    *(uint4*)&Al[sr][sh + 8] = t3;
            uint4 t4 = *(const uint4*)pBh; uint4 t5 = *(const uint4*)(pBh + 8);
            *(uint4*)&Bh[sr][sh] = t4;    *(uint4*)&Bh[sr][sh + 8] = t5;
            uint4 t6 = *(const uint4*)pBl; uint4 t7 = *(const uint4*)(pBl + 8);
            *(uint4*)&Bl[sr][sh] = t6;    *(uint4*)&Bl[sr][sh + 8] = t7;
        }
        __syncthreads();
        short8 afh[4], afl[4], bfh[4], bfl[4];
        #pragma unroll
        for (int mi = 0; mi < 4; mi++){
            afh[mi] = *(const short8*)&Ah[wr * 64 + mi * 16 + fr][kg * 8];
            afl[mi] = *(const short8*)&Al[wr * 64 + mi * 16 + fr][kg * 8];
            bfh[mi] = *(const short8*)&Bh[wc * 64 + mi * 16 + fr][kg * 8];
            bfl[mi] = *(const short8*)&Bl[wc * 64 + mi * 16 + fr][kg * 8];
        }
        #pragma unroll
        for (int mi = 0; mi < 4; mi++)
            #pragma unroll
            for (int ni = 0; ni < 4; ni++){
                acc[mi][ni] = __builtin_amdgcn_mfma_f32_16x16x32_bf16(afh[mi], bfh[ni], acc[mi][ni], 0, 0, 0);
                acc[mi][ni] = __builtin_amdgcn_mfma_f32_16x16x32_bf16(afh[mi], bfl[ni], acc[mi][ni], 0, 0, 0);
                acc[mi][ni] = __builtin_amdgcn_mfma_f32_16x16x32_bf16(afl[mi], bfh[ni], acc[mi][ni], 0, 0, 0);
            }
    }
    const float* sqb = sq + (b << 11);
    float* dbase = dist + (size_t)blockIdx.z * NPTS * NPTS;
    #pragma unroll
    for (int mi = 0; mi < 4; mi++){
        #pragma unroll
        for (int r = 0; r < 4; r++){
            int i = i0 + wr * 64 + mi * 16 + kg * 4 + r;
            float si = sqb[i];
            float* dr = dbase + (size_t)i * NPTS;
            #pragma unroll
            for (int ni = 0; ni < 4; ni++){
                int j = j0 + wc * 64 + ni * 16 + fr;
                dr[j] = 2.f * acc[mi][ni][r] - si - sqb[j];
            }
        }
    }
}

// ---- approx top-NCAND per row via fkey bit-descent + rank compaction ----
__global__ __launch_bounds__(256) void topk_kernel(const float* __restrict__ dist, int* __restrict__ cand,
                                                   int chunk_base){
    int w = threadIdx.x >> 6;
    int lrow = blockIdx.x * 4 + w;
    int lane = threadIdx.x & 63;
    const float* D = dist + (size_t)lrow * NPTS;
    unsigned key[32];
    #pragma unroll
    for (int t = 0; t < 32; t++) key[t] = fkey(D[t * 64 + lane]);
    int* out = cand + (size_t)(chunk_base + lrow) * NCAND;

    // bit-descent: find prefix p with NCAND <= #{key >= p} <= 64
    unsigned p = 0;
    int cl_acc = 32;
    int ct_acc = NPTS;
    for (int bit = 31; bit >= 0; --bit){
        if (ct_acc <= 64) break;
        unsigned pp = p | (1u << bit);
        int cl = 0;
        #pragma unroll
        for (int t = 0; t < 32; t++) cl += (key[t] >= pp) ? 1 : 0;
        int ct = cl;
        #pragma unroll
        for (int off = 1; off < 64; off <<= 1) ct += __shfl_xor(ct, off);
        if (ct >= NCAND){ p = pp; cl_acc = cl; ct_acc = ct; }
    }

    __shared__ unsigned long long spk[4][64];
    if (ct_acc <= 64){
        int ex = cl_acc;
        #pragma unroll
        for (int off = 1; off < 64; off <<= 1){
            int tu = __shfl_up(ex, off);
            if (lane >= off) ex += tu;
        }
        ex -= cl_acc;
        spk[w][lane] = 0ull;
        int k = ex;
        #pragma unroll
        for (int t = 0; t < 32; t++){
            if (key[t] >= p){
                unsigned col = (unsigned)(t * 64 + lane);
                spk[w][k] = ((unsigned long long)key[t] << 32) | (unsigned)(~col);
                k++;
            }
        }
        asm volatile("s_waitcnt lgkmcnt(0)" ::: "memory");
        unsigned long long mypk = spk[w][lane];
        int rank = 0;
        #pragma unroll
        for (int m = 0; m < 64; m++){
            unsigned long long pm = spk[w][m];
            rank += (pm > mypk) ? 1 : 0;
        }
        if (lane < ct_acc && rank < NCAND)
            out[rank] = (int)(~(unsigned)(mypk & 0xFFFFFFFFu));
    } else {
        for (int it = 0; it < NCAND; it++){
            unsigned bv = key[0]; int bt = 0;
            #pragma unroll
            for (int t = 1; t < 32; t++){ if (key[t] > bv){ bv = key[t]; bt = t; } }
            int bcol = bt * 64 + lane;
            #pragma unroll
            for (int off = 1; off < 64; off <<= 1){
                unsigned ov = __shfl_xor(bv, off);
                int      oc = __shfl_xor(bcol, off);
                if (ov > bv || (ov == bv && oc < bcol)){ bv = ov; bcol = oc; }
            }
            if (lane == 0) out[it] = bcol;
            #pragma unroll
            for (int q = 0; q < 32; q++){
                if (bcol == q * 64 + lane) key[q] = 0;
            }
        }
    }
}

// ---- FP64 re-rank of NCAND candidates -> true top-21, drop first (self) ----
// One lane per candidate, XCD swizzle, template-C unroll, and 8-deep explicit
// load batching (a[8]/bb[8] in flight -> MLP 8; round-11 was MLP~1 at 36 VGPR).
// FMA order (ascending q into t[q%4]) IDENTICAL to rounds 5-11 -> bitwise-same.
template<int C>
__global__ __launch_bounds__(256, 2) void refine_kernel(const float* __restrict__ F,
                                                        const double* __restrict__ sqd,
                                                        const int* __restrict__ cand,
                                                        int* __restrict__ idxo){
    int orig = blockIdx.x;
    int wg = (orig & 7) * (gridDim.x >> 3) + (orig >> 3);   // bijective: gridDim % 8 == 0
    int tid = threadIdx.x;
    int half = tid >> 5, cl = tid & 31;
    int row = wg * 8 + half;
    int b = row >> 11;
    const float* Fi = F + (size_t)row * FSTR;
    int cj = cand[(size_t)row * NCAND + cl];
    const float* Fj = F + ((size_t)(b << 11) + cj) * FSTR;

    double t0 = 0.0, t1 = 0.0, t2 = 0.0, t3 = 0.0;
    constexpr int nv = C >> 2;       // C % 4 == 3 for all stages
    #pragma unroll
    for (int g0 = 0; g0 < nv; g0 += 8){
        float4 a[8], bb[8];
        #pragma unroll
        for (int i = 0; i < 8; i++){
            int q = g0 + i;
            if (q < nv){
                a[i]  = *(const float4*)(Fi + q * 4);
                bb[i] = *(const float4*)(Fj + q * 4);
            }
        }
        #pragma unroll
        for (int i = 0; i < 8; i++){
            int q = g0 + i;
            if (q < nv){
                t0 = fma((double)a[i].x, (double)bb[i].x, t0);
                t1 = fma((double)a[i].y, (double)bb[i].y, t1);
                t2 = fma((double)a[i].z, (double)bb[i].z, t2);
                t3 = fma((double)a[i].w, (double)bb[i].w, t3);
            }
        }
    }
    constexpr int c0 = nv * 4;
    t0 = fma((double)Fi[c0],     (double)Fj[c0],     t0);
    t1 = fma((double)Fi[c0 + 1], (double)Fj[c0 + 1], t1);
    t2 = fma((double)Fi[c0 + 2], (double)Fj[c0 + 2], t2);
    double t = (t0 + t1) + (t2 + t3);
    double d = 2.0 * t - sqd[row] - sqd[(b << 11) + cj];

    int cnt = 0;
    #pragma unroll
    for (int m = 0; m < NCAND; m++){
        double vm = __shfl(d, m, 32);
        int    im = __shfl(cj, m, 32);
        if (vm > d || (vm == d && im < cj)) cnt++;
    }
    if (cnt >= 1 && cnt <= K)
        idxo[(size_t)row * K + cnt - 1] = cj;
}

// ---- v = Wa*x, u = (Wb-Wa)*x -> layout (b,n,o). ROWS=32/block + register
// double-buffer prefetch of next chunk's W/F (hides L2 latency under FMAs).
template<int O>
__global__ __launch_bounds__(256) void uv_gemm_kernel(const float* __restrict__ F, const float* __restrict__ W,
                                                      float* __restrict__ u, float* __restrict__ v, int C){
    const int G = 256 / O;          // 4 (O=64) or 2 (O=128)
    const int R = 32 / G;           // 8 or 16
    const int ROWS = 32;
    const int WL = O * 16 / 256;    // 4 or 8 W elems per thread per chunk
    __shared__ float Wa[O][17], Wd[O][17], Fl[ROWS][17];
    int tid = threadIdx.x;
    int o = tid % O, g = tid / O;
    int row0 = blockIdx.x * ROWS;
    float va[R], ua[R];
    #pragma unroll
    for (int r = 0; r < R; r++){ va[r] = 0.f; ua[r] = 0.f; }

    float wa_r[WL], wb_r[WL], f_r[2];
    auto prefetch = [&](int c0){
        #pragma unroll
        for (int i = 0; i < WL; i++){
            int idx = tid + i * 256;
            int oo = idx >> 4, cc = idx & 15; int c = c0 + cc;
            float wa = 0.f, wb = 0.f;
            if (c < C){ wa = W[(size_t)oo * (2 * C) + c]; wb = W[(size_t)oo * (2 * C) + C + c]; }
            wa_r[i] = wa; wb_r[i] = wb;
        }
        #pragma unroll
        for (int i = 0; i < 2; i++){
            int idx = tid + i * 256;
            int rr = idx >> 4, cc = idx & 15; int c = c0 + cc;
            f_r[i] = (c < C) ? F[(size_t)(row0 + rr) * FSTR + c] : 0.f;
        }
    };
    prefetch(0);
    for (int c0 = 0; c0 < C; c0 += 16){
        __syncthreads();
        #pragma unroll
        for (int i = 0; i < WL; i++){
            int idx = tid + i * 256;
            int oo = idx >> 4, cc = idx & 15;
            Wa[oo][cc] = wa_r[i]; Wd[oo][cc] = wb_r[i] - wa_r[i];
        }
        #pragma unroll
        for (int i = 0; i < 2; i++){
            int idx = tid + i * 256;
            int rr = idx >> 4, cc = idx & 15;
            Fl[rr][cc] = f_r[i];
        }
        __syncthreads();
        if (c0 + 16 < C) prefetch(c0 + 16);
        #pragma unroll
        for (int cc = 0; cc < 16; cc++){
            float wa = Wa[o][cc], wd = Wd[o][cc];
            #pragma unroll
            for (int r = 0; r < R; r++){
                float f = Fl[g * R + r][cc];
                va[r] += wa * f; ua[r] += wd * f;
            }
        }
    }
    #pragma unroll
    for (int r = 0; r < R; r++){
        size_t row = (size_t)row0 + g * R + r;
        v[row * O + o] = va[r];
        u[row * O + o] = ua[r];
    }
}

// ---- gather neighbors: per (b,n,o) max/min of v[nbr] + exact channel stats ----
template<int O>
__global__ __launch_bounds__(256) void gather_kernel(const float* __restrict__ v, const float* __restrict__ u,
                                                     const int* __restrict__ idxb, float* __restrict__ mx,
                                                     float* __restrict__ mn, float* __restrict__ ssum,
                                                     float* __restrict__ ssum2){
    const int G = 256 / O;
    const int RPB = (NB * NPTS) / 256;   // 64 rows per block
    int orig = blockIdx.x;
    int wg = (orig & 7) * (gridDim.x >> 3) + (orig >> 3);   // gridDim = 256
    int tid = threadIdx.x;
    int o = tid % O, g = tid / O;
    float csum = 0.f, csq = 0.f;
    for (int it = 0; it < RPB / G; it++){
        int row = wg * RPB + it * G + g;
        int b = row >> 11;
        float uv = u[(size_t)row * O + o];
        const int* ip = idxb + (size_t)row * K;
        float s1 = 0.f, s2 = 0.f, vmax = -INFINITY, vmin = INFINITY;
        for (int j = 0; j < K; j++){
            int nb = ip[j];
            float vv = v[((size_t)(b << 11) + nb) * O + o];
            s1 += vv; s2 += vv * vv;
            vmax = fmaxf(vmax, vv); vmin = fminf(vmin, vv);
        }
        mx[(size_t)row * O + o] = vmax;
        mn[(size_t)row * O + o] = vmin;
        csum += s1 + (float)K * uv;
        csq  += s2 + 2.f * uv * s1 + (float)K * uv * uv;
    }
    __shared__ float red[256];
    red[tid] = csum; __syncthreads();
    if (tid < O){ float t = 0.f; for (int gg = 0; gg < G; gg++) t += red[gg * O + tid]; atomicAdd(&ssum[tid], t); }
    __syncthreads();
    red[tid] = csq; __syncthreads();
    if (tid < O){ float t = 0.f; for (int gg = 0; gg < G; gg++) t += red[gg * O + tid]; atomicAdd(&ssum2[tid], t); }
}

__global__ void finalize_kernel(const float* __restrict__ ssum, const float* __restrict__ ssum2,
                                const float* __restrict__ gg, const float* __restrict__ bb,
                                float* __restrict__ scale, float* __restrict__ shift, int O, float inv_count){
    int o = blockIdx.x * blockDim.x + threadIdx.x;
    if (o >= O) return;
    float mean = ssum[o] * inv_count;
    float var = fmaxf(ssum2[o] * inv_count - mean * mean, 0.f);
    float sc = gg[o] * rsqrtf(var + EPSV);
    scale[o] = sc;
    shift[o] = bb[o] - mean * sc;
}

template<int O>
__global__ __launch_bounds__(256) void apply_kernel(const float* __restrict__ u, const float* __restrict__ mx,
                                                    const float* __restrict__ mn, const float* __restrict__ scale,
                                                    const float* __restrict__ shift, float* __restrict__ F,
                                                    unsigned short* __restrict__ Fh, unsigned short* __restrict__ Fl,
                                                    int coff){
    int gid = blockIdx.x * 256 + threadIdx.x;
    int row = gid / O, o = gid % O;
    float sc = scale[o];
    float sel = sc >= 0.f ? mx[gid] : mn[gid];
    float val = lrelu((u[gid] + sel) * sc + shift[o]);
    F[(size_t)row * FSTR + coff + o] = val;
    unsigned short h, l; split_bf(val, h, l);
    Fh[(size_t)row * CPAD + coff + o] = h;
    Fl[(size_t)row * CPAD + coff + o] = l;
}

// ---- final GEMM via bf16x3 MFMA, fused BN-stat + max/min epilogue ----
__global__ __launch_bounds__(256) void final_mfma_kernel(
    const unsigned short* __restrict__ Wh, const unsigned short* __restrict__ Wl,
    const unsigned short* __restrict__ Fh, const unsigned short* __restrict__ Fl,
    float* __restrict__ ssum, float* __restrict__ ssum2,
    unsigned* __restrict__ maxk, unsigned* __restrict__ mink)
{
    __shared__ __align__(16) unsigned short Ah[128][40], Al[128][40], Bh[128][40], Bl[128][40];
    int tid = threadIdx.x;
    int o0 = blockIdx.x * 128, n0 = blockIdx.y * 128, b = blockIdx.z;
    const size_t fbase = (size_t)b * NPTS * CPAD;
    int lane = tid & 63, wave = tid >> 6;
    int wr = wave >> 1, wc = wave & 1;
    int fr = lane & 15, kg = lane >> 4;
    int sr = tid >> 1, sh = (tid & 1) * 16;

    f32x4 acc[4][4];
    #pragma unroll
    for (int a = 0; a < 4; a++)
        #pragma unroll
        for (int c = 0; c < 4; c++) acc[a][c] = (f32x4){0.f, 0.f, 0.f, 0.f};

    for (int k0 = 0; k0 < CPAD; k0 += 32){
        __syncthreads();
        {
            const unsigned short* pAh = Wh + (size_t)(o0 + sr) * CPAD + k0 + sh;
            const unsigned short* pAl = Wl + (size_t)(o0 + sr) * CPAD + k0 + sh;
            const unsigned short* pBh = Fh + fbase + (size_t)(n0 + sr) * CPAD + k0 + sh;
            const unsigned short* pBl = Fl + fbase + (size_t)(n0 + sr) * CPAD + k0 + sh;
            uint4 t0 = *(const uint4*)pAh; uint4 t1 = *(const uint4*)(pAh + 8);
            *(uint4*)&Ah[sr][sh] = t0;    *(uint4*)&Ah[sr][sh + 8] = t1;
            uint4 t2 = *(const uint4*)pAl; uint4 t3 = *(const uint4*)(pAl + 8);
            *(uint4*)&Al[sr][sh] = t2;    *(uint4*)&Al[sr][sh + 8] = t3;
            uint4 t4 = *(const uint4*)pBh; uint4 t5 = *(const uint4*)(pBh + 8);
            *(uint4*)&Bh[sr][sh] = t4;    *(uint4*)&Bh[sr][sh + 8] = t5;
            uint4 t6 = *(const uint4*)pBl; uint4 t7 = *(const uint4*)(pBl + 8);
            *(uint4*)&Bl[sr][sh] = t6;    *(uint4*)&Bl[sr][sh + 8] = t7;
        }
        __syncthreads();
        short8 afh[4], afl[4], bfh[4], bfl[4];
        #pragma unroll
        for (int mi = 0; mi < 4; mi++){
            afh[mi] = *(const short8*)&Ah[wr * 64 + mi * 16 + fr][kg * 8];
            afl[mi] = *(const short8*)&Al[wr * 64 + mi * 16 + fr][kg * 8];
            bfh[mi] = *(const short8*)&Bh[wc * 64 + mi * 16 + fr][kg * 8];
            bfl[mi] = *(const short8*)&Bl[wc * 64 + mi * 16 + fr][kg * 8];
        }
        #pragma unroll
        for (int mi = 0; mi < 4; mi++)
            #pragma unroll
            for (int ni = 0; ni < 4; ni++){
                acc[mi][ni] = __builtin_amdgcn_mfma_f32_16x16x32_bf16(afh[mi], bfh[ni], acc[mi][ni], 0, 0, 0);
                acc[mi][ni] = __builtin_amdgcn_mfma_f32_16x16x32_bf16(afh[mi], bfl[ni], acc[mi][ni], 0, 0, 0);
                acc[mi][ni] = __builtin_amdgcn_mfma_f32_16x16x32_bf16(afl[mi], bfh[ni], acc[mi][ni], 0, 0, 0);
            }
    }
    #pragma unroll
    for (int mi = 0; mi < 4; mi++){
        #pragma unroll
        for (int r = 0; r < 4; r++){
            int o = o0 + wr * 64 + mi * 16 + kg * 4 + r;
            float s = 0.f, s2 = 0.f, mxv = -INFINITY, mnv = INFINITY;
            #pragma unroll
            for (int ni = 0; ni < 4; ni++){
                float y = acc[mi][ni][r];
                s += y; s2 += y * y;
                mxv = fmaxf(mxv, y); mnv = fminf(mnv, y);
            }
            #pragma unroll
            for (int off = 1; off < 16; off <<= 1){
                s  += __shfl_xor(s, off);
                s2 += __shfl_xor(s2, off);
                mxv = fmaxf(mxv, __shfl_xor(mxv, off));
                mnv = fminf(mnv, __shfl_xor(mnv, off));
            }
            if (fr == 0){
                atomicAdd(&ssum[o], s);
                atomicAdd(&ssum2[o], s2);
                atomicMax(&maxk[b * 1024 + o], fkey(mxv));
                atomicMin(&mink[b * 1024 + o], fkey(mnv));
            }
        }
    }
}

__global__ void final_out_kernel(const unsigned* __restrict__ maxk, const unsigned* __restrict__ mink,
                                 const float* __restrict__ ssum, const float* __restrict__ ssum2,
                                 const float* __restrict__ g5, const float* __restrict__ b5,
                                 float* __restrict__ out){
    int gid = blockIdx.x * 256 + threadIdx.x;
    if (gid >= NB * 1024) return;
    int o = gid & 1023;
    const float inv = 1.f / (NB * NPTS);
    float mean = ssum[o] * inv;
    float var = fmaxf(ssum2[o] * inv - mean * mean, 0.f);
    float sc = g5[o] * rsqrtf(var + EPSV);
    float sh = b5[o] - mean * sc;
    float sel = sc >= 0.f ? funkey(maxk[gid]) : funkey(mink[gid]);
    out[gid] = lrelu(sel * sc + sh);
}

extern "C" void kernel_launch(void* const* d_in, const int* in_sizes, int n_in,
                              void* d_out, int out_size, void* d_ws, size_t ws_size,
                              hipStream_t stream){
    (void)in_sizes; (void)n_in; (void)out_size;
    const float* x = (const float*)d_in[0];
    const float* Ws[5] = {(const float*)d_in[1], (const float*)d_in[4], (const float*)d_in[7],
                          (const float*)d_in[10], (const float*)d_in[13]};
    const float* Gs[5] = {(const float*)d_in[2], (const float*)d_in[5], (const float*)d_in[8],
                          (const float*)d_in[11], (const float*)d_in[14]};
    const float* Bs[5] = {(const float*)d_in[3], (const float*)d_in[6], (const float*)d_in[9],
                          (const float*)d_in[12], (const float*)d_in[15]};
    float* out = (float*)d_out;

    char* base = (char*)d_ws;
    size_t off = 0;
    auto alloc = [&](size_t bytes) -> char* {
        char* p = base + off;
        off = (off + bytes + 255) & ~(size_t)255;
        return p;
    };
    float*          F    = (float*)alloc((size_t)NB * NPTS * FSTR * 4);
    unsigned short* Fh   = (unsigned short*)alloc((size_t)NB * NPTS * CPAD * 2);
    unsigned short* Fl   = (unsigned short*)alloc((size_t)NB * NPTS * CPAD * 2);
    unsigned short* W5h  = (unsigned short*)alloc((size_t)1024 * CPAD * 2);
    unsigned short* W5l  = (unsigned short*)alloc((size_t)1024 * CPAD * 2);
    float*          sq   = (float*)alloc((size_t)NB * NPTS * 4);
    double*         sqd  = (double*)alloc((size_t)NB * NPTS * 8);
    int*            cand = (int*)  alloc((size_t)NB * NPTS * NCAND * 4);
    int*            idxb = (int*)  alloc((size_t)NB * NPTS * K * 4);
    float*          mx   = (float*)alloc((size_t)NB * NPTS * 128 * 4);
    float*          mn   = (float*)alloc((size_t)NB * NPTS * 128 * 4);
    float*          ssum = (float*)alloc(1024 * 4);   // ssum2 contiguous after
    float*          ssum2= (float*)alloc(1024 * 4);
    float*          scale= (float*)alloc(1024 * 4);
    float*          shift= (float*)alloc(1024 * 4);
    unsigned*       maxk = (unsigned*)alloc(NB * 1024 * 4);
    unsigned*       mink = (unsigned*)alloc(NB * 1024 * 4);
    // union region: dist (bz batches) overlaps u,v (used in disjoint phases)
    char* R = base + off;
    size_t avail = (ws_size > off) ? ws_size - off : 0;
    const size_t DSZ = (size_t)NPTS * NPTS * 4;
    int bz = 1;
    if (avail >= 8 * DSZ + 256) bz = 8;
    else if (avail >= 4 * DSZ + 256) bz = 4;
    else if (avail >= 2 * DSZ + 256) bz = 2;
    float* dist = (float*)R;
    float* u    = (float*)R;
    float* v    = (float*)(R + (size_t)NB * NPTS * 128 * 4);

    hipMemsetAsync(Fh, 0, (size_t)NB * NPTS * CPAD * 2, stream);
    hipMemsetAsync(Fl, 0, (size_t)NB * NPTS * CPAD * 2, stream);
    copy_x_kernel<<<(NB * NPTS + 255) / 256, 256, 0, stream>>>(x, F, Fh, Fl);
    convW_kernel<<<(1024 * CPAD + 255) / 256, 256, 0, stream>>>(Ws[4], W5h, W5l);

    const int Cs[4] = {3, 67, 131, 195};
    const int Os[4] = {64, 64, 64, 128};
    for (int s = 0; s < 4; s++){
        int C = Cs[s], O = Os[s];
        int Kp = (C + 31) & ~31;
        sqnorm2_kernel<<<NB * NPTS / 4, 256, 0, stream>>>(F, sq, sqd, C);
        for (int b0 = 0; b0 < NB; b0 += bz){
            dist_mfma_kernel<<<dim3(NPTS / 128, NPTS / 128, bz), 256, 0, stream>>>(Fh, Fl, sq, dist, b0, Kp);
            topk_kernel<<<bz * NPTS / 4, 256, 0, stream>>>(dist, cand, b0 * NPTS);
        }
        switch (C){
            case 3:   refine_kernel<3>  <<<NB * NPTS / 8, 256, 0, stream>>>(F, sqd, cand, idxb); break;
            case 67:  refine_kernel<67> <<<NB * NPTS / 8, 256, 0, stream>>>(F, sqd, cand, idxb); break;
            case 131: refine_kernel<131><<<NB * NPTS / 8, 256, 0, stream>>>(F, sqd, cand, idxb); break;
            default:  refine_kernel<195><<<NB * NPTS / 8, 256, 0, stream>>>(F, sqd, cand, idxb); break;
        }
        hipMemsetAsync(ssum, 0, 2048 * 4, stream);   // ssum + ssum2 (contiguous)
        if (O == 64){
            uv_gemm_kernel<64><<<NB * NPTS / 32, 256, 0, stream>>>(F, Ws[s], u, v, C);
            gather_kernel<64><<<256, 256, 0, stream>>>(v, u, idxb, mx, mn, ssum, ssum2);
            finalize_kernel<<<1, 64, 0, stream>>>(ssum, ssum2, Gs[s], Bs[s], scale, shift, 64,
                                                  1.f / ((float)NB * NPTS * K));
            apply_kernel<64><<<NB * NPTS * 64 / 256, 256, 0, stream>>>(u, mx, mn, scale, shift, F, Fh, Fl, C);
        } else {
            uv_gemm_kernel<128><<<NB * NPTS / 32, 256, 0, stream>>>(F, Ws[s], u, v, C);
            gather_kernel<128><<<256, 256, 0, stream>>>(v, u, idxb, mx, mn, ssum, ssum2);
            finalize_kernel<<<1, 128, 0, stream>>>(ssum, ssum2, Gs[s], Bs[s], scale, shift, 128,
                                                   1.f / ((float)NB * NPTS * K));
            apply_kernel<128><<<NB * NPTS * 128 / 256, 256, 0, stream>>>(u, mx, mn, scale, shift, F, Fh, Fl, C);
        }
    }

    hipMemsetAsync(ssum, 0, 2048 * 4, stream);
    hipMemsetAsync(maxk, 0, NB * 1024 * 4, stream);
    hipMemsetAsync(mink, 0xFF, NB * 1024 * 4, stream);
    final_mfma_kernel<<<dim3(1024 / 128, NPTS / 128, NB), 256, 0, stream>>>(W5h, W5l, Fh, Fl,
                                                                            ssum, ssum2, maxk, mink);
    final_out_kernel<<<NB * 1024 / 256, 256, 0, stream>>>(maxk, mink, ssum, ssum2, Gs[4], Bs[4], out);
}